// Round 12
// baseline (201.435 us; speedup 1.0000x reference)
//
#include <hip/hip_runtime.h>
#include <math.h>

#define TSEQ 2048
#define NB   2
#define NH   16
#define NE   8
#define DHD  64
#define MDIM 1024
#define MBT  4096   // NB*TSEQ
#define LDQKV 2560  // Q(1024) | K(1024) | V-experts(512)
#define NFULL 2816  // + gates Ws(128) | Wd(128)
#define GTAU 1.2e-2f  // margin threshold: 6 sigma of single-bf16 gate error
#define MAXFLAG 32768

typedef __attribute__((ext_vector_type(8))) short bf16x8;
typedef __attribute__((ext_vector_type(4))) float f32x4;
typedef __attribute__((ext_vector_type(16))) float f32x16;
typedef unsigned int u32;

__device__ inline unsigned short f2bf(float f) {
    union { float f; unsigned u; } v; v.f = f;
    unsigned r = v.u + 0x7fff + ((v.u >> 16) & 1);
    return (unsigned short)(r >> 16);
}
__device__ inline float bf2f(unsigned short h) {
    union { unsigned u; float f; } v; v.u = ((unsigned)h) << 16;
    return v.f;
}
__device__ inline u32 cvtpk(float a, float b) {   // low16=bf16(a), high16=bf16(b)
    u32 r;
    asm("v_cvt_pk_bf16_f32 %0, %1, %2" : "=v"(r) : "v"(a), "v"(b));
    return r;
}
// single-instruction exp2 (inputs bounded |x|<~8 here)
__device__ inline float fexp2(float x) {
#if __has_builtin(__builtin_amdgcn_exp2f)
    return __builtin_amdgcn_exp2f(x);
#else
    float r; asm("v_exp_f32 %0, %1" : "=v"(r) : "v"(x)); return r;
#endif
}

// async global->LDS, 16B per lane (dst wave-uniform base + lane*16)
__device__ inline void gload16(const void* g, void* l) {
    __builtin_amdgcn_global_load_lds((const __attribute__((address_space(1))) u32*)g,
                                     (__attribute__((address_space(3))) u32*)l, 16, 0, 0);
}

__device__ inline void cast8s(const float* __restrict__ in, unsigned short* __restrict__ out,
                              int i, float sc) {
    const float4* p = (const float4*)(in + (size_t)i * 8);
    float4 a = p[0], b = p[1];
    unsigned short o[8] = { f2bf(a.x*sc), f2bf(a.y*sc), f2bf(a.z*sc), f2bf(a.w*sc),
                            f2bf(b.x*sc), f2bf(b.y*sc), f2bf(b.z*sc), f2bf(b.w*sc) };
    *(uint4*)(out + (size_t)i * 8) = *(const uint4*)o;
}

// ---------------- fused prep (casts + Wsd bf16 append + Wo repack/split + flag reset) ----------
__global__ __launch_bounds__(256)
void prep(const float* __restrict__ x,  const float* __restrict__ Wq,
          const float* __restrict__ Wk, const float* __restrict__ Wv,
          const float* __restrict__ Ws, const float* __restrict__ Wd,
          const float* __restrict__ Wo,
          unsigned short* __restrict__ xb, unsigned short* __restrict__ Wqkvb,
          unsigned short* __restrict__ WoTh, unsigned short* __restrict__ WoTl,
          u32* __restrict__ flags)
{
    const float qsc = 0.125f * 1.4426950408889634f;  // fold scale*log2(e) into Q
    int b = blockIdx.x, tid = threadIdx.x;
    if (b == 0 && tid == 0) flags[0] = 0;
    if (b < 2048)      cast8s(x,  xb,               (b        ) * 256 + tid, 1.f);
    else if (b < 2560) cast8s(Wq, Wqkvb,            (b - 2048) * 256 + tid, qsc);
    else if (b < 3072) cast8s(Wk, Wqkvb + 1048576,  (b - 2560) * 256 + tid, 1.f);
    else if (b < 3328) cast8s(Wv, Wqkvb + 2097152,  (b - 3072) * 256 + tid, 1.f);
    else if (b < 3456) {
        int i = (b - 3328) * 256 + tid;   // 0..32767; 8 elems each of Ws|Wd -> rows 2560..2815
        const float* src = (i < 16384) ? Ws + (size_t)i * 8 : Wd + (size_t)(i - 16384) * 8;
        const float4* p = (const float4*)src;
        float4 a = p[0], bq = p[1];
        unsigned short o[8] = { f2bf(a.x), f2bf(a.y), f2bf(a.z), f2bf(a.w),
                                f2bf(bq.x), f2bf(bq.y), f2bf(bq.z), f2bf(bq.w) };
        *(uint4*)(Wqkvb + 2621440 + (size_t)i * 8) = *(const uint4*)o;
    } else {
        int idx = (b - 3456) * 256 + tid;  // < 524288
        int f = idx >> 9, ed = idx & 511, e = ed >> 6, d = ed & 63;
        float v = Wo[(size_t)e * (MDIM * DHD) + (size_t)f * DHD + d];
        unsigned short hi = f2bf(v);
        WoTh[idx] = hi;
        WoTl[idx] = f2bf(v - bf2f(hi));
    }
}

// ---------------- QKV+gate MFMA GEMM (gload_lds, XCD-swizzled) ----------------
// B has 2816 rows; cols <2560 -> bf16 QKVb (ld 2560); cols >=2560 -> fp32 Gf (ld 256)
__global__ __launch_bounds__(256)
void qkv_gemm(const unsigned short* __restrict__ A,
              const unsigned short* __restrict__ B,
              unsigned short* __restrict__ Cb, float* __restrict__ Gf)
{
    const int K = 1024, nbx = 22;
    __shared__ __align__(16) unsigned short As[128 * 32];
    __shared__ __align__(16) unsigned short Bs[128 * 32];
    const int o = blockIdx.x;                       // 704 blocks
    const int q8 = (int)gridDim.x >> 3;
    const int virt = (o & 7) * q8 + (o >> 3);       // bijective XCD-chunked remap
    const int bx = virt % nbx, by = virt / nbx;
    const int tid = threadIdx.x;
    const int lane = tid & 63, wave = tid >> 6;
    const int m0 = by * 128, n0 = bx * 128;
    const int wm = (wave >> 1) * 64, wn = (wave & 1) * 64;
    const int fr = lane & 15, fg = lane >> 4;
    const int grow = lane >> 2, gcol = (lane & 3) * 8;

    f32x4 acc[4][4];
    #pragma unroll
    for (int i = 0; i < 4; ++i)
        #pragma unroll
        for (int j = 0; j < 4; ++j) acc[i][j] = (f32x4)0.f;

    for (int k0 = 0; k0 < K; k0 += 32) {
        __syncthreads();
        const unsigned short* gA = A + (size_t)(m0 + wave * 32 + grow) * K + k0 + gcol;
        gload16(gA,                 As + wave * 1024);
        gload16(gA + (size_t)16 * K, As + wave * 1024 + 512);
        const unsigned short* gB = B + (size_t)(n0 + wave * 32 + grow) * K + k0 + gcol;
        gload16(gB,                 Bs + wave * 1024);
        gload16(gB + (size_t)16 * K, Bs + wave * 1024 + 512);
        __syncthreads();
        bf16x8 af[4], bfr[4];
        #pragma unroll
        for (int t = 0; t < 4; ++t) {
            af[t]  = *(const bf16x8*)(As + (wm + t * 16 + fr) * 32 + fg * 8);
            bfr[t] = *(const bf16x8*)(Bs + (wn + t * 16 + fr) * 32 + fg * 8);
        }
        #pragma unroll
        for (int i = 0; i < 4; ++i)
            #pragma unroll
            for (int j = 0; j < 4; ++j)
                acc[i][j] = __builtin_amdgcn_mfma_f32_16x16x32_bf16(af[i], bfr[j], acc[i][j], 0, 0, 0);
    }
    if (n0 < LDQKV) {
        #pragma unroll
        for (int i = 0; i < 4; ++i)
            #pragma unroll
            for (int j = 0; j < 4; ++j)
                #pragma unroll
                for (int rr = 0; rr < 4; ++rr) {
                    int row = m0 + wm + i * 16 + fg * 4 + rr;
                    int col = n0 + wn + j * 16 + fr;
                    Cb[(size_t)row * LDQKV + col] = f2bf(acc[i][j][rr]);
                }
    } else {
        #pragma unroll
        for (int i = 0; i < 4; ++i)
            #pragma unroll
            for (int j = 0; j < 4; ++j)
                #pragma unroll
                for (int rr = 0; rr < 4; ++rr) {
                    int row = m0 + wm + i * 16 + fg * 4 + rr;
                    int col = n0 - LDQKV + wn + j * 16 + fr;
                    Gf[(size_t)row * 256 + col] = acc[i][j][rr];
                }
    }
}

// ---------------- split-bf16 3-pass MFMA GEMM, fp32 out (final projection, swizzled) ----------------
__global__ __launch_bounds__(256)
void mfma_gemm3(const unsigned short* __restrict__ Ah, const unsigned short* __restrict__ Al,
                const unsigned short* __restrict__ Bh, const unsigned short* __restrict__ Bl,
                float* __restrict__ C)
{
    const int Kc = 512, N = 1024;
    __shared__ __align__(16) unsigned short Ash[128 * 32];
    __shared__ __align__(16) unsigned short Asl[128 * 32];
    __shared__ __align__(16) unsigned short Bsh[128 * 32];
    __shared__ __align__(16) unsigned short Bsl[128 * 32];
    const int o = blockIdx.x;                       // 256 blocks
    const int virt = (o & 7) * 32 + (o >> 3);
    const int bx = virt & 7, by = virt >> 3;
    const int tid = threadIdx.x;
    const int lane = tid & 63, wave = tid >> 6;
    const int m0 = by * 128, n0 = bx * 128;
    const int wm = (wave >> 1) * 64, wn = (wave & 1) * 64;
    const int fr = lane & 15, fg = lane >> 4;
    const int grow = lane >> 2, gcol = (lane & 3) * 8;

    f32x4 acc[4][4];
    #pragma unroll
    for (int i = 0; i < 4; ++i)
        #pragma unroll
        for (int j = 0; j < 4; ++j) acc[i][j] = (f32x4)0.f;

    for (int k0 = 0; k0 < Kc; k0 += 32) {
        __syncthreads();
        const size_t roff  = (size_t)(m0 + wave * 32 + grow) * Kc + k0 + gcol;
        const size_t roffB = (size_t)(n0 + wave * 32 + grow) * Kc + k0 + gcol;
        gload16(Ah + roff,             Ash + wave * 1024);
        gload16(Ah + roff + 16 * Kc,   Ash + wave * 1024 + 512);
        gload16(Al + roff,             Asl + wave * 1024);
        gload16(Al + roff + 16 * Kc,   Asl + wave * 1024 + 512);
        gload16(Bh + roffB,            Bsh + wave * 1024);
        gload16(Bh + roffB + 16 * Kc,  Bsh + wave * 1024 + 512);
        gload16(Bl + roffB,            Bsl + wave * 1024);
        gload16(Bl + roffB + 16 * Kc,  Bsl + wave * 1024 + 512);
        __syncthreads();
        bf16x8 ah[4], al[4], bh[4], bl[4];
        #pragma unroll
        for (int t = 0; t < 4; ++t) {
            ah[t] = *(const bf16x8*)(Ash + (wm + t * 16 + fr) * 32 + fg * 8);
            al[t] = *(const bf16x8*)(Asl + (wm + t * 16 + fr) * 32 + fg * 8);
            bh[t] = *(const bf16x8*)(Bsh + (wn + t * 16 + fr) * 32 + fg * 8);
            bl[t] = *(const bf16x8*)(Bsl + (wn + t * 16 + fr) * 32 + fg * 8);
        }
        #pragma unroll
        for (int i = 0; i < 4; ++i)
            #pragma unroll
            for (int j = 0; j < 4; ++j) {
                acc[i][j] = __builtin_amdgcn_mfma_f32_16x16x32_bf16(ah[i], bh[j], acc[i][j], 0, 0, 0);
                acc[i][j] = __builtin_amdgcn_mfma_f32_16x16x32_bf16(ah[i], bl[j], acc[i][j], 0, 0, 0);
                acc[i][j] = __builtin_amdgcn_mfma_f32_16x16x32_bf16(al[i], bh[j], acc[i][j], 0, 0, 0);
            }
    }
    #pragma unroll
    for (int i = 0; i < 4; ++i)
        #pragma unroll
        for (int j = 0; j < 4; ++j)
            #pragma unroll
            for (int rr = 0; rr < 4; ++rr) {
                int row = m0 + wm + i * 16 + fg * 4 + rr;
                int col = n0 + wn + j * 16 + fr;
                C[(size_t)row * N + col] = acc[i][j][rr];
            }
}

// ---------------- top-2 + margin flagging ----------------
__global__ __launch_bounds__(256)
void gate_topk2(const float* __restrict__ Gf,
                float2* __restrict__ wv, u32* __restrict__ selv, u32* __restrict__ selo,
                u32* __restrict__ flags)
{
    int item = blockIdx.x * 256 + threadIdx.x;   // < 65536
    int bt = item >> 4, h = item & 15;
    const float* g = Gf + (size_t)bt * 256 + h * NE;
    float b1 = -1e30f, b2 = -1e30f, b3 = -1e30f; int e1 = 0, e2 = 0;
    #pragma unroll
    for (int e = 0; e < NE; ++e) {
        float v = g[e];
        if (v > b1)      { b3 = b2; b2 = b1; e2 = e1; b1 = v; e1 = e; }
        else if (v > b2) { b3 = b2; b2 = v;  e2 = e; }
        else if (v > b3) { b3 = v; }
    }
    wv[item] = make_float2(1.f / (1.f + __expf(-b1)), 1.f / (1.f + __expf(-b2)));
    selv[item] = (u32)e1 | ((u32)e2 << 4);
    if (b2 - b3 < GTAU) {
        u32 p = atomicAdd(flags, 1u);
        if (p < MAXFLAG) flags[1 + p] = (u32)item;
    }
    const float* go = g + 128;
    float o1 = -1e30f, o2 = -1e30f, o3 = -1e30f; int f1 = 0, f2 = 0;
    #pragma unroll
    for (int e = 0; e < NE; ++e) {
        float v = go[e];
        if (v > o1)      { o3 = o2; o2 = o1; f2 = f1; o1 = v; f1 = e; }
        else if (v > o2) { o3 = o2; o2 = v;  f2 = e; }
        else if (v > o3) { o3 = v; }
    }
    selo[item] = (1u << f1) | (1u << f2);
    if (o2 - o3 < GTAU) {
        u32 p = atomicAdd(flags, 1u);
        if (p < MAXFLAG) flags[1 + p] = (u32)item | 0x10000u;
    }
}

// ---------------- fp64 fix-up for flagged near-tie items (one wave per record) ----------------
__global__ __launch_bounds__(256)
void gate_fix(const float* __restrict__ x, const float* __restrict__ Ws,
              const float* __restrict__ Wd, const u32* __restrict__ flags,
              float2* __restrict__ wv, u32* __restrict__ selv, u32* __restrict__ selo)
{
    u32 nf = flags[0]; if (nf > MAXFLAG) nf = MAXFLAG;
    int gw = (blockIdx.x * 256 + threadIdx.x) >> 6;
    int lane = threadIdx.x & 63;
    int nwaves = gridDim.x * 4;
    for (u32 w = gw; w < nf; w += nwaves) {
        u32 rec = flags[1 + w];
        int item = rec & 0xffff, which = rec >> 16;
        int bt = item >> 4, h = item & 15;
        const float* W = (which ? Wd : Ws) + (size_t)h * NE * MDIM + lane * 16;
        const float* xr = x + (size_t)bt * MDIM + lane * 16;
        double g[8];
        #pragma unroll
        for (int e = 0; e < 8; ++e) {
            double s = 0.0;
            #pragma unroll
            for (int c = 0; c < 16; ++c)
                s += (double)xr[c] * (double)W[(size_t)e * MDIM + c];
            g[e] = s;
        }
        #pragma unroll
        for (int off = 32; off; off >>= 1)
            #pragma unroll
            for (int e = 0; e < 8; ++e)
                g[e] += __shfl_xor(g[e], off, 64);
        if (lane == 0) {
            double b1 = -1e300, b2 = -1e300; int i1 = 0, i2 = 0;
            #pragma unroll
            for (int e = 0; e < 8; ++e) {
                double v = g[e];
                if (v > b1)      { b2 = b1; i2 = i1; b1 = v; i1 = e; }
                else if (v > b2) { b2 = v;  i2 = e; }
            }
            if (which == 0) {
                wv[item] = make_float2(1.f / (1.f + __expf(-(float)b1)),
                                       1.f / (1.f + __expf(-(float)b2)));
                selv[item] = (u32)i1 | ((u32)i2 << 4);
            } else {
                selo[item] = (1u << i1) | (1u << i2);
            }
        }
    }
}

// ---------------- V mix + transpose, LDS-staged: Vtg[b][h][d][t] ----------------
#define VTP 72   // LDS row stride (bf16 elems), 144 B, 16B-aligned
__global__ __launch_bounds__(256)
void vtrans(const unsigned short* __restrict__ QKVb, const float2* __restrict__ wv,
            const u32* __restrict__ selv, unsigned short* __restrict__ Vtg)
{
    __shared__ __align__(16) unsigned short Ls[256 * VTP];
    const int vid = blockIdx.x;              // 0..255
    const int xcd = vid & 7, local = vid >> 3;
    const int virt = xcd * 32 + local;       // bijective XCD-chunked remap
    const int b = virt >> 7, rem = virt & 127;
    const int tblk = rem >> 4, h = rem & 15;
    const int tid = threadIdx.x;

    // phase 1: one thread per t — mix the 2 selected experts, vector loads
    {
        const int bt = b * TSEQ + tblk * 256 + tid;
        u32 s = selv[bt * 16 + h];
        float2 w = wv[bt * 16 + h];
        int e1 = s & 15, e2 = (s >> 4) & 15;
        const unsigned short* pv = QKVb + (size_t)bt * LDQKV + 2048;
        #pragma unroll
        for (int c = 0; c < 8; ++c) {
            uint4 a  = *(const uint4*)(pv + e1 * 64 + c * 8);
            uint4 bb = *(const uint4*)(pv + e2 * 64 + c * 8);
            unsigned short ea[8], eb[8], eo[8];
            *(uint4*)ea = a; *(uint4*)eb = bb;
            #pragma unroll
            for (int j = 0; j < 8; ++j)
                eo[j] = f2bf(w.x * bf2f(ea[j]) + w.y * bf2f(eb[j]));
            *(uint4*)(Ls + tid * VTP + c * 8) = *(const uint4*)eo;
        }
    }
    __syncthreads();
    // phase 2: transpose out of LDS — lane = d (conflict-free broadcast pairs)
    {
        const int d = tid & 63, outer = tid >> 6;
        const size_t vrow = ((size_t)((b * NH + h) * DHD + d)) * TSEQ + tblk * 256;
        #pragma unroll
        for (int c8 = 0; c8 < 8; ++c8) {
            int t0 = (outer * 8 + c8) * 8;
            unsigned short o[8];
            #pragma unroll
            for (int j = 0; j < 8; ++j)
                o[j] = Ls[(t0 + j) * VTP + d];
            *(uint4*)(Vtg + vrow + t0) = *(const uint4*)o;
        }
    }
}

// ---------------- attn: swapped-QK 32x32 MFMA, in-register P, fixed-max softmax ----------------
// flat grid 1024, XCD-swizzled: each XCD owns 8 (b,h,split) groups x 16 q-blocks
#define SPA 72   // LDS row stride (bf16) = 144 B
#define MFMA32(A,B,C) __builtin_amdgcn_mfma_f32_32x32x16_bf16(A, B, C, 0, 0, 0)
__global__ __launch_bounds__(256)
void attn_mfma(const unsigned short* __restrict__ QKVb,
               const unsigned short* __restrict__ Vtg,
               float* __restrict__ Op0, float* __restrict__ Op1,
               float* __restrict__ lp)
{
    __shared__ __align__(16) unsigned short Ks[64 * SPA];
    __shared__ __align__(16) unsigned short Vt[64 * SPA];   // V^T: rows=d, cols=key
    const int vid = blockIdx.x;                  // 0..1023
    const int xcd = vid & 7, sl = vid >> 3;      // sl 0..127
    const int grp = xcd * 8 + (sl >> 4);         // 0..63 (b,h,split group)
    const int q0  = (sl & 15) * 128;
    const int h   = grp & 15;
    const int z   = grp >> 4;                    // 0..3
    const int b = z >> 1, split = z & 1;
    const int tid = threadIdx.x;
    const int lane = tid & 63, wq = tid >> 6;
    const int ql = lane & 31;
    const int hi = lane >> 5;
    const size_t base_q = ((size_t)b * TSEQ) * LDQKV + h * DHD;
    const size_t base_k = base_q + 1024;
    const size_t base_v = ((size_t)(b * NH + h) * DHD) * TSEQ;
    const int k00 = split * 1024;

    const int qrow = q0 + wq * 32 + ql;
    bf16x8 qa[4];
    #pragma unroll
    for (int t = 0; t < 4; ++t)
        qa[t] = *(const bf16x8*)(QKVb + base_q + (size_t)qrow * LDQKV + t * 16 + hi * 8);

    f32x16 o0 = (f32x16)0.f, o1 = (f32x16)0.f;
    float l_lane = 0.f;

    const int srow = tid >> 2, scol = (tid & 3) * 8;
    uint4 kr0 = *(const uint4*)(QKVb + base_k + (size_t)(k00 + srow) * LDQKV + scol);
    uint4 kr1 = *(const uint4*)(QKVb + base_k + (size_t)(k00 + srow) * LDQKV + scol + 32);
    uint4 vr0 = *(const uint4*)(Vtg + base_v + (size_t)srow * TSEQ + k00 + scol);
    uint4 vr1 = *(const uint4*)(Vtg + base_v + (size_t)srow * TSEQ + k00 + scol + 32);

    const int NT = 1024 / 64;
    for (int kb = 0; kb < NT; ++kb) {
        __syncthreads();
        *(uint4*)(Ks + srow * SPA + scol)      = kr0;
        *(uint4*)(Ks + srow * SPA + scol + 32) = kr1;
        *(uint4*)(Vt + srow * SPA + scol)      = vr0;
        *(uint4*)(Vt + srow * SPA + scol + 32) = vr1;
        __syncthreads();
        if (kb + 1 < NT) {
            const size_t gk = base_k + (size_t)(k00 + (kb + 1) * 64 + srow) * LDQKV + scol;
            const size_t gv = base_v + (size_t)srow * TSEQ + k00 + (kb + 1) * 64 + scol;
            kr0 = *(const uint4*)(QKVb + gk);
            kr1 = *(const uint4*)(QKVb + gk + 32);
            vr0 = *(const uint4*)(Vtg + gv);
            vr1 = *(const uint4*)(Vtg + gv + 32);
        }
        f32x16 s0 = (f32x16)0.f, s1 = (f32x16)0.f;
        #pragma unroll
        for (int t = 0; t < 4; ++t) {
            bf16x8 k0 = *(const bf16x8*)(Ks + ql * SPA + t * 16 + hi * 8);
            bf16x8 k1 = *(const bf16x8*)(Ks + (32 + ql) * SPA + t * 16 + hi * 8);
            s0 = MFMA32(k0, qa[t], s0);
            s1 = MFMA32(k1, qa[t], s1);
        }
        float ls0 = 0.f, ls1 = 0.f;
        u32 w[8];
        #pragma unroll
        for (int r = 0; r < 16; r += 2) {
            float pa = fexp2(s0[r]), pb = fexp2(s0[r + 1]);
            s0[r] = pa; s0[r + 1] = pb;
            ls0 += pa; ls1 += pb;
        }
        #pragma unroll
        for (int m = 0; m < 8; ++m) w[m] = cvtpk(s0[2*m], s0[2*m+1]);
        #pragma unroll
        for (int tl = 0; tl < 2; ++tl) {
            const int mb = 4 * tl, tk = tl;
            u32 send0 = hi ? w[mb]   : w[mb+2];
            u32 send1 = hi ? w[mb+1] : w[mb+3];
            u32 r0 = (u32)__shfl_xor((int)send0, 32, 64);
            u32 r1 = (u32)__shfl_xor((int)send1, 32, 64);
            union { u32 uw[4]; bf16x8 v; } pu;
            pu.uw[0] = hi ? r0 : w[mb];
            pu.uw[1] = hi ? r1 : w[mb+1];
            pu.uw[2] = hi ? w[mb+2] : r0;
            pu.uw[3] = hi ? w[mb+3] : r1;
            bf16x8 v0 = *(const bf16x8*)(Vt + ql * SPA + tk * 16 + hi * 8);
            bf16x8 v1 = *(const bf16x8*)(Vt + (32 + ql) * SPA + tk * 16 + hi * 8);
            o0 = MFMA32(pu.v, v0, o0);
            o1 = MFMA32(pu.v, v1, o1);
        }
        #pragma unroll
        for (int r = 0; r < 16; r += 2) {
            float pa = fexp2(s1[r]), pb = fexp2(s1[r + 1]);
            s1[r] = pa; s1[r + 1] = pb;
            ls0 += pa; ls1 += pb;
        }
        #pragma unroll
        for (int m = 0; m < 8; ++m) w[m] = cvtpk(s1[2*m], s1[2*m+1]);
        #pragma unroll
        for (int tl = 0; tl < 2; ++tl) {
            const int mb = 4 * tl, tk = 2 + tl;
            u32 send0 = hi ? w[mb]   : w[mb+2];
            u32 send1 = hi ? w[mb+1] : w[mb+3];
            u32 r0 = (u32)__shfl_xor((int)send0, 32, 64);
            u32 r1 = (u32)__shfl_xor((int)send1, 32, 64);
            union { u32 uw[4]; bf16x8 v; } pu;
            pu.uw[0] = hi ? r0 : w[mb];
            pu.uw[1] = hi ? r1 : w[mb+1];
            pu.uw[2] = hi ? w[mb+2] : r0;
            pu.uw[3] = hi ? w[mb+3] : r1;
            bf16x8 v0 = *(const bf16x8*)(Vt + ql * SPA + tk * 16 + hi * 8);
            bf16x8 v1 = *(const bf16x8*)(Vt + (32 + ql) * SPA + tk * 16 + hi * 8);
            o0 = MFMA32(pu.v, v0, o0);
            o1 = MFMA32(pu.v, v1, o1);
        }
        l_lane += ls0 + ls1;
    }
    float l_tot = l_lane + __shfl_xor(l_lane, 32, 64);
    float* Op = split ? Op1 : Op0;
    const size_t ob = ((size_t)b * TSEQ) * MDIM + h * DHD;
    #pragma unroll
    for (int r = 0; r < 16; ++r) {
        int qr = q0 + wq * 32 + (r & 3) + 8 * (r >> 2) + 4 * hi;
        Op[ob + (size_t)qr * MDIM + ql]      = o0[r];
        Op[ob + (size_t)qr * MDIM + 32 + ql] = o1[r];
    }
    if (hi == 0)
        lp[(((size_t)split * NB + b) * NH + h) * TSEQ + q0 + wq * 32 + ql] = l_tot;
}

// ---------------- U: per-(bt,d) — att[h] once, distribute to 8 experts, bf16 split -------------
__global__ __launch_bounds__(256)
void compute_U2(const float* __restrict__ Op0, const float* __restrict__ Op1,
                const float* __restrict__ lp, const u32* __restrict__ selo,
                unsigned short* __restrict__ Uh, unsigned short* __restrict__ Ul)
{
    int t = blockIdx.x * 256 + threadIdx.x;      // < MBT*64 = 262144
    int bt = t >> 6, d = t & 63;
    int b = bt >> 11, ts = bt & 2047;
    float att[16];
    #pragma unroll
    for (int h = 0; h < NH; ++h) {
        size_t li = ((size_t)b * NH + h) * TSEQ + ts;
        float l = lp[li] + lp[li + (size_t)NB * NH * TSEQ];
        size_t oi = (size_t)bt * MDIM + h * DHD + d;
        att[h] = (Op0[oi] + Op1[oi]) / l;
    }
    const u32* sp = selo + bt * 16;
    u32 m[16];
    #pragma unroll
    for (int h = 0; h < NH; ++h) m[h] = sp[h];
    #pragma unroll
    for (int e = 0; e < NE; ++e) {
        float sum = 0.f;
        #pragma unroll
        for (int h = 0; h < NH; ++h)
            if (m[h] & (1u << e)) sum += att[h];
        int idx = bt * 512 + e * 64 + d;
        unsigned short hi16 = f2bf(sum);
        Uh[idx] = hi16;
        Ul[idx] = f2bf(sum - bf2f(hi16));
    }
}

extern "C" void kernel_launch(void* const* d_in, const int* in_sizes, int n_in,
                              void* d_out, int out_size, void* d_ws, size_t ws_size,
                              hipStream_t stream)
{
    const float* x  = (const float*)d_in[0];
    const float* Wq = (const float*)d_in[1];
    const float* Wk = (const float*)d_in[2];
    const float* Wv = (const float*)d_in[3];
    const float* Ws = (const float*)d_in[4];
    const float* Wd = (const float*)d_in[5];
    const float* Wo = (const float*)d_in[6];
    float* out = (float*)d_out;
    char* ws = (char*)d_ws;

    // region 0 (16.78 MB): [xb 8.39 | Wqkvb 5.77] -> Op0 ; region @46137344: Op1
    unsigned short* xb    = (unsigned short*)(ws);
    unsigned short* Wqkvb = (unsigned short*)(ws + 8388608);    // 2816x1024 bf16 = 5.77 MB
    float*          Op0   = (float*)(ws);
    unsigned short* QKVb  = (unsigned short*)(ws + 16777216);   // 20.97 MB
    unsigned short* Vtg   = (unsigned short*)(ws + 37748736);   // 8.39 MB
    float*          Op1   = (float*)(ws + 46137344);            // 16.78 MB
    float*          lp    = (float*)(ws + 62914560);            // 0.52 MB
    unsigned short* WoTh  = (unsigned short*)(ws + 63438848);   // 1.05 MB
    unsigned short* WoTl  = (unsigned short*)(ws + 64487424);   // 1.05 MB
    float*          Gf    = (float*)(ws + 65536000);            // 4.19 MB (dead before Uh)
    unsigned short* Uh    = (unsigned short*)(ws + 65536000);   // 4.19 MB
    u32*            flags = (u32*)(ws + 69730304);              // 128 KB (dead before Ul)
    unsigned short* Ul    = (unsigned short*)(ws + 69730304);   // 4.19 MB
    float2*         wvp   = (float2*)(ws + 73924608);           // 0.52 MB
    u32*            selv  = (u32*)(ws + 74448896);              // 0.26 MB
    u32*            selo  = (u32*)(ws + 74711040);              // 0.26 MB

    dim3 blk(256);
    prep<<<5504, blk, 0, stream>>>(x, Wq, Wk, Wv, Ws, Wd, Wo,
                                   xb, Wqkvb, WoTh, WoTl, flags);

    // fused QKV+gate projection: [4096,2816] = xb * Wqkv|sd^T (gates -> fp32 Gf)
    qkv_gemm<<<704, blk, 0, stream>>>(xb, Wqkvb, QKVb, Gf);

    gate_topk2<<<256, blk, 0, stream>>>(Gf, wvp, selv, selo, flags);
    gate_fix<<<512, blk, 0, stream>>>(x, Ws, Wd, flags, wvp, selv, selo);

    vtrans<<<256, blk, 0, stream>>>(QKVb, wvp, selv, Vtg);

    attn_mfma<<<1024, blk, 0, stream>>>(QKVb, Vtg, Op0, Op1, lp);

    compute_U2<<<1024, blk, 0, stream>>>(Op0, Op1, lp, selo, Uh, Ul);
    mfma_gemm3<<<256, blk, 0, stream>>>(Uh, Ul, WoTh, WoTl, out);
}

// Round 13
// 175.399 us; speedup vs baseline: 1.1484x; 1.1484x over previous
//
#include <hip/hip_runtime.h>
#include <math.h>

#define TSEQ 2048
#define NB   2
#define NH   16
#define NE   8
#define DHD  64
#define MDIM 1024
#define MBT  4096   // NB*TSEQ
#define LDQKV 2560  // Q(1024) | K(1024) | V-experts(512)
#define GTAU 1e-3f  // margin threshold for fp64 gate fix-up
#define MAXFLAG 16384

typedef __attribute__((ext_vector_type(8))) short bf16x8;
typedef __attribute__((ext_vector_type(4))) float f32x4;
typedef __attribute__((ext_vector_type(16))) float f32x16;
typedef unsigned int u32;

__device__ inline unsigned short f2bf(float f) {
    union { float f; unsigned u; } v; v.f = f;
    unsigned r = v.u + 0x7fff + ((v.u >> 16) & 1);
    return (unsigned short)(r >> 16);
}
__device__ inline float bf2f(unsigned short h) {
    union { unsigned u; float f; } v; v.u = ((unsigned)h) << 16;
    return v.f;
}
__device__ inline u32 cvtpk(float a, float b) {   // low16=bf16(a), high16=bf16(b)
    u32 r;
    asm("v_cvt_pk_bf16_f32 %0, %1, %2" : "=v"(r) : "v"(a), "v"(b));
    return r;
}
// single-instruction exp2 (inputs bounded |x|<~8 here; no denorm/range handling needed)
__device__ inline float fexp2(float x) {
#if __has_builtin(__builtin_amdgcn_exp2f)
    return __builtin_amdgcn_exp2f(x);
#else
    float r; asm("v_exp_f32 %0, %1" : "=v"(r) : "v"(x)); return r;
#endif
}

// async global->LDS, 16B per lane (dst wave-uniform base + lane*16)
__device__ inline void gload16(const void* g, void* l) {
    __builtin_amdgcn_global_load_lds((const __attribute__((address_space(1))) u32*)g,
                                     (__attribute__((address_space(3))) u32*)l, 16, 0, 0);
}

__device__ inline void cast8s(const float* __restrict__ in, unsigned short* __restrict__ out,
                              int i, float sc) {
    const float4* p = (const float4*)(in + (size_t)i * 8);
    float4 a = p[0], b = p[1];
    unsigned short o[8] = { f2bf(a.x*sc), f2bf(a.y*sc), f2bf(a.z*sc), f2bf(a.w*sc),
                            f2bf(b.x*sc), f2bf(b.y*sc), f2bf(b.z*sc), f2bf(b.w*sc) };
    *(uint4*)(out + (size_t)i * 8) = *(const uint4*)o;
}
__device__ inline void cast8hl(const float* __restrict__ in,
                               unsigned short* __restrict__ oh, unsigned short* __restrict__ ol,
                               int i) {
    const float4* p = (const float4*)(in + (size_t)i * 8);
    float4 a = p[0], b = p[1];
    float f[8] = { a.x, a.y, a.z, a.w, b.x, b.y, b.z, b.w };
    unsigned short h8[8], l8[8];
    #pragma unroll
    for (int j = 0; j < 8; ++j) {
        unsigned short hi = f2bf(f[j]);
        h8[j] = hi;
        l8[j] = f2bf(f[j] - bf2f(hi));
    }
    *(uint4*)(oh + (size_t)i * 8) = *(const uint4*)h8;
    *(uint4*)(ol + (size_t)i * 8) = *(const uint4*)l8;
}

// ---------------- fused prep (casts + Wsd split + Wo repack/split + flag reset) ----------------
__global__ __launch_bounds__(256)
void prep(const float* __restrict__ x,  const float* __restrict__ Wq,
          const float* __restrict__ Wk, const float* __restrict__ Wv,
          const float* __restrict__ Ws, const float* __restrict__ Wd,
          const float* __restrict__ Wo,
          unsigned short* __restrict__ xb, unsigned short* __restrict__ xbl,
          unsigned short* __restrict__ Wqkvb,
          unsigned short* __restrict__ Wsdh, unsigned short* __restrict__ Wsdl,
          unsigned short* __restrict__ WoTh, unsigned short* __restrict__ WoTl,
          u32* __restrict__ flags)
{
    const float qsc = 0.125f * 1.4426950408889634f;  // fold scale*log2(e) into Q
    int b = blockIdx.x, tid = threadIdx.x;
    if (b == 0 && tid == 0) flags[0] = 0;
    if (b < 2048)      cast8hl(x, xb, xbl,          (b        ) * 256 + tid);
    else if (b < 2560) cast8s(Wq, Wqkvb,            (b - 2048) * 256 + tid, qsc);
    else if (b < 3072) cast8s(Wk, Wqkvb + 1048576,  (b - 2560) * 256 + tid, 1.f);
    else if (b < 3328) cast8s(Wv, Wqkvb + 2097152,  (b - 3072) * 256 + tid, 1.f);
    else if (b < 3456) {
        int i = (b - 3328) * 256 + tid;   // 0..32767; 8 elems each of Ws|Wd
        const float* src = (i < 16384) ? Ws + (size_t)i * 8 : Wd + (size_t)(i - 16384) * 8;
        const float4* p = (const float4*)src;
        float4 a = p[0], bq = p[1];
        float f8[8] = { a.x, a.y, a.z, a.w, bq.x, bq.y, bq.z, bq.w };
        unsigned short h8[8], l8[8];
        #pragma unroll
        for (int j = 0; j < 8; ++j) {
            unsigned short hi = f2bf(f8[j]);
            h8[j] = hi;
            l8[j] = f2bf(f8[j] - bf2f(hi));
        }
        *(uint4*)(Wsdh + (size_t)i * 8) = *(const uint4*)h8;
        *(uint4*)(Wsdl + (size_t)i * 8) = *(const uint4*)l8;
    } else {
        int idx = (b - 3456) * 256 + tid;  // < 524288
        int f = idx >> 9, ed = idx & 511, e = ed >> 6, d = ed & 63;
        float v = Wo[(size_t)e * (MDIM * DHD) + (size_t)f * DHD + d];
        unsigned short hi = f2bf(v);
        WoTh[idx] = hi;
        WoTl[idx] = f2bf(v - bf2f(hi));
    }
}

// ---------------- bf16 MFMA GEMM (gload_lds staging, XCD-swizzled): C[M,N]=A*B^T ----------------
__global__ __launch_bounds__(256)
void mfma_gemm(const unsigned short* __restrict__ A,
               const unsigned short* __restrict__ B,
               unsigned short* __restrict__ C, int N, int K, int nbx)
{
    __shared__ __align__(16) unsigned short As[128 * 32];
    __shared__ __align__(16) unsigned short Bs[128 * 32];
    const int o = blockIdx.x;
    const int q8 = (int)gridDim.x >> 3;
    const int virt = (o & 7) * q8 + (o >> 3);      // bijective XCD-chunked remap
    const int bx = virt % nbx, by = virt / nbx;
    const int tid = threadIdx.x;
    const int lane = tid & 63, wave = tid >> 6;
    const int m0 = by * 128, n0 = bx * 128;
    const int wm = (wave >> 1) * 64, wn = (wave & 1) * 64;
    const int fr = lane & 15, fg = lane >> 4;
    const int grow = lane >> 2, gcol = (lane & 3) * 8;

    f32x4 acc[4][4];
    #pragma unroll
    for (int i = 0; i < 4; ++i)
        #pragma unroll
        for (int j = 0; j < 4; ++j) acc[i][j] = (f32x4)0.f;

    for (int k0 = 0; k0 < K; k0 += 32) {
        __syncthreads();
        const unsigned short* gA = A + (size_t)(m0 + wave * 32 + grow) * K + k0 + gcol;
        gload16(gA,                 As + wave * 1024);
        gload16(gA + (size_t)16 * K, As + wave * 1024 + 512);
        const unsigned short* gB = B + (size_t)(n0 + wave * 32 + grow) * K + k0 + gcol;
        gload16(gB,                 Bs + wave * 1024);
        gload16(gB + (size_t)16 * K, Bs + wave * 1024 + 512);
        __syncthreads();
        bf16x8 af[4], bfr[4];
        #pragma unroll
        for (int t = 0; t < 4; ++t) {
            af[t]  = *(const bf16x8*)(As + (wm + t * 16 + fr) * 32 + fg * 8);
            bfr[t] = *(const bf16x8*)(Bs + (wn + t * 16 + fr) * 32 + fg * 8);
        }
        #pragma unroll
        for (int i = 0; i < 4; ++i)
            #pragma unroll
            for (int j = 0; j < 4; ++j)
                acc[i][j] = __builtin_amdgcn_mfma_f32_16x16x32_bf16(af[i], bfr[j], acc[i][j], 0, 0, 0);
    }
    #pragma unroll
    for (int i = 0; i < 4; ++i)
        #pragma unroll
        for (int j = 0; j < 4; ++j)
            #pragma unroll
            for (int rr = 0; rr < 4; ++rr) {
                int row = m0 + wm + i * 16 + fg * 4 + rr;
                int col = n0 + wn + j * 16 + fr;
                C[(size_t)row * N + col] = f2bf(acc[i][j][rr]);
            }
}

// ---------------- split-bf16 3-pass MFMA GEMM, fp32 out (final projection, swizzled) ----------------
__global__ __launch_bounds__(256)
void mfma_gemm3(const unsigned short* __restrict__ Ah, const unsigned short* __restrict__ Al,
                const unsigned short* __restrict__ Bh, const unsigned short* __restrict__ Bl,
                float* __restrict__ C)
{
    const int Kc = 512, N = 1024;
    __shared__ __align__(16) unsigned short Ash[128 * 32];
    __shared__ __align__(16) unsigned short Asl[128 * 32];
    __shared__ __align__(16) unsigned short Bsh[128 * 32];
    __shared__ __align__(16) unsigned short Bsl[128 * 32];
    const int o = blockIdx.x;                       // 256 blocks
    const int virt = (o & 7) * 32 + (o >> 3);
    const int bx = virt & 7, by = virt >> 3;
    const int tid = threadIdx.x;
    const int lane = tid & 63, wave = tid >> 6;
    const int m0 = by * 128, n0 = bx * 128;
    const int wm = (wave >> 1) * 64, wn = (wave & 1) * 64;
    const int fr = lane & 15, fg = lane >> 4;
    const int grow = lane >> 2, gcol = (lane & 3) * 8;

    f32x4 acc[4][4];
    #pragma unroll
    for (int i = 0; i < 4; ++i)
        #pragma unroll
        for (int j = 0; j < 4; ++j) acc[i][j] = (f32x4)0.f;

    for (int k0 = 0; k0 < Kc; k0 += 32) {
        __syncthreads();
        const size_t roff  = (size_t)(m0 + wave * 32 + grow) * Kc + k0 + gcol;
        const size_t roffB = (size_t)(n0 + wave * 32 + grow) * Kc + k0 + gcol;
        gload16(Ah + roff,             Ash + wave * 1024);
        gload16(Ah + roff + 16 * Kc,   Ash + wave * 1024 + 512);
        gload16(Al + roff,             Asl + wave * 1024);
        gload16(Al + roff + 16 * Kc,   Asl + wave * 1024 + 512);
        gload16(Bh + roffB,            Bsh + wave * 1024);
        gload16(Bh + roffB + 16 * Kc,  Bsh + wave * 1024 + 512);
        gload16(Bl + roffB,            Bsl + wave * 1024);
        gload16(Bl + roffB + 16 * Kc,  Bsl + wave * 1024 + 512);
        __syncthreads();
        bf16x8 ah[4], al[4], bh[4], bl[4];
        #pragma unroll
        for (int t = 0; t < 4; ++t) {
            ah[t] = *(const bf16x8*)(Ash + (wm + t * 16 + fr) * 32 + fg * 8);
            al[t] = *(const bf16x8*)(Asl + (wm + t * 16 + fr) * 32 + fg * 8);
            bh[t] = *(const bf16x8*)(Bsh + (wn + t * 16 + fr) * 32 + fg * 8);
            bl[t] = *(const bf16x8*)(Bsl + (wn + t * 16 + fr) * 32 + fg * 8);
        }
        #pragma unroll
        for (int i = 0; i < 4; ++i)
            #pragma unroll
            for (int j = 0; j < 4; ++j) {
                acc[i][j] = __builtin_amdgcn_mfma_f32_16x16x32_bf16(ah[i], bh[j], acc[i][j], 0, 0, 0);
                acc[i][j] = __builtin_amdgcn_mfma_f32_16x16x32_bf16(ah[i], bl[j], acc[i][j], 0, 0, 0);
                acc[i][j] = __builtin_amdgcn_mfma_f32_16x16x32_bf16(al[i], bh[j], acc[i][j], 0, 0, 0);
            }
    }
    #pragma unroll
    for (int i = 0; i < 4; ++i)
        #pragma unroll
        for (int j = 0; j < 4; ++j)
            #pragma unroll
            for (int rr = 0; rr < 4; ++rr) {
                int row = m0 + wm + i * 16 + fg * 4 + rr;
                int col = n0 + wn + j * 16 + fr;
                C[(size_t)row * N + col] = acc[i][j][rr];
            }
}

// ---------------- gate GEMM: split-bf16 3-pass, Gf[4096][256] fp32 ----------------
__global__ __launch_bounds__(256)
void gate_gemm(const unsigned short* __restrict__ Ah, const unsigned short* __restrict__ Al,
               const unsigned short* __restrict__ Bh, const unsigned short* __restrict__ Bl,
               float* __restrict__ C)
{
    const int K = 1024, N = 256;
    __shared__ __align__(16) unsigned short S[4][64 * 32];
    const int tid = threadIdx.x;
    const int lane = tid & 63, wave = tid >> 6;
    const int m0 = blockIdx.y * 64, n0 = blockIdx.x * 64;
    const int wm = (wave >> 1) * 32, wn = (wave & 1) * 32;
    const int fr = lane & 15, fg = lane >> 4;
    const int grow = lane >> 2, gcol = (lane & 3) * 8;

    const unsigned short* src = (wave == 0) ? Ah : (wave == 1) ? Al : (wave == 2) ? Bh : Bl;
    const int brow = (wave >= 2) ? n0 : m0;

    f32x4 acc[2][2];
    #pragma unroll
    for (int i = 0; i < 2; ++i)
        #pragma unroll
        for (int j = 0; j < 2; ++j) acc[i][j] = (f32x4)0.f;

    for (int k0 = 0; k0 < K; k0 += 32) {
        __syncthreads();
        #pragma unroll
        for (int i = 0; i < 4; ++i)
            gload16(src + (size_t)(brow + i * 16 + grow) * K + k0 + gcol, &S[wave][i * 512]);
        __syncthreads();
        bf16x8 ah[2], al[2], bh[2], bl[2];
        #pragma unroll
        for (int t = 0; t < 2; ++t) {
            ah[t] = *(const bf16x8*)(&S[0][(wm + t * 16 + fr) * 32 + fg * 8]);
            al[t] = *(const bf16x8*)(&S[1][(wm + t * 16 + fr) * 32 + fg * 8]);
            bh[t] = *(const bf16x8*)(&S[2][(wn + t * 16 + fr) * 32 + fg * 8]);
            bl[t] = *(const bf16x8*)(&S[3][(wn + t * 16 + fr) * 32 + fg * 8]);
        }
        #pragma unroll
        for (int i = 0; i < 2; ++i)
            #pragma unroll
            for (int j = 0; j < 2; ++j) {
                acc[i][j] = __builtin_amdgcn_mfma_f32_16x16x32_bf16(ah[i], bh[j], acc[i][j], 0, 0, 0);
                acc[i][j] = __builtin_amdgcn_mfma_f32_16x16x32_bf16(ah[i], bl[j], acc[i][j], 0, 0, 0);
                acc[i][j] = __builtin_amdgcn_mfma_f32_16x16x32_bf16(al[i], bh[j], acc[i][j], 0, 0, 0);
            }
    }
    #pragma unroll
    for (int i = 0; i < 2; ++i)
        #pragma unroll
        for (int j = 0; j < 2; ++j)
            #pragma unroll
            for (int rr = 0; rr < 4; ++rr) {
                int row = m0 + wm + i * 16 + fg * 4 + rr;
                int col = n0 + wn + j * 16 + fr;
                C[(size_t)row * N + col] = acc[i][j][rr];
            }
}

// ---------------- top-2 + margin flagging ----------------
__global__ __launch_bounds__(256)
void gate_topk2(const float* __restrict__ Gf,
                float2* __restrict__ wv, u32* __restrict__ selv, u32* __restrict__ selo,
                u32* __restrict__ flags)
{
    int item = blockIdx.x * 256 + threadIdx.x;   // < 65536
    int bt = item >> 4, h = item & 15;
    const float* g = Gf + (size_t)bt * 256 + h * NE;
    float b1 = -1e30f, b2 = -1e30f, b3 = -1e30f; int e1 = 0, e2 = 0;
    #pragma unroll
    for (int e = 0; e < NE; ++e) {
        float v = g[e];
        if (v > b1)      { b3 = b2; b2 = b1; e2 = e1; b1 = v; e1 = e; }
        else if (v > b2) { b3 = b2; b2 = v;  e2 = e; }
        else if (v > b3) { b3 = v; }
    }
    wv[item] = make_float2(1.f / (1.f + __expf(-b1)), 1.f / (1.f + __expf(-b2)));
    selv[item] = (u32)e1 | ((u32)e2 << 4);
    if (b2 - b3 < GTAU) {
        u32 p = atomicAdd(flags, 1u);
        if (p < MAXFLAG) flags[1 + p] = (u32)item;
    }
    const float* go = g + 128;
    float o1 = -1e30f, o2 = -1e30f, o3 = -1e30f; int f1 = 0, f2 = 0;
    #pragma unroll
    for (int e = 0; e < NE; ++e) {
        float v = go[e];
        if (v > o1)      { o3 = o2; o2 = o1; f2 = f1; o1 = v; f1 = e; }
        else if (v > o2) { o3 = o2; o2 = v;  f2 = e; }
        else if (v > o3) { o3 = v; }
    }
    selo[item] = (1u << f1) | (1u << f2);
    if (o2 - o3 < GTAU) {
        u32 p = atomicAdd(flags, 1u);
        if (p < MAXFLAG) flags[1 + p] = (u32)item | 0x10000u;
    }
}

// ---------------- fp64 fix-up for flagged near-tie items (one wave per record) ----------------
__global__ __launch_bounds__(256)
void gate_fix(const float* __restrict__ x, const float* __restrict__ Ws,
              const float* __restrict__ Wd, const u32* __restrict__ flags,
              float2* __restrict__ wv, u32* __restrict__ selv, u32* __restrict__ selo)
{
    u32 nf = flags[0]; if (nf > MAXFLAG) nf = MAXFLAG;
    int gw = (blockIdx.x * 256 + threadIdx.x) >> 6;
    int lane = threadIdx.x & 63;
    int nwaves = gridDim.x * 4;
    for (u32 w = gw; w < nf; w += nwaves) {
        u32 rec = flags[1 + w];
        int item = rec & 0xffff, which = rec >> 16;
        int bt = item >> 4, h = item & 15;
        const float* W = (which ? Wd : Ws) + (size_t)h * NE * MDIM + lane * 16;
        const float* xr = x + (size_t)bt * MDIM + lane * 16;
        double g[8];
        #pragma unroll
        for (int e = 0; e < 8; ++e) {
            double s = 0.0;
            #pragma unroll
            for (int c = 0; c < 16; ++c)
                s += (double)xr[c] * (double)W[(size_t)e * MDIM + c];
            g[e] = s;
        }
        #pragma unroll
        for (int off = 32; off; off >>= 1)
            #pragma unroll
            for (int e = 0; e < 8; ++e)
                g[e] += __shfl_xor(g[e], off, 64);
        if (lane == 0) {
            double b1 = -1e300, b2 = -1e300; int i1 = 0, i2 = 0;
            #pragma unroll
            for (int e = 0; e < 8; ++e) {
                double v = g[e];
                if (v > b1)      { b2 = b1; i2 = i1; b1 = v; i1 = e; }
                else if (v > b2) { b2 = v;  i2 = e; }
            }
            if (which == 0) {
                wv[item] = make_float2(1.f / (1.f + __expf(-(float)b1)),
                                       1.f / (1.f + __expf(-(float)b2)));
                selv[item] = (u32)i1 | ((u32)i2 << 4);
            } else {
                selo[item] = (1u << i1) | (1u << i2);
            }
        }
    }
}

// ---------------- V mix + transpose, LDS-staged: Vtg[b][h][d][t] ----------------
#define VTP 72   // LDS row stride (bf16 elems), 144 B, 16B-aligned
__global__ __launch_bounds__(256)
void vtrans(const unsigned short* __restrict__ QKVb, const float2* __restrict__ wv,
            const u32* __restrict__ selv, unsigned short* __restrict__ Vtg)
{
    __shared__ __align__(16) unsigned short Ls[256 * VTP];
    const int vid = blockIdx.x;              // 0..255
    const int xcd = vid & 7, local = vid >> 3;
    const int virt = xcd * 32 + local;       // bijective XCD-chunked remap
    const int b = virt >> 7, rem = virt & 127;
    const int tblk = rem >> 4, h = rem & 15;
    const int tid = threadIdx.x;

    // phase 1: one thread per t — mix the 2 selected experts, vector loads
    {
        const int bt = b * TSEQ + tblk * 256 + tid;
        u32 s = selv[bt * 16 + h];
        float2 w = wv[bt * 16 + h];
        int e1 = s & 15, e2 = (s >> 4) & 15;
        const unsigned short* pv = QKVb + (size_t)bt * LDQKV + 2048;
        #pragma unroll
        for (int c = 0; c < 8; ++c) {
            uint4 a  = *(const uint4*)(pv + e1 * 64 + c * 8);
            uint4 bb = *(const uint4*)(pv + e2 * 64 + c * 8);
            unsigned short ea[8], eb[8], eo[8];
            *(uint4*)ea = a; *(uint4*)eb = bb;
            #pragma unroll
            for (int j = 0; j < 8; ++j)
                eo[j] = f2bf(w.x * bf2f(ea[j]) + w.y * bf2f(eb[j]));
            *(uint4*)(Ls + tid * VTP + c * 8) = *(const uint4*)eo;
        }
    }
    __syncthreads();
    // phase 2: transpose out of LDS — lane = d (conflict-free broadcast pairs)
    {
        const int d = tid & 63, outer = tid >> 6;
        const size_t vrow = ((size_t)((b * NH + h) * DHD + d)) * TSEQ + tblk * 256;
        #pragma unroll
        for (int c8 = 0; c8 < 8; ++c8) {
            int t0 = (outer * 8 + c8) * 8;
            unsigned short o[8];
            #pragma unroll
            for (int j = 0; j < 8; ++j)
                o[j] = Ls[(t0 + j) * VTP + d];
            *(uint4*)(Vtg + vrow + t0) = *(const uint4*)o;
        }
    }
}

// ---------------- attn: swapped-QK 32x32 MFMA, in-register P, fixed-max softmax ----------------
// flat grid 1024, XCD-swizzled: each XCD owns 8 (b,h,split) groups x 16 q-blocks
#define SPA 72   // LDS row stride (bf16) = 144 B
#define MFMA32(A,B,C) __builtin_amdgcn_mfma_f32_32x32x16_bf16(A, B, C, 0, 0, 0)
__global__ __launch_bounds__(256)
void attn_mfma(const unsigned short* __restrict__ QKVb,
               const unsigned short* __restrict__ Vtg,
               float* __restrict__ Op0, float* __restrict__ Op1,
               float* __restrict__ lp)
{
    __shared__ __align__(16) unsigned short Ks[64 * SPA];
    __shared__ __align__(16) unsigned short Vt[64 * SPA];   // V^T: rows=d, cols=key
    const int vid = blockIdx.x;                  // 0..1023
    const int xcd = vid & 7, sl = vid >> 3;      // sl 0..127
    const int grp = xcd * 8 + (sl >> 4);         // 0..63 (b,h,split group)
    const int q0  = (sl & 15) * 128;
    const int h   = grp & 15;
    const int z   = grp >> 4;                    // 0..3
    const int b = z >> 1, split = z & 1;
    const int tid = threadIdx.x;
    const int lane = tid & 63, wq = tid >> 6;
    const int ql = lane & 31;
    const int hi = lane >> 5;
    const size_t base_q = ((size_t)b * TSEQ) * LDQKV + h * DHD;
    const size_t base_k = base_q + 1024;
    const size_t base_v = ((size_t)(b * NH + h) * DHD) * TSEQ;
    const int k00 = split * 1024;

    const int qrow = q0 + wq * 32 + ql;
    bf16x8 qa[4];
    #pragma unroll
    for (int t = 0; t < 4; ++t)
        qa[t] = *(const bf16x8*)(QKVb + base_q + (size_t)qrow * LDQKV + t * 16 + hi * 8);

    f32x16 o0 = (f32x16)0.f, o1 = (f32x16)0.f;
    float l_lane = 0.f;

    const int srow = tid >> 2, scol = (tid & 3) * 8;
    uint4 kr0 = *(const uint4*)(QKVb + base_k + (size_t)(k00 + srow) * LDQKV + scol);
    uint4 kr1 = *(const uint4*)(QKVb + base_k + (size_t)(k00 + srow) * LDQKV + scol + 32);
    uint4 vr0 = *(const uint4*)(Vtg + base_v + (size_t)srow * TSEQ + k00 + scol);
    uint4 vr1 = *(const uint4*)(Vtg + base_v + (size_t)srow * TSEQ + k00 + scol + 32);

    const int NT = 1024 / 64;
    for (int kb = 0; kb < NT; ++kb) {
        __syncthreads();
        *(uint4*)(Ks + srow * SPA + scol)      = kr0;
        *(uint4*)(Ks + srow * SPA + scol + 32) = kr1;
        *(uint4*)(Vt + srow * SPA + scol)      = vr0;
        *(uint4*)(Vt + srow * SPA + scol + 32) = vr1;
        __syncthreads();
        if (kb + 1 < NT) {
            const size_t gk = base_k + (size_t)(k00 + (kb + 1) * 64 + srow) * LDQKV + scol;
            const size_t gv = base_v + (size_t)srow * TSEQ + k00 + (kb + 1) * 64 + scol;
            kr0 = *(const uint4*)(QKVb + gk);
            kr1 = *(const uint4*)(QKVb + gk + 32);
            vr0 = *(const uint4*)(Vtg + gv);
            vr1 = *(const uint4*)(Vtg + gv + 32);
        }
        f32x16 s0 = (f32x16)0.f, s1 = (f32x16)0.f;
        #pragma unroll
        for (int t = 0; t < 4; ++t) {
            bf16x8 k0 = *(const bf16x8*)(Ks + ql * SPA + t * 16 + hi * 8);
            bf16x8 k1 = *(const bf16x8*)(Ks + (32 + ql) * SPA + t * 16 + hi * 8);
            s0 = MFMA32(k0, qa[t], s0);
            s1 = MFMA32(k1, qa[t], s1);
        }
        float ls0 = 0.f, ls1 = 0.f;
        u32 w[8];
        #pragma unroll
        for (int r = 0; r < 16; r += 2) {
            float pa = fexp2(s0[r]), pb = fexp2(s0[r + 1]);
            s0[r] = pa; s0[r + 1] = pb;
            ls0 += pa; ls1 += pb;
        }
        #pragma unroll
        for (int m = 0; m < 8; ++m) w[m] = cvtpk(s0[2*m], s0[2*m+1]);
        #pragma unroll
        for (int tl = 0; tl < 2; ++tl) {
            const int mb = 4 * tl, tk = tl;
            u32 send0 = hi ? w[mb]   : w[mb+2];
            u32 send1 = hi ? w[mb+1] : w[mb+3];
            u32 r0 = (u32)__shfl_xor((int)send0, 32, 64);
            u32 r1 = (u32)__shfl_xor((int)send1, 32, 64);
            union { u32 uw[4]; bf16x8 v; } pu;
            pu.uw[0] = hi ? r0 : w[mb];
            pu.uw[1] = hi ? r1 : w[mb+1];
            pu.uw[2] = hi ? w[mb+2] : r0;
            pu.uw[3] = hi ? w[mb+3] : r1;
            bf16x8 v0 = *(const bf16x8*)(Vt + ql * SPA + tk * 16 + hi * 8);
            bf16x8 v1 = *(const bf16x8*)(Vt + (32 + ql) * SPA + tk * 16 + hi * 8);
            o0 = MFMA32(pu.v, v0, o0);
            o1 = MFMA32(pu.v, v1, o1);
        }
        #pragma unroll
        for (int r = 0; r < 16; r += 2) {
            float pa = fexp2(s1[r]), pb = fexp2(s1[r + 1]);
            s1[r] = pa; s1[r + 1] = pb;
            ls0 += pa; ls1 += pb;
        }
        #pragma unroll
        for (int m = 0; m < 8; ++m) w[m] = cvtpk(s1[2*m], s1[2*m+1]);
        #pragma unroll
        for (int tl = 0; tl < 2; ++tl) {
            const int mb = 4 * tl, tk = 2 + tl;
            u32 send0 = hi ? w[mb]   : w[mb+2];
            u32 send1 = hi ? w[mb+1] : w[mb+3];
            u32 r0 = (u32)__shfl_xor((int)send0, 32, 64);
            u32 r1 = (u32)__shfl_xor((int)send1, 32, 64);
            union { u32 uw[4]; bf16x8 v; } pu;
            pu.uw[0] = hi ? r0 : w[mb];
            pu.uw[1] = hi ? r1 : w[mb+1];
            pu.uw[2] = hi ? w[mb+2] : r0;
            pu.uw[3] = hi ? w[mb+3] : r1;
            bf16x8 v0 = *(const bf16x8*)(Vt + ql * SPA + tk * 16 + hi * 8);
            bf16x8 v1 = *(const bf16x8*)(Vt + (32 + ql) * SPA + tk * 16 + hi * 8);
            o0 = MFMA32(pu.v, v0, o0);
            o1 = MFMA32(pu.v, v1, o1);
        }
        l_lane += ls0 + ls1;
    }
    float l_tot = l_lane + __shfl_xor(l_lane, 32, 64);
    float* Op = split ? Op1 : Op0;
    const size_t ob = ((size_t)b * TSEQ) * MDIM + h * DHD;
    #pragma unroll
    for (int r = 0; r < 16; ++r) {
        int qr = q0 + wq * 32 + (r & 3) + 8 * (r >> 2) + 4 * hi;
        Op[ob + (size_t)qr * MDIM + ql]      = o0[r];
        Op[ob + (size_t)qr * MDIM + 32 + ql] = o1[r];
    }
    if (hi == 0)
        lp[(((size_t)split * NB + b) * NH + h) * TSEQ + q0 + wq * 32 + ql] = l_tot;
}

// ---------------- U: per-(bt,d) — att[h] once, distribute to 8 experts, bf16 split -------------
__global__ __launch_bounds__(256)
void compute_U2(const float* __restrict__ Op0, const float* __restrict__ Op1,
                const float* __restrict__ lp, const u32* __restrict__ selo,
                unsigned short* __restrict__ Uh, unsigned short* __restrict__ Ul)
{
    int t = blockIdx.x * 256 + threadIdx.x;      // < MBT*64 = 262144
    int bt = t >> 6, d = t & 63;
    int b = bt >> 11, ts = bt & 2047;
    float att[16];
    #pragma unroll
    for (int h = 0; h < NH; ++h) {
        size_t li = ((size_t)b * NH + h) * TSEQ + ts;
        float l = lp[li] + lp[li + (size_t)NB * NH * TSEQ];
        size_t oi = (size_t)bt * MDIM + h * DHD + d;
        att[h] = (Op0[oi] + Op1[oi]) / l;
    }
    const u32* sp = selo + bt * 16;
    u32 m[16];
    #pragma unroll
    for (int h = 0; h < NH; ++h) m[h] = sp[h];
    #pragma unroll
    for (int e = 0; e < NE; ++e) {
        float sum = 0.f;
        #pragma unroll
        for (int h = 0; h < NH; ++h)
            if (m[h] & (1u << e)) sum += att[h];
        int idx = bt * 512 + e * 64 + d;
        unsigned short hi16 = f2bf(sum);
        Uh[idx] = hi16;
        Ul[idx] = f2bf(sum - bf2f(hi16));
    }
}

extern "C" void kernel_launch(void* const* d_in, const int* in_sizes, int n_in,
                              void* d_out, int out_size, void* d_ws, size_t ws_size,
                              hipStream_t stream)
{
    const float* x  = (const float*)d_in[0];
    const float* Wq = (const float*)d_in[1];
    const float* Wk = (const float*)d_in[2];
    const float* Wv = (const float*)d_in[3];
    const float* Ws = (const float*)d_in[4];
    const float* Wd = (const float*)d_in[5];
    const float* Wo = (const float*)d_in[6];
    float* out = (float*)d_out;
    char* ws = (char*)d_ws;

    // region 0 (16.78 MB): [xb|Wqkvb] -> Op0 ; region @46137344 (16.78 MB): xbl -> Op1
    unsigned short* xb    = (unsigned short*)(ws);
    unsigned short* Wqkvb = (unsigned short*)(ws + 8388608);
    float*          Op0   = (float*)(ws);
    unsigned short* QKVb  = (unsigned short*)(ws + 16777216);   // 20.97 MB
    unsigned short* Vtg   = (unsigned short*)(ws + 37748736);   // 8.39 MB
    unsigned short* xbl   = (unsigned short*)(ws + 46137344);   // 8.39 MB (dead before attn)
    float*          Op1   = (float*)(ws + 46137344);            // 16.78 MB
    float*          lp    = (float*)(ws + 62914560);            // 0.52 MB
    unsigned short* WoTh  = (unsigned short*)(ws + 63438848);   // 1.05 MB
    unsigned short* WoTl  = (unsigned short*)(ws + 64487424);   // 1.05 MB
    float*          Gf    = (float*)(ws + 65536000);            // 4.19 MB (dead before Uh)
    unsigned short* Uh    = (unsigned short*)(ws + 65536000);   // 4.19 MB
    u32*            flags = (u32*)(ws + 69730304);              // 64 KB (dead before Ul)
    unsigned short* Ul    = (unsigned short*)(ws + 69730304);   // 4.19 MB
    float2*         wvp   = (float2*)(ws + 73924608);           // 0.52 MB
    u32*            selv  = (u32*)(ws + 74448896);              // 0.26 MB
    u32*            selo  = (u32*)(ws + 74711040);              // 0.26 MB
    unsigned short* Wsdh  = (unsigned short*)(ws + 74973184);   // 0.52 MB
    unsigned short* Wsdl  = (unsigned short*)(ws + 75497472);   // 0.52 MB

    dim3 blk(256);
    prep<<<5504, blk, 0, stream>>>(x, Wq, Wk, Wv, Ws, Wd, Wo,
                                   xb, xbl, Wqkvb, Wsdh, Wsdl, WoTh, WoTl, flags);

    // fused QKV projection (Q pre-scaled): [4096,2560] = xb * Wqkv^T  (XCD-swizzled)
    mfma_gemm<<<640, blk, 0, stream>>>(xb, Wqkvb, QKVb, LDQKV, 1024, 20);

    // gates: split-bf16 MFMA + margin-gated fp64 fix-up
    gate_gemm<<<dim3(4, 64), blk, 0, stream>>>(xb, xbl, Wsdh, Wsdl, Gf);
    gate_topk2<<<256, blk, 0, stream>>>(Gf, wvp, selv, selo, flags);
    gate_fix<<<128, blk, 0, stream>>>(x, Ws, Wd, flags, wvp, selv, selo);

    vtrans<<<256, blk, 0, stream>>>(QKVb, wvp, selv, Vtg);

    attn_mfma<<<1024, blk, 0, stream>>>(QKVb, Vtg, Op0, Op1, lp);

    compute_U2<<<1024, blk, 0, stream>>>(Op0, Op1, lp, selo, Uh, Ul);
    mfma_gemm3<<<256, blk, 0, stream>>>(Uh, Ul, WoTh, WoTl, out);
}

// Round 14
// 167.616 us; speedup vs baseline: 1.2018x; 1.0464x over previous
//
#include <hip/hip_runtime.h>
#include <math.h>

#define TSEQ 2048
#define NB   2
#define NH   16
#define NE   8
#define DHD  64
#define MDIM 1024
#define MBT  4096   // NB*TSEQ
#define LDQKV 2560  // Q(1024) | K(1024) | V-experts(512)
#define GTAU 1e-3f  // margin threshold for fp64 gate fix-up
#define MAXFLAG 16384

typedef __attribute__((ext_vector_type(8))) short bf16x8;
typedef __attribute__((ext_vector_type(4))) float f32x4;
typedef __attribute__((ext_vector_type(16))) float f32x16;
typedef unsigned int u32;

__device__ inline unsigned short f2bf(float f) {
    union { float f; unsigned u; } v; v.f = f;
    unsigned r = v.u + 0x7fff + ((v.u >> 16) & 1);
    return (unsigned short)(r >> 16);
}
__device__ inline float bf2f(unsigned short h) {
    union { unsigned u; float f; } v; v.u = ((unsigned)h) << 16;
    return v.f;
}
__device__ inline u32 cvtpk(float a, float b) {   // low16=bf16(a), high16=bf16(b)
    u32 r;
    asm("v_cvt_pk_bf16_f32 %0, %1, %2" : "=v"(r) : "v"(a), "v"(b));
    return r;
}
// single-instruction exp2 (inputs bounded |x|<~8 here; no denorm/range handling needed)
__device__ inline float fexp2(float x) {
#if __has_builtin(__builtin_amdgcn_exp2f)
    return __builtin_amdgcn_exp2f(x);
#else
    float r; asm("v_exp_f32 %0, %1" : "=v"(r) : "v"(x)); return r;
#endif
}

// async global->LDS, 16B per lane (dst wave-uniform base + lane*16)
__device__ inline void gload16(const void* g, void* l) {
    __builtin_amdgcn_global_load_lds((const __attribute__((address_space(1))) u32*)g,
                                     (__attribute__((address_space(3))) u32*)l, 16, 0, 0);
}

__device__ inline void cast8s(const float* __restrict__ in, unsigned short* __restrict__ out,
                              int i, float sc) {
    const float4* p = (const float4*)(in + (size_t)i * 8);
    float4 a = p[0], b = p[1];
    unsigned short o[8] = { f2bf(a.x*sc), f2bf(a.y*sc), f2bf(a.z*sc), f2bf(a.w*sc),
                            f2bf(b.x*sc), f2bf(b.y*sc), f2bf(b.z*sc), f2bf(b.w*sc) };
    *(uint4*)(out + (size_t)i * 8) = *(const uint4*)o;
}
__device__ inline void cast8hl(const float* __restrict__ in,
                               unsigned short* __restrict__ oh, unsigned short* __restrict__ ol,
                               int i) {
    const float4* p = (const float4*)(in + (size_t)i * 8);
    float4 a = p[0], b = p[1];
    float f[8] = { a.x, a.y, a.z, a.w, b.x, b.y, b.z, b.w };
    unsigned short h8[8], l8[8];
    #pragma unroll
    for (int j = 0; j < 8; ++j) {
        unsigned short hi = f2bf(f[j]);
        h8[j] = hi;
        l8[j] = f2bf(f[j] - bf2f(hi));
    }
    *(uint4*)(oh + (size_t)i * 8) = *(const uint4*)h8;
    *(uint4*)(ol + (size_t)i * 8) = *(const uint4*)l8;
}

// ---------------- fused prep (casts + Wsd split + Wo repack/split + flag reset) ----------------
__global__ __launch_bounds__(256)
void prep(const float* __restrict__ x,  const float* __restrict__ Wq,
          const float* __restrict__ Wk, const float* __restrict__ Wv,
          const float* __restrict__ Ws, const float* __restrict__ Wd,
          const float* __restrict__ Wo,
          unsigned short* __restrict__ xb, unsigned short* __restrict__ xbl,
          unsigned short* __restrict__ Wqkvb,
          unsigned short* __restrict__ Wsdh, unsigned short* __restrict__ Wsdl,
          unsigned short* __restrict__ WoTh, unsigned short* __restrict__ WoTl,
          u32* __restrict__ flags)
{
    const float qsc = 0.125f * 1.4426950408889634f;  // fold scale*log2(e) into Q
    int b = blockIdx.x, tid = threadIdx.x;
    if (b == 0 && tid == 0) flags[0] = 0;
    if (b < 2048)      cast8hl(x, xb, xbl,          (b        ) * 256 + tid);
    else if (b < 2560) cast8s(Wq, Wqkvb,            (b - 2048) * 256 + tid, qsc);
    else if (b < 3072) cast8s(Wk, Wqkvb + 1048576,  (b - 2560) * 256 + tid, 1.f);
    else if (b < 3328) cast8s(Wv, Wqkvb + 2097152,  (b - 3072) * 256 + tid, 1.f);
    else if (b < 3456) {
        int i = (b - 3328) * 256 + tid;   // 0..32767; 8 elems each of Ws|Wd
        const float* src = (i < 16384) ? Ws + (size_t)i * 8 : Wd + (size_t)(i - 16384) * 8;
        const float4* p = (const float4*)src;
        float4 a = p[0], bq = p[1];
        float f8[8] = { a.x, a.y, a.z, a.w, bq.x, bq.y, bq.z, bq.w };
        unsigned short h8[8], l8[8];
        #pragma unroll
        for (int j = 0; j < 8; ++j) {
            unsigned short hi = f2bf(f8[j]);
            h8[j] = hi;
            l8[j] = f2bf(f8[j] - bf2f(hi));
        }
        *(uint4*)(Wsdh + (size_t)i * 8) = *(const uint4*)h8;
        *(uint4*)(Wsdl + (size_t)i * 8) = *(const uint4*)l8;
    } else {
        int idx = (b - 3456) * 256 + tid;  // < 524288
        int f = idx >> 9, ed = idx & 511, e = ed >> 6, d = ed & 63;
        float v = Wo[(size_t)e * (MDIM * DHD) + (size_t)f * DHD + d];
        unsigned short hi = f2bf(v);
        WoTh[idx] = hi;
        WoTl[idx] = f2bf(v - bf2f(hi));
    }
}

// ---------------- merged QKV GEMM (640 blocks) + gate GEMM (256 blocks) ----------------
// blockIdx < 640: C[4096,2560] = xb * Wqkv^T (bf16 out, XCD-swizzled)
// blockIdx >= 640: Gf[4096,256] = (xb+xbl) * (Wsdh+Wsdl)^T 3-pass split-bf16 (fp32 out)
__global__ __launch_bounds__(256)
void qkvgate(const unsigned short* __restrict__ A,
             const unsigned short* __restrict__ B,
             unsigned short* __restrict__ C,
             const unsigned short* __restrict__ Al,
             const unsigned short* __restrict__ Bh2, const unsigned short* __restrict__ Bl2,
             float* __restrict__ Gf)
{
    __shared__ __align__(16) unsigned short S[8192];   // 16 KB, unioned between paths
    const int tid = threadIdx.x;
    const int lane = tid & 63, wave = tid >> 6;
    const int fr = lane & 15, fg = lane >> 4;
    const int grow = lane >> 2, gcol = (lane & 3) * 8;

    if (blockIdx.x < 640) {
        // ---------------- QKV path ----------------
        const int K = 1024, N = LDQKV, nbx = 20;
        unsigned short* As = S;            // 128*32
        unsigned short* Bs = S + 4096;     // 128*32
        const int o = blockIdx.x;
        const int virt = (o & 7) * 80 + (o >> 3);      // bijective XCD-chunked remap (640/8=80)
        const int bx = virt % nbx, by = virt / nbx;
        const int m0 = by * 128, n0 = bx * 128;
        const int wm = (wave >> 1) * 64, wn = (wave & 1) * 64;

        f32x4 acc[4][4];
        #pragma unroll
        for (int i = 0; i < 4; ++i)
            #pragma unroll
            for (int j = 0; j < 4; ++j) acc[i][j] = (f32x4)0.f;

        for (int k0 = 0; k0 < K; k0 += 32) {
            __syncthreads();
            const unsigned short* gA = A + (size_t)(m0 + wave * 32 + grow) * K + k0 + gcol;
            gload16(gA,                  As + wave * 1024);
            gload16(gA + (size_t)16 * K, As + wave * 1024 + 512);
            const unsigned short* gB = B + (size_t)(n0 + wave * 32 + grow) * K + k0 + gcol;
            gload16(gB,                  Bs + wave * 1024);
            gload16(gB + (size_t)16 * K, Bs + wave * 1024 + 512);
            __syncthreads();
            bf16x8 af[4], bfr[4];
            #pragma unroll
            for (int t = 0; t < 4; ++t) {
                af[t]  = *(const bf16x8*)(As + (wm + t * 16 + fr) * 32 + fg * 8);
                bfr[t] = *(const bf16x8*)(Bs + (wn + t * 16 + fr) * 32 + fg * 8);
            }
            #pragma unroll
            for (int i = 0; i < 4; ++i)
                #pragma unroll
                for (int j = 0; j < 4; ++j)
                    acc[i][j] = __builtin_amdgcn_mfma_f32_16x16x32_bf16(af[i], bfr[j], acc[i][j], 0, 0, 0);
        }
        #pragma unroll
        for (int i = 0; i < 4; ++i)
            #pragma unroll
            for (int j = 0; j < 4; ++j)
                #pragma unroll
                for (int rr = 0; rr < 4; ++rr) {
                    int row = m0 + wm + i * 16 + fg * 4 + rr;
                    int col = n0 + wn + j * 16 + fr;
                    C[(size_t)row * N + col] = f2bf(acc[i][j][rr]);
                }
    } else {
        // ---------------- gate path (3-pass split-bf16, 64x64 tile, 4 waves of 32x32) ----------
        const int K = 1024, N = 256;
        const int g = blockIdx.x - 640;                // 0..255
        const int m0 = (g >> 2) * 64, n0 = (g & 3) * 64;
        const int wm = (wave >> 1) * 32, wn = (wave & 1) * 32;
        const unsigned short* src = (wave == 0) ? A : (wave == 1) ? Al : (wave == 2) ? Bh2 : Bl2;
        const int brow = (wave >= 2) ? n0 : m0;

        f32x4 acc[2][2];
        #pragma unroll
        for (int i = 0; i < 2; ++i)
            #pragma unroll
            for (int j = 0; j < 2; ++j) acc[i][j] = (f32x4)0.f;

        for (int k0 = 0; k0 < K; k0 += 32) {
            __syncthreads();
            #pragma unroll
            for (int i = 0; i < 4; ++i)
                gload16(src + (size_t)(brow + i * 16 + grow) * K + k0 + gcol,
                        S + wave * 2048 + i * 512);
            __syncthreads();
            bf16x8 ah[2], al[2], bh[2], bl[2];
            #pragma unroll
            for (int t = 0; t < 2; ++t) {
                ah[t] = *(const bf16x8*)(S +        (wm + t * 16 + fr) * 32 + fg * 8);
                al[t] = *(const bf16x8*)(S + 2048 + (wm + t * 16 + fr) * 32 + fg * 8);
                bh[t] = *(const bf16x8*)(S + 4096 + (wn + t * 16 + fr) * 32 + fg * 8);
                bl[t] = *(const bf16x8*)(S + 6144 + (wn + t * 16 + fr) * 32 + fg * 8);
            }
            #pragma unroll
            for (int i = 0; i < 2; ++i)
                #pragma unroll
                for (int j = 0; j < 2; ++j) {
                    acc[i][j] = __builtin_amdgcn_mfma_f32_16x16x32_bf16(ah[i], bh[j], acc[i][j], 0, 0, 0);
                    acc[i][j] = __builtin_amdgcn_mfma_f32_16x16x32_bf16(ah[i], bl[j], acc[i][j], 0, 0, 0);
                    acc[i][j] = __builtin_amdgcn_mfma_f32_16x16x32_bf16(al[i], bh[j], acc[i][j], 0, 0, 0);
                }
        }
        #pragma unroll
        for (int i = 0; i < 2; ++i)
            #pragma unroll
            for (int j = 0; j < 2; ++j)
                #pragma unroll
                for (int rr = 0; rr < 4; ++rr) {
                    int row = m0 + wm + i * 16 + fg * 4 + rr;
                    int col = n0 + wn + j * 16 + fr;
                    Gf[(size_t)row * N + col] = acc[i][j][rr];
                }
    }
}

// ---------------- split-bf16 3-pass MFMA GEMM, fp32 out (final projection, swizzled) ----------------
__global__ __launch_bounds__(256)
void mfma_gemm3(const unsigned short* __restrict__ Ah, const unsigned short* __restrict__ Al,
                const unsigned short* __restrict__ Bh, const unsigned short* __restrict__ Bl,
                float* __restrict__ C)
{
    const int Kc = 512, N = 1024;
    __shared__ __align__(16) unsigned short Ash[128 * 32];
    __shared__ __align__(16) unsigned short Asl[128 * 32];
    __shared__ __align__(16) unsigned short Bsh[128 * 32];
    __shared__ __align__(16) unsigned short Bsl[128 * 32];
    const int o = blockIdx.x;                       // 256 blocks
    const int virt = (o & 7) * 32 + (o >> 3);
    const int bx = virt & 7, by = virt >> 3;
    const int tid = threadIdx.x;
    const int lane = tid & 63, wave = tid >> 6;
    const int m0 = by * 128, n0 = bx * 128;
    const int wm = (wave >> 1) * 64, wn = (wave & 1) * 64;
    const int fr = lane & 15, fg = lane >> 4;
    const int grow = lane >> 2, gcol = (lane & 3) * 8;

    f32x4 acc[4][4];
    #pragma unroll
    for (int i = 0; i < 4; ++i)
        #pragma unroll
        for (int j = 0; j < 4; ++j) acc[i][j] = (f32x4)0.f;

    for (int k0 = 0; k0 < Kc; k0 += 32) {
        __syncthreads();
        const size_t roff  = (size_t)(m0 + wave * 32 + grow) * Kc + k0 + gcol;
        const size_t roffB = (size_t)(n0 + wave * 32 + grow) * Kc + k0 + gcol;
        gload16(Ah + roff,             Ash + wave * 1024);
        gload16(Ah + roff + 16 * Kc,   Ash + wave * 1024 + 512);
        gload16(Al + roff,             Asl + wave * 1024);
        gload16(Al + roff + 16 * Kc,   Asl + wave * 1024 + 512);
        gload16(Bh + roffB,            Bsh + wave * 1024);
        gload16(Bh + roffB + 16 * Kc,  Bsh + wave * 1024 + 512);
        gload16(Bl + roffB,            Bsl + wave * 1024);
        gload16(Bl + roffB + 16 * Kc,  Bsl + wave * 1024 + 512);
        __syncthreads();
        bf16x8 ah[4], al[4], bh[4], bl[4];
        #pragma unroll
        for (int t = 0; t < 4; ++t) {
            ah[t] = *(const bf16x8*)(Ash + (wm + t * 16 + fr) * 32 + fg * 8);
            al[t] = *(const bf16x8*)(Asl + (wm + t * 16 + fr) * 32 + fg * 8);
            bh[t] = *(const bf16x8*)(Bsh + (wn + t * 16 + fr) * 32 + fg * 8);
            bl[t] = *(const bf16x8*)(Bsl + (wn + t * 16 + fr) * 32 + fg * 8);
        }
        #pragma unroll
        for (int i = 0; i < 4; ++i)
            #pragma unroll
            for (int j = 0; j < 4; ++j) {
                acc[i][j] = __builtin_amdgcn_mfma_f32_16x16x32_bf16(ah[i], bh[j], acc[i][j], 0, 0, 0);
                acc[i][j] = __builtin_amdgcn_mfma_f32_16x16x32_bf16(ah[i], bl[j], acc[i][j], 0, 0, 0);
                acc[i][j] = __builtin_amdgcn_mfma_f32_16x16x32_bf16(al[i], bh[j], acc[i][j], 0, 0, 0);
            }
    }
    #pragma unroll
    for (int i = 0; i < 4; ++i)
        #pragma unroll
        for (int j = 0; j < 4; ++j)
            #pragma unroll
            for (int rr = 0; rr < 4; ++rr) {
                int row = m0 + wm + i * 16 + fg * 4 + rr;
                int col = n0 + wn + j * 16 + fr;
                C[(size_t)row * N + col] = acc[i][j][rr];
            }
}

// ---------------- top-2 + margin flagging ----------------
__global__ __launch_bounds__(256)
void gate_topk2(const float* __restrict__ Gf,
                float2* __restrict__ wv, u32* __restrict__ selv, u32* __restrict__ selo,
                u32* __restrict__ flags)
{
    int item = blockIdx.x * 256 + threadIdx.x;   // < 65536
    int bt = item >> 4, h = item & 15;
    const float* g = Gf + (size_t)bt * 256 + h * NE;
    float b1 = -1e30f, b2 = -1e30f, b3 = -1e30f; int e1 = 0, e2 = 0;
    #pragma unroll
    for (int e = 0; e < NE; ++e) {
        float v = g[e];
        if (v > b1)      { b3 = b2; b2 = b1; e2 = e1; b1 = v; e1 = e; }
        else if (v > b2) { b3 = b2; b2 = v;  e2 = e; }
        else if (v > b3) { b3 = v; }
    }
    wv[item] = make_float2(1.f / (1.f + __expf(-b1)), 1.f / (1.f + __expf(-b2)));
    selv[item] = (u32)e1 | ((u32)e2 << 4);
    if (b2 - b3 < GTAU) {
        u32 p = atomicAdd(flags, 1u);
        if (p < MAXFLAG) flags[1 + p] = (u32)item;
    }
    const float* go = g + 128;
    float o1 = -1e30f, o2 = -1e30f, o3 = -1e30f; int f1 = 0, f2 = 0;
    #pragma unroll
    for (int e = 0; e < NE; ++e) {
        float v = go[e];
        if (v > o1)      { o3 = o2; o2 = o1; f2 = f1; o1 = v; f1 = e; }
        else if (v > o2) { o3 = o2; o2 = v;  f2 = e; }
        else if (v > o3) { o3 = v; }
    }
    selo[item] = (1u << f1) | (1u << f2);
    if (o2 - o3 < GTAU) {
        u32 p = atomicAdd(flags, 1u);
        if (p < MAXFLAG) flags[1 + p] = (u32)item | 0x10000u;
    }
}

// ---------------- fp64 fix-up for flagged near-tie items (one wave per record) ----------------
__global__ __launch_bounds__(256)
void gate_fix(const float* __restrict__ x, const float* __restrict__ Ws,
              const float* __restrict__ Wd, const u32* __restrict__ flags,
              float2* __restrict__ wv, u32* __restrict__ selv, u32* __restrict__ selo)
{
    u32 nf = flags[0]; if (nf > MAXFLAG) nf = MAXFLAG;
    int gw = (blockIdx.x * 256 + threadIdx.x) >> 6;
    int lane = threadIdx.x & 63;
    int nwaves = gridDim.x * 4;
    for (u32 w = gw; w < nf; w += nwaves) {
        u32 rec = flags[1 + w];
        int item = rec & 0xffff, which = rec >> 16;
        int bt = item >> 4, h = item & 15;
        const float* W = (which ? Wd : Ws) + (size_t)h * NE * MDIM + lane * 16;
        const float* xr = x + (size_t)bt * MDIM + lane * 16;
        double g[8];
        #pragma unroll
        for (int e = 0; e < 8; ++e) {
            double s = 0.0;
            #pragma unroll
            for (int c = 0; c < 16; ++c)
                s += (double)xr[c] * (double)W[(size_t)e * MDIM + c];
            g[e] = s;
        }
        #pragma unroll
        for (int off = 32; off; off >>= 1)
            #pragma unroll
            for (int e = 0; e < 8; ++e)
                g[e] += __shfl_xor(g[e], off, 64);
        if (lane == 0) {
            double b1 = -1e300, b2 = -1e300; int i1 = 0, i2 = 0;
            #pragma unroll
            for (int e = 0; e < 8; ++e) {
                double v = g[e];
                if (v > b1)      { b2 = b1; i2 = i1; b1 = v; i1 = e; }
                else if (v > b2) { b2 = v;  i2 = e; }
            }
            if (which == 0) {
                wv[item] = make_float2(1.f / (1.f + __expf(-(float)b1)),
                                       1.f / (1.f + __expf(-(float)b2)));
                selv[item] = (u32)i1 | ((u32)i2 << 4);
            } else {
                selo[item] = (1u << i1) | (1u << i2);
            }
        }
    }
}

// ---------------- V mix + transpose, LDS-staged: Vtg[b][h][d][t] ----------------
#define VTP 72   // LDS row stride (bf16 elems), 144 B, 16B-aligned
__global__ __launch_bounds__(256)
void vtrans(const unsigned short* __restrict__ QKVb, const float2* __restrict__ wv,
            const u32* __restrict__ selv, unsigned short* __restrict__ Vtg)
{
    __shared__ __align__(16) unsigned short Ls[256 * VTP];
    const int vid = blockIdx.x;              // 0..255
    const int xcd = vid & 7, local = vid >> 3;
    const int virt = xcd * 32 + local;       // bijective XCD-chunked remap
    const int b = virt >> 7, rem = virt & 127;
    const int tblk = rem >> 4, h = rem & 15;
    const int tid = threadIdx.x;

    // phase 1: one thread per t — mix the 2 selected experts, vector loads
    {
        const int bt = b * TSEQ + tblk * 256 + tid;
        u32 s = selv[bt * 16 + h];
        float2 w = wv[bt * 16 + h];
        int e1 = s & 15, e2 = (s >> 4) & 15;
        const unsigned short* pv = QKVb + (size_t)bt * LDQKV + 2048;
        #pragma unroll
        for (int c = 0; c < 8; ++c) {
            uint4 a  = *(const uint4*)(pv + e1 * 64 + c * 8);
            uint4 bb = *(const uint4*)(pv + e2 * 64 + c * 8);
            unsigned short ea[8], eb[8], eo[8];
            *(uint4*)ea = a; *(uint4*)eb = bb;
            #pragma unroll
            for (int j = 0; j < 8; ++j)
                eo[j] = f2bf(w.x * bf2f(ea[j]) + w.y * bf2f(eb[j]));
            *(uint4*)(Ls + tid * VTP + c * 8) = *(const uint4*)eo;
        }
    }
    __syncthreads();
    // phase 2: transpose out of LDS — lane = d (conflict-free broadcast pairs)
    {
        const int d = tid & 63, outer = tid >> 6;
        const size_t vrow = ((size_t)((b * NH + h) * DHD + d)) * TSEQ + tblk * 256;
        #pragma unroll
        for (int c8 = 0; c8 < 8; ++c8) {
            int t0 = (outer * 8 + c8) * 8;
            unsigned short o[8];
            #pragma unroll
            for (int j = 0; j < 8; ++j)
                o[j] = Ls[(t0 + j) * VTP + d];
            *(uint4*)(Vtg + vrow + t0) = *(const uint4*)o;
        }
    }
}

// ---------------- attn: swapped-QK 32x32 MFMA, in-register P, fixed-max softmax ----------------
// flat grid 1024, XCD-swizzled: each XCD owns 8 (b,h,split) groups x 16 q-blocks
#define SPA 72   // LDS row stride (bf16) = 144 B
#define MFMA32(A,B,C) __builtin_amdgcn_mfma_f32_32x32x16_bf16(A, B, C, 0, 0, 0)
__global__ __launch_bounds__(256)
void attn_mfma(const unsigned short* __restrict__ QKVb,
               const unsigned short* __restrict__ Vtg,
               float* __restrict__ Op0, float* __restrict__ Op1,
               float* __restrict__ lp)
{
    __shared__ __align__(16) unsigned short Ks[64 * SPA];
    __shared__ __align__(16) unsigned short Vt[64 * SPA];   // V^T: rows=d, cols=key
    const int vid = blockIdx.x;                  // 0..1023
    const int xcd = vid & 7, sl = vid >> 3;      // sl 0..127
    const int grp = xcd * 8 + (sl >> 4);         // 0..63 (b,h,split group)
    const int q0  = (sl & 15) * 128;
    const int h   = grp & 15;
    const int z   = grp >> 4;                    // 0..3
    const int b = z >> 1, split = z & 1;
    const int tid = threadIdx.x;
    const int lane = tid & 63, wq = tid >> 6;
    const int ql = lane & 31;
    const int hi = lane >> 5;
    const size_t base_q = ((size_t)b * TSEQ) * LDQKV + h * DHD;
    const size_t base_k = base_q + 1024;
    const size_t base_v = ((size_t)(b * NH + h) * DHD) * TSEQ;
    const int k00 = split * 1024;

    const int qrow = q0 + wq * 32 + ql;
    bf16x8 qa[4];
    #pragma unroll
    for (int t = 0; t < 4; ++t)
        qa[t] = *(const bf16x8*)(QKVb + base_q + (size_t)qrow * LDQKV + t * 16 + hi * 8);

    f32x16 o0 = (f32x16)0.f, o1 = (f32x16)0.f;
    float l_lane = 0.f;

    const int srow = tid >> 2, scol = (tid & 3) * 8;
    uint4 kr0 = *(const uint4*)(QKVb + base_k + (size_t)(k00 + srow) * LDQKV + scol);
    uint4 kr1 = *(const uint4*)(QKVb + base_k + (size_t)(k00 + srow) * LDQKV + scol + 32);
    uint4 vr0 = *(const uint4*)(Vtg + base_v + (size_t)srow * TSEQ + k00 + scol);
    uint4 vr1 = *(const uint4*)(Vtg + base_v + (size_t)srow * TSEQ + k00 + scol + 32);

    const int NT = 1024 / 64;
    for (int kb = 0; kb < NT; ++kb) {
        __syncthreads();
        *(uint4*)(Ks + srow * SPA + scol)      = kr0;
        *(uint4*)(Ks + srow * SPA + scol + 32) = kr1;
        *(uint4*)(Vt + srow * SPA + scol)      = vr0;
        *(uint4*)(Vt + srow * SPA + scol + 32) = vr1;
        __syncthreads();
        if (kb + 1 < NT) {
            const size_t gk = base_k + (size_t)(k00 + (kb + 1) * 64 + srow) * LDQKV + scol;
            const size_t gv = base_v + (size_t)srow * TSEQ + k00 + (kb + 1) * 64 + scol;
            kr0 = *(const uint4*)(QKVb + gk);
            kr1 = *(const uint4*)(QKVb + gk + 32);
            vr0 = *(const uint4*)(Vtg + gv);
            vr1 = *(const uint4*)(Vtg + gv + 32);
        }
        f32x16 s0 = (f32x16)0.f, s1 = (f32x16)0.f;
        #pragma unroll
        for (int t = 0; t < 4; ++t) {
            bf16x8 k0 = *(const bf16x8*)(Ks + ql * SPA + t * 16 + hi * 8);
            bf16x8 k1 = *(const bf16x8*)(Ks + (32 + ql) * SPA + t * 16 + hi * 8);
            s0 = MFMA32(k0, qa[t], s0);
            s1 = MFMA32(k1, qa[t], s1);
        }
        float ls0 = 0.f, ls1 = 0.f;
        u32 w[8];
        #pragma unroll
        for (int r = 0; r < 16; r += 2) {
            float pa = fexp2(s0[r]), pb = fexp2(s0[r + 1]);
            s0[r] = pa; s0[r + 1] = pb;
            ls0 += pa; ls1 += pb;
        }
        #pragma unroll
        for (int m = 0; m < 8; ++m) w[m] = cvtpk(s0[2*m], s0[2*m+1]);
        #pragma unroll
        for (int tl = 0; tl < 2; ++tl) {
            const int mb = 4 * tl, tk = tl;
            u32 send0 = hi ? w[mb]   : w[mb+2];
            u32 send1 = hi ? w[mb+1] : w[mb+3];
            u32 r0 = (u32)__shfl_xor((int)send0, 32, 64);
            u32 r1 = (u32)__shfl_xor((int)send1, 32, 64);
            union { u32 uw[4]; bf16x8 v; } pu;
            pu.uw[0] = hi ? r0 : w[mb];
            pu.uw[1] = hi ? r1 : w[mb+1];
            pu.uw[2] = hi ? w[mb+2] : r0;
            pu.uw[3] = hi ? w[mb+3] : r1;
            bf16x8 v0 = *(const bf16x8*)(Vt + ql * SPA + tk * 16 + hi * 8);
            bf16x8 v1 = *(const bf16x8*)(Vt + (32 + ql) * SPA + tk * 16 + hi * 8);
            o0 = MFMA32(pu.v, v0, o0);
            o1 = MFMA32(pu.v, v1, o1);
        }
        #pragma unroll
        for (int r = 0; r < 16; r += 2) {
            float pa = fexp2(s1[r]), pb = fexp2(s1[r + 1]);
            s1[r] = pa; s1[r + 1] = pb;
            ls0 += pa; ls1 += pb;
        }
        #pragma unroll
        for (int m = 0; m < 8; ++m) w[m] = cvtpk(s1[2*m], s1[2*m+1]);
        #pragma unroll
        for (int tl = 0; tl < 2; ++tl) {
            const int mb = 4 * tl, tk = 2 + tl;
            u32 send0 = hi ? w[mb]   : w[mb+2];
            u32 send1 = hi ? w[mb+1] : w[mb+3];
            u32 r0 = (u32)__shfl_xor((int)send0, 32, 64);
            u32 r1 = (u32)__shfl_xor((int)send1, 32, 64);
            union { u32 uw[4]; bf16x8 v; } pu;
            pu.uw[0] = hi ? r0 : w[mb];
            pu.uw[1] = hi ? r1 : w[mb+1];
            pu.uw[2] = hi ? w[mb+2] : r0;
            pu.uw[3] = hi ? w[mb+3] : r1;
            bf16x8 v0 = *(const bf16x8*)(Vt + ql * SPA + tk * 16 + hi * 8);
            bf16x8 v1 = *(const bf16x8*)(Vt + (32 + ql) * SPA + tk * 16 + hi * 8);
            o0 = MFMA32(pu.v, v0, o0);
            o1 = MFMA32(pu.v, v1, o1);
        }
        l_lane += ls0 + ls1;
    }
    float l_tot = l_lane + __shfl_xor(l_lane, 32, 64);
    float* Op = split ? Op1 : Op0;
    const size_t ob = ((size_t)b * TSEQ) * MDIM + h * DHD;
    #pragma unroll
    for (int r = 0; r < 16; ++r) {
        int qr = q0 + wq * 32 + (r & 3) + 8 * (r >> 2) + 4 * hi;
        Op[ob + (size_t)qr * MDIM + ql]      = o0[r];
        Op[ob + (size_t)qr * MDIM + 32 + ql] = o1[r];
    }
    if (hi == 0)
        lp[(((size_t)split * NB + b) * NH + h) * TSEQ + q0 + wq * 32 + ql] = l_tot;
}

// ---------------- U: per-(bt,d) — att[h] once, distribute to 8 experts, bf16 split -------------
__global__ __launch_bounds__(256)
void compute_U2(const float* __restrict__ Op0, const float* __restrict__ Op1,
                const float* __restrict__ lp, const u32* __restrict__ selo,
                unsigned short* __restrict__ Uh, unsigned short* __restrict__ Ul)
{
    int t = blockIdx.x * 256 + threadIdx.x;      // < MBT*64 = 262144
    int bt = t >> 6, d = t & 63;
    int b = bt >> 11, ts = bt & 2047;
    float att[16];
    #pragma unroll
    for (int h = 0; h < NH; ++h) {
        size_t li = ((size_t)b * NH + h) * TSEQ + ts;
        float l = lp[li] + lp[li + (size_t)NB * NH * TSEQ];
        size_t oi = (size_t)bt * MDIM + h * DHD + d;
        att[h] = (Op0[oi] + Op1[oi]) / l;
    }
    const u32* sp = selo + bt * 16;
    u32 m[16];
    #pragma unroll
    for (int h = 0; h < NH; ++h) m[h] = sp[h];
    #pragma unroll
    for (int e = 0; e < NE; ++e) {
        float sum = 0.f;
        #pragma unroll
        for (int h = 0; h < NH; ++h)
            if (m[h] & (1u << e)) sum += att[h];
        int idx = bt * 512 + e * 64 + d;
        unsigned short hi16 = f2bf(sum);
        Uh[idx] = hi16;
        Ul[idx] = f2bf(sum - bf2f(hi16));
    }
}

extern "C" void kernel_launch(void* const* d_in, const int* in_sizes, int n_in,
                              void* d_out, int out_size, void* d_ws, size_t ws_size,
                              hipStream_t stream)
{
    const float* x  = (const float*)d_in[0];
    const float* Wq = (const float*)d_in[1];
    const float* Wk = (const float*)d_in[2];
    const float* Wv = (const float*)d_in[3];
    const float* Ws = (const float*)d_in[4];
    const float* Wd = (const float*)d_in[5];
    const float* Wo = (const float*)d_in[6];
    float* out = (float*)d_out;
    char* ws = (char*)d_ws;

    // region 0 (16.78 MB): [xb|Wqkvb] -> Op0 ; region @46137344 (16.78 MB): xbl -> Op1
    unsigned short* xb    = (unsigned short*)(ws);
    unsigned short* Wqkvb = (unsigned short*)(ws + 8388608);
    float*          Op0   = (float*)(ws);
    unsigned short* QKVb  = (unsigned short*)(ws + 16777216);   // 20.97 MB
    unsigned short* Vtg   = (unsigned short*)(ws + 37748736);   // 8.39 MB
    unsigned short* xbl   = (unsigned short*)(ws + 46137344);   // 8.39 MB (dead before attn)
    float*          Op1   = (float*)(ws + 46137344);            // 16.78 MB
    float*          lp    = (float*)(ws + 62914560);            // 0.52 MB
    unsigned short* WoTh  = (unsigned short*)(ws + 63438848);   // 1.05 MB
    unsigned short* WoTl  = (unsigned short*)(ws + 64487424);   // 1.05 MB
    float*          Gf    = (float*)(ws + 65536000);            // 4.19 MB (dead before Uh)
    unsigned short* Uh    = (unsigned short*)(ws + 65536000);   // 4.19 MB
    u32*            flags = (u32*)(ws + 69730304);              // 64 KB (dead before Ul)
    unsigned short* Ul    = (unsigned short*)(ws + 69730304);   // 4.19 MB
    float2*         wvp   = (float2*)(ws + 73924608);           // 0.52 MB
    u32*            selv  = (u32*)(ws + 74448896);              // 0.26 MB
    u32*            selo  = (u32*)(ws + 74711040);              // 0.26 MB
    unsigned short* Wsdh  = (unsigned short*)(ws + 74973184);   // 0.52 MB
    unsigned short* Wsdl  = (unsigned short*)(ws + 75497472);   // 0.52 MB

    dim3 blk(256);
    prep<<<5504, blk, 0, stream>>>(x, Wq, Wk, Wv, Ws, Wd, Wo,
                                   xb, xbl, Wqkvb, Wsdh, Wsdl, WoTh, WoTl, flags);

    // merged QKV projection (640 blocks) + gate GEMM (256 blocks): gate fills QKV's tail
    qkvgate<<<896, blk, 0, stream>>>(xb, Wqkvb, QKVb, xbl, Wsdh, Wsdl, Gf);

    gate_topk2<<<256, blk, 0, stream>>>(Gf, wvp, selv, selo, flags);
    gate_fix<<<128, blk, 0, stream>>>(x, Ws, Wd, flags, wvp, selv, selo);

    vtrans<<<256, blk, 0, stream>>>(QKVb, wvp, selv, Vtg);

    attn_mfma<<<1024, blk, 0, stream>>>(QKVb, Vtg, Op0, Op1, lp);

    compute_U2<<<1024, blk, 0, stream>>>(Op0, Op1, lp, selo, Uh, Ul);
    mfma_gemm3<<<256, blk, 0, stream>>>(Uh, Ul, WoTh, WoTl, out);
}

// Round 15
// 156.525 us; speedup vs baseline: 1.2869x; 1.0709x over previous
//
#include <hip/hip_runtime.h>
#include <math.h>

#define TSEQ 2048
#define NB   2
#define NH   16
#define NE   8
#define DHD  64
#define MDIM 1024
#define MBT  4096   // NB*TSEQ
#define LDQKV 2560  // Q(1024) | K(1024) | V-experts(512)
#define GTAU 1e-3f  // margin threshold for fp64 gate fix-up
#define MAXFLAG 16384

typedef __attribute__((ext_vector_type(8))) short bf16x8;
typedef __attribute__((ext_vector_type(4))) float f32x4;
typedef __attribute__((ext_vector_type(16))) float f32x16;
typedef unsigned int u32;

__device__ inline unsigned short f2bf(float f) {
    union { float f; unsigned u; } v; v.f = f;
    unsigned r = v.u + 0x7fff + ((v.u >> 16) & 1);
    return (unsigned short)(r >> 16);
}
__device__ inline float bf2f(unsigned short h) {
    union { unsigned u; float f; } v; v.u = ((unsigned)h) << 16;
    return v.f;
}
__device__ inline u32 cvtpk(float a, float b) {   // low16=bf16(a), high16=bf16(b)
    u32 r;
    asm("v_cvt_pk_bf16_f32 %0, %1, %2" : "=v"(r) : "v"(a), "v"(b));
    return r;
}
// single-instruction exp2 (inputs bounded |x|<~8 here; no denorm/range handling needed)
__device__ inline float fexp2(float x) {
#if __has_builtin(__builtin_amdgcn_exp2f)
    return __builtin_amdgcn_exp2f(x);
#else
    float r; asm("v_exp_f32 %0, %1" : "=v"(r) : "v"(x)); return r;
#endif
}

// async global->LDS, 16B per lane (dst wave-uniform base + lane*16)
__device__ inline void gload16(const void* g, void* l) {
    __builtin_amdgcn_global_load_lds((const __attribute__((address_space(1))) u32*)g,
                                     (__attribute__((address_space(3))) u32*)l, 16, 0, 0);
}

__device__ inline void cast8s(const float* __restrict__ in, unsigned short* __restrict__ out,
                              int i, float sc) {
    const float4* p = (const float4*)(in + (size_t)i * 8);
    float4 a = p[0], b = p[1];
    unsigned short o[8] = { f2bf(a.x*sc), f2bf(a.y*sc), f2bf(a.z*sc), f2bf(a.w*sc),
                            f2bf(b.x*sc), f2bf(b.y*sc), f2bf(b.z*sc), f2bf(b.w*sc) };
    *(uint4*)(out + (size_t)i * 8) = *(const uint4*)o;
}
__device__ inline void cast8hl(const float* __restrict__ in,
                               unsigned short* __restrict__ oh, unsigned short* __restrict__ ol,
                               int i) {
    const float4* p = (const float4*)(in + (size_t)i * 8);
    float4 a = p[0], b = p[1];
    float f[8] = { a.x, a.y, a.z, a.w, b.x, b.y, b.z, b.w };
    unsigned short h8[8], l8[8];
    #pragma unroll
    for (int j = 0; j < 8; ++j) {
        unsigned short hi = f2bf(f[j]);
        h8[j] = hi;
        l8[j] = f2bf(f[j] - bf2f(hi));
    }
    *(uint4*)(oh + (size_t)i * 8) = *(const uint4*)h8;
    *(uint4*)(ol + (size_t)i * 8) = *(const uint4*)l8;
}

// ---------------- fused prep (casts + Wsd split + Wo repack/split + flag reset) ----------------
__global__ __launch_bounds__(256)
void prep(const float* __restrict__ x,  const float* __restrict__ Wq,
          const float* __restrict__ Wk, const float* __restrict__ Wv,
          const float* __restrict__ Ws, const float* __restrict__ Wd,
          const float* __restrict__ Wo,
          unsigned short* __restrict__ xb, unsigned short* __restrict__ xbl,
          unsigned short* __restrict__ Wqkvb,
          unsigned short* __restrict__ Wsdh, unsigned short* __restrict__ Wsdl,
          unsigned short* __restrict__ WoTh, unsigned short* __restrict__ WoTl,
          u32* __restrict__ flags)
{
    const float qsc = 0.125f * 1.4426950408889634f;  // fold scale*log2(e) into Q
    int b = blockIdx.x, tid = threadIdx.x;
    if (b == 0 && tid == 0) flags[0] = 0;
    if (b < 2048)      cast8hl(x, xb, xbl,          (b        ) * 256 + tid);
    else if (b < 2560) cast8s(Wq, Wqkvb,            (b - 2048) * 256 + tid, qsc);
    else if (b < 3072) cast8s(Wk, Wqkvb + 1048576,  (b - 2560) * 256 + tid, 1.f);
    else if (b < 3328) cast8s(Wv, Wqkvb + 2097152,  (b - 3072) * 256 + tid, 1.f);
    else if (b < 3456) {
        int i = (b - 3328) * 256 + tid;   // 0..32767; 8 elems each of Ws|Wd
        const float* src = (i < 16384) ? Ws + (size_t)i * 8 : Wd + (size_t)(i - 16384) * 8;
        const float4* p = (const float4*)src;
        float4 a = p[0], bq = p[1];
        float f8[8] = { a.x, a.y, a.z, a.w, bq.x, bq.y, bq.z, bq.w };
        unsigned short h8[8], l8[8];
        #pragma unroll
        for (int j = 0; j < 8; ++j) {
            unsigned short hi = f2bf(f8[j]);
            h8[j] = hi;
            l8[j] = f2bf(f8[j] - bf2f(hi));
        }
        *(uint4*)(Wsdh + (size_t)i * 8) = *(const uint4*)h8;
        *(uint4*)(Wsdl + (size_t)i * 8) = *(const uint4*)l8;
    } else {
        int idx = (b - 3456) * 256 + tid;  // < 524288
        int f = idx >> 9, ed = idx & 511, e = ed >> 6, d = ed & 63;
        float v = Wo[(size_t)e * (MDIM * DHD) + (size_t)f * DHD + d];
        unsigned short hi = f2bf(v);
        WoTh[idx] = hi;
        WoTl[idx] = f2bf(v - bf2f(hi));
    }
}

// ---------------- merged QKV GEMM (640 blocks) + gate GEMM w/ fused top-k (256 blocks) --------
// blockIdx < 640: C[4096,2560] = xb * Wqkv^T (bf16 out, XCD-swizzled)
// blockIdx >= 640: gate tile (xb+xbl)*(Wsdh+Wsdl)^T -> LDS -> top-2/margin epilogue (no Gf)
__global__ __launch_bounds__(256)
void qkvgate(const unsigned short* __restrict__ A,
             const unsigned short* __restrict__ B,
             unsigned short* __restrict__ C,
             const unsigned short* __restrict__ Al,
             const unsigned short* __restrict__ Bh2, const unsigned short* __restrict__ Bl2,
             float2* __restrict__ wv, u32* __restrict__ selv, u32* __restrict__ selo,
             u32* __restrict__ flags)
{
    __shared__ __align__(16) unsigned short S[8192];   // 16 KB, unioned between paths/phases
    const int tid = threadIdx.x;
    const int lane = tid & 63, wave = tid >> 6;
    const int fr = lane & 15, fg = lane >> 4;
    const int grow = lane >> 2, gcol = (lane & 3) * 8;

    if (blockIdx.x < 640) {
        // ---------------- QKV path ----------------
        const int K = 1024, N = LDQKV, nbx = 20;
        unsigned short* As = S;            // 128*32
        unsigned short* Bs = S + 4096;     // 128*32
        const int o = blockIdx.x;
        const int virt = (o & 7) * 80 + (o >> 3);      // bijective XCD-chunked remap (640/8=80)
        const int bx = virt % nbx, by = virt / nbx;
        const int m0 = by * 128, n0 = bx * 128;
        const int wm = (wave >> 1) * 64, wn = (wave & 1) * 64;

        f32x4 acc[4][4];
        #pragma unroll
        for (int i = 0; i < 4; ++i)
            #pragma unroll
            for (int j = 0; j < 4; ++j) acc[i][j] = (f32x4)0.f;

        for (int k0 = 0; k0 < K; k0 += 32) {
            __syncthreads();
            const unsigned short* gA = A + (size_t)(m0 + wave * 32 + grow) * K + k0 + gcol;
            gload16(gA,                  As + wave * 1024);
            gload16(gA + (size_t)16 * K, As + wave * 1024 + 512);
            const unsigned short* gB = B + (size_t)(n0 + wave * 32 + grow) * K + k0 + gcol;
            gload16(gB,                  Bs + wave * 1024);
            gload16(gB + (size_t)16 * K, Bs + wave * 1024 + 512);
            __syncthreads();
            bf16x8 af[4], bfr[4];
            #pragma unroll
            for (int t = 0; t < 4; ++t) {
                af[t]  = *(const bf16x8*)(As + (wm + t * 16 + fr) * 32 + fg * 8);
                bfr[t] = *(const bf16x8*)(Bs + (wn + t * 16 + fr) * 32 + fg * 8);
            }
            #pragma unroll
            for (int i = 0; i < 4; ++i)
                #pragma unroll
                for (int j = 0; j < 4; ++j)
                    acc[i][j] = __builtin_amdgcn_mfma_f32_16x16x32_bf16(af[i], bfr[j], acc[i][j], 0, 0, 0);
        }
        #pragma unroll
        for (int i = 0; i < 4; ++i)
            #pragma unroll
            for (int j = 0; j < 4; ++j)
                #pragma unroll
                for (int rr = 0; rr < 4; ++rr) {
                    int row = m0 + wm + i * 16 + fg * 4 + rr;
                    int col = n0 + wn + j * 16 + fr;
                    C[(size_t)row * N + col] = f2bf(acc[i][j][rr]);
                }
    } else {
        // ---------------- gate path (3-pass split-bf16, 64x64 tile, 4 waves of 32x32) ----------
        const int K = 1024;
        const int g = blockIdx.x - 640;                // 0..255
        const int m0 = (g >> 2) * 64, n0 = (g & 3) * 64;
        const int wm = (wave >> 1) * 32, wn = (wave & 1) * 32;
        const unsigned short* src = (wave == 0) ? A : (wave == 1) ? Al : (wave == 2) ? Bh2 : Bl2;
        const int brow = (wave >= 2) ? n0 : m0;

        f32x4 acc[2][2];
        #pragma unroll
        for (int i = 0; i < 2; ++i)
            #pragma unroll
            for (int j = 0; j < 2; ++j) acc[i][j] = (f32x4)0.f;

        for (int k0 = 0; k0 < K; k0 += 32) {
            __syncthreads();
            #pragma unroll
            for (int i = 0; i < 4; ++i)
                gload16(src + (size_t)(brow + i * 16 + grow) * K + k0 + gcol,
                        S + wave * 2048 + i * 512);
            __syncthreads();
            bf16x8 ah[2], al[2], bh[2], bl[2];
            #pragma unroll
            for (int t = 0; t < 2; ++t) {
                ah[t] = *(const bf16x8*)(S +        (wm + t * 16 + fr) * 32 + fg * 8);
                al[t] = *(const bf16x8*)(S + 2048 + (wm + t * 16 + fr) * 32 + fg * 8);
                bh[t] = *(const bf16x8*)(S + 4096 + (wn + t * 16 + fr) * 32 + fg * 8);
                bl[t] = *(const bf16x8*)(S + 6144 + (wn + t * 16 + fr) * 32 + fg * 8);
            }
            #pragma unroll
            for (int i = 0; i < 2; ++i)
                #pragma unroll
                for (int j = 0; j < 2; ++j) {
                    acc[i][j] = __builtin_amdgcn_mfma_f32_16x16x32_bf16(ah[i], bh[j], acc[i][j], 0, 0, 0);
                    acc[i][j] = __builtin_amdgcn_mfma_f32_16x16x32_bf16(ah[i], bl[j], acc[i][j], 0, 0, 0);
                    acc[i][j] = __builtin_amdgcn_mfma_f32_16x16x32_bf16(al[i], bh[j], acc[i][j], 0, 0, 0);
                }
        }
        // ---- fused top-k epilogue: spill 64x64 tile to LDS, then per-(bt,h) top-2/margin ----
        float* Tf = (float*)S;   // 64*64 f32 = 16 KB (exactly S)
        __syncthreads();         // all waves done reading staging from last k-step
        #pragma unroll
        for (int i = 0; i < 2; ++i)
            #pragma unroll
            for (int j = 0; j < 2; ++j)
                #pragma unroll
                for (int rr = 0; rr < 4; ++rr)
                    Tf[(wm + i * 16 + fg * 4 + rr) * 64 + wn + j * 16 + fr] = acc[i][j][rr];
        __syncthreads();
        const int type = (n0 >= 128);           // 0 = V gate, 1 = O gate
        const int hbase = (n0 & 127) >> 3;      // 0 or 8
        #pragma unroll
        for (int k = 0; k < 2; ++k) {
            int it = tid + k * 256;             // 512 items: 64 rows x 8 local-h
            int lr = it >> 3, lh = it & 7;
            int item = (m0 + lr) * 16 + hbase + lh;
            const float* gp = Tf + lr * 64 + lh * 8;
            float b1 = -1e30f, b2 = -1e30f, b3 = -1e30f; int e1 = 0, e2 = 0;
            #pragma unroll
            for (int e = 0; e < NE; ++e) {
                float v = gp[e];
                if (v > b1)      { b3 = b2; b2 = b1; e2 = e1; b1 = v; e1 = e; }
                else if (v > b2) { b3 = b2; b2 = v;  e2 = e; }
                else if (v > b3) { b3 = v; }
            }
            if (type == 0) {
                wv[item] = make_float2(1.f / (1.f + __expf(-b1)), 1.f / (1.f + __expf(-b2)));
                selv[item] = (u32)e1 | ((u32)e2 << 4);
                if (b2 - b3 < GTAU) {
                    u32 p = atomicAdd(flags, 1u);
                    if (p < MAXFLAG) flags[1 + p] = (u32)item;
                }
            } else {
                selo[item] = (1u << e1) | (1u << e2);
                if (b2 - b3 < GTAU) {
                    u32 p = atomicAdd(flags, 1u);
                    if (p < MAXFLAG) flags[1 + p] = (u32)item | 0x10000u;
                }
            }
        }
    }
}

// ---------------- split-bf16 3-pass MFMA GEMM, fp32 out (128x64 tiles, 512 blocks) ------------
__global__ __launch_bounds__(256)
void mfma_gemm3(const unsigned short* __restrict__ Ah, const unsigned short* __restrict__ Al,
                const unsigned short* __restrict__ Bh, const unsigned short* __restrict__ Bl,
                float* __restrict__ C)
{
    const int Kc = 512, N = 1024;
    __shared__ __align__(16) unsigned short Ash[128 * 32];
    __shared__ __align__(16) unsigned short Asl[128 * 32];
    __shared__ __align__(16) unsigned short Bsh[64 * 32];
    __shared__ __align__(16) unsigned short Bsl[64 * 32];
    const int o = blockIdx.x;                       // 512 blocks
    const int virt = (o & 7) * 64 + (o >> 3);       // bijective XCD-chunked remap
    const int bx = virt & 15, by = virt >> 4;
    const int tid = threadIdx.x;
    const int lane = tid & 63, wave = tid >> 6;
    const int m0 = by * 128, n0 = bx * 64;
    const int wm = (wave >> 1) * 64, wn = (wave & 1) * 32;
    const int fr = lane & 15, fg = lane >> 4;
    const int grow = lane >> 2, gcol = (lane & 3) * 8;

    f32x4 acc[4][2];
    #pragma unroll
    for (int i = 0; i < 4; ++i)
        #pragma unroll
        for (int j = 0; j < 2; ++j) acc[i][j] = (f32x4)0.f;

    for (int k0 = 0; k0 < Kc; k0 += 32) {
        __syncthreads();
        const size_t roff  = (size_t)(m0 + wave * 32 + grow) * Kc + k0 + gcol;
        const size_t roffB = (size_t)(n0 + wave * 16 + grow) * Kc + k0 + gcol;
        gload16(Ah + roff,             Ash + wave * 1024);
        gload16(Ah + roff + 16 * Kc,   Ash + wave * 1024 + 512);
        gload16(Al + roff,             Asl + wave * 1024);
        gload16(Al + roff + 16 * Kc,   Asl + wave * 1024 + 512);
        gload16(Bh + roffB,            Bsh + wave * 512);
        gload16(Bl + roffB,            Bsl + wave * 512);
        __syncthreads();
        bf16x8 ah[4], al[4], bh[2], bl[2];
        #pragma unroll
        for (int t = 0; t < 4; ++t) {
            ah[t] = *(const bf16x8*)(Ash + (wm + t * 16 + fr) * 32 + fg * 8);
            al[t] = *(const bf16x8*)(Asl + (wm + t * 16 + fr) * 32 + fg * 8);
        }
        #pragma unroll
        for (int t = 0; t < 2; ++t) {
            bh[t] = *(const bf16x8*)(Bsh + (wn + t * 16 + fr) * 32 + fg * 8);
            bl[t] = *(const bf16x8*)(Bsl + (wn + t * 16 + fr) * 32 + fg * 8);
        }
        #pragma unroll
        for (int i = 0; i < 4; ++i)
            #pragma unroll
            for (int j = 0; j < 2; ++j) {
                acc[i][j] = __builtin_amdgcn_mfma_f32_16x16x32_bf16(ah[i], bh[j], acc[i][j], 0, 0, 0);
                acc[i][j] = __builtin_amdgcn_mfma_f32_16x16x32_bf16(ah[i], bl[j], acc[i][j], 0, 0, 0);
                acc[i][j] = __builtin_amdgcn_mfma_f32_16x16x32_bf16(al[i], bh[j], acc[i][j], 0, 0, 0);
            }
    }
    #pragma unroll
    for (int i = 0; i < 4; ++i)
        #pragma unroll
        for (int j = 0; j < 2; ++j)
            #pragma unroll
            for (int rr = 0; rr < 4; ++rr) {
                int row = m0 + wm + i * 16 + fg * 4 + rr;
                int col = n0 + wn + j * 16 + fr;
                C[(size_t)row * N + col] = acc[i][j][rr];
            }
}

// ---------------- fp64 fix-up for flagged near-tie items (one wave per record) ----------------
__global__ __launch_bounds__(256)
void gate_fix(const float* __restrict__ x, const float* __restrict__ Ws,
              const float* __restrict__ Wd, const u32* __restrict__ flags,
              float2* __restrict__ wv, u32* __restrict__ selv, u32* __restrict__ selo)
{
    u32 nf = flags[0]; if (nf > MAXFLAG) nf = MAXFLAG;
    int gw = (blockIdx.x * 256 + threadIdx.x) >> 6;
    int lane = threadIdx.x & 63;
    int nwaves = gridDim.x * 4;
    for (u32 w = gw; w < nf; w += nwaves) {
        u32 rec = flags[1 + w];
        int item = rec & 0xffff, which = rec >> 16;
        int bt = item >> 4, h = item & 15;
        const float* W = (which ? Wd : Ws) + (size_t)h * NE * MDIM + lane * 16;
        const float* xr = x + (size_t)bt * MDIM + lane * 16;
        double g[8];
        #pragma unroll
        for (int e = 0; e < 8; ++e) {
            double s = 0.0;
            #pragma unroll
            for (int c = 0; c < 16; ++c)
                s += (double)xr[c] * (double)W[(size_t)e * MDIM + c];
            g[e] = s;
        }
        #pragma unroll
        for (int off = 32; off; off >>= 1)
            #pragma unroll
            for (int e = 0; e < 8; ++e)
                g[e] += __shfl_xor(g[e], off, 64);
        if (lane == 0) {
            double b1 = -1e300, b2 = -1e300; int i1 = 0, i2 = 0;
            #pragma unroll
            for (int e = 0; e < 8; ++e) {
                double v = g[e];
                if (v > b1)      { b2 = b1; i2 = i1; b1 = v; i1 = e; }
                else if (v > b2) { b2 = v;  i2 = e; }
            }
            if (which == 0) {
                wv[item] = make_float2(1.f / (1.f + __expf(-(float)b1)),
                                       1.f / (1.f + __expf(-(float)b2)));
                selv[item] = (u32)i1 | ((u32)i2 << 4);
            } else {
                selo[item] = (1u << i1) | (1u << i2);
            }
        }
    }
}

// ---------------- V mix + transpose, LDS-staged: Vtg[b][h][d][t] ----------------
#define VTP 72   // LDS row stride (bf16 elems), 144 B, 16B-aligned
__global__ __launch_bounds__(256)
void vtrans(const unsigned short* __restrict__ QKVb, const float2* __restrict__ wv,
            const u32* __restrict__ selv, unsigned short* __restrict__ Vtg)
{
    __shared__ __align__(16) unsigned short Ls[256 * VTP];
    const int vid = blockIdx.x;              // 0..255
    const int xcd = vid & 7, local = vid >> 3;
    const int virt = xcd * 32 + local;       // bijective XCD-chunked remap
    const int b = virt >> 7, rem = virt & 127;
    const int tblk = rem >> 4, h = rem & 15;
    const int tid = threadIdx.x;

    // phase 1: one thread per t — mix the 2 selected experts, vector loads
    {
        const int bt = b * TSEQ + tblk * 256 + tid;
        u32 s = selv[bt * 16 + h];
        float2 w = wv[bt * 16 + h];
        int e1 = s & 15, e2 = (s >> 4) & 15;
        const unsigned short* pv = QKVb + (size_t)bt * LDQKV + 2048;
        #pragma unroll
        for (int c = 0; c < 8; ++c) {
            uint4 a  = *(const uint4*)(pv + e1 * 64 + c * 8);
            uint4 bb = *(const uint4*)(pv + e2 * 64 + c * 8);
            unsigned short ea[8], eb[8], eo[8];
            *(uint4*)ea = a; *(uint4*)eb = bb;
            #pragma unroll
            for (int j = 0; j < 8; ++j)
                eo[j] = f2bf(w.x * bf2f(ea[j]) + w.y * bf2f(eb[j]));
            *(uint4*)(Ls + tid * VTP + c * 8) = *(const uint4*)eo;
        }
    }
    __syncthreads();
    // phase 2: transpose out of LDS — lane = d (conflict-free broadcast pairs)
    {
        const int d = tid & 63, outer = tid >> 6;
        const size_t vrow = ((size_t)((b * NH + h) * DHD + d)) * TSEQ + tblk * 256;
        #pragma unroll
        for (int c8 = 0; c8 < 8; ++c8) {
            int t0 = (outer * 8 + c8) * 8;
            unsigned short o[8];
            #pragma unroll
            for (int j = 0; j < 8; ++j)
                o[j] = Ls[(t0 + j) * VTP + d];
            *(uint4*)(Vtg + vrow + t0) = *(const uint4*)o;
        }
    }
}

// ---------------- attn: swapped-QK 32x32 MFMA, in-register P, fixed-max softmax ----------------
// flat grid 1024, XCD-swizzled: each XCD owns 8 (b,h,split) groups x 16 q-blocks
#define SPA 72   // LDS row stride (bf16) = 144 B
#define MFMA32(A,B,C) __builtin_amdgcn_mfma_f32_32x32x16_bf16(A, B, C, 0, 0, 0)
__global__ __launch_bounds__(256)
void attn_mfma(const unsigned short* __restrict__ QKVb,
               const unsigned short* __restrict__ Vtg,
               float* __restrict__ Op0, float* __restrict__ Op1,
               float* __restrict__ lp)
{
    __shared__ __align__(16) unsigned short Ks[64 * SPA];
    __shared__ __align__(16) unsigned short Vt[64 * SPA];   // V^T: rows=d, cols=key
    const int vid = blockIdx.x;                  // 0..1023
    const int xcd = vid & 7, sl = vid >> 3;      // sl 0..127
    const int grp = xcd * 8 + (sl >> 4);         // 0..63 (b,h,split group)
    const int q0  = (sl & 15) * 128;
    const int h   = grp & 15;
    const int z   = grp >> 4;                    // 0..3
    const int b = z >> 1, split = z & 1;
    const int tid = threadIdx.x;
    const int lane = tid & 63, wq = tid >> 6;
    const int ql = lane & 31;
    const int hi = lane >> 5;
    const size_t base_q = ((size_t)b * TSEQ) * LDQKV + h * DHD;
    const size_t base_k = base_q + 1024;
    const size_t base_v = ((size_t)(b * NH + h) * DHD) * TSEQ;
    const int k00 = split * 1024;

    const int qrow = q0 + wq * 32 + ql;
    bf16x8 qa[4];
    #pragma unroll
    for (int t = 0; t < 4; ++t)
        qa[t] = *(const bf16x8*)(QKVb + base_q + (size_t)qrow * LDQKV + t * 16 + hi * 8);

    f32x16 o0 = (f32x16)0.f, o1 = (f32x16)0.f;
    float l_lane = 0.f;

    const int srow = tid >> 2, scol = (tid & 3) * 8;
    uint4 kr0 = *(const uint4*)(QKVb + base_k + (size_t)(k00 + srow) * LDQKV + scol);
    uint4 kr1 = *(const uint4*)(QKVb + base_k + (size_t)(k00 + srow) * LDQKV + scol + 32);
    uint4 vr0 = *(const uint4*)(Vtg + base_v + (size_t)srow * TSEQ + k00 + scol);
    uint4 vr1 = *(const uint4*)(Vtg + base_v + (size_t)srow * TSEQ + k00 + scol + 32);

    const int NT = 1024 / 64;
    for (int kb = 0; kb < NT; ++kb) {
        __syncthreads();
        *(uint4*)(Ks + srow * SPA + scol)      = kr0;
        *(uint4*)(Ks + srow * SPA + scol + 32) = kr1;
        *(uint4*)(Vt + srow * SPA + scol)      = vr0;
        *(uint4*)(Vt + srow * SPA + scol + 32) = vr1;
        __syncthreads();
        if (kb + 1 < NT) {
            const size_t gk = base_k + (size_t)(k00 + (kb + 1) * 64 + srow) * LDQKV + scol;
            const size_t gv = base_v + (size_t)srow * TSEQ + k00 + (kb + 1) * 64 + scol;
            kr0 = *(const uint4*)(QKVb + gk);
            kr1 = *(const uint4*)(QKVb + gk + 32);
            vr0 = *(const uint4*)(Vtg + gv);
            vr1 = *(const uint4*)(Vtg + gv + 32);
        }
        f32x16 s0 = (f32x16)0.f, s1 = (f32x16)0.f;
        #pragma unroll
        for (int t = 0; t < 4; ++t) {
            bf16x8 k0 = *(const bf16x8*)(Ks + ql * SPA + t * 16 + hi * 8);
            bf16x8 k1 = *(const bf16x8*)(Ks + (32 + ql) * SPA + t * 16 + hi * 8);
            s0 = MFMA32(k0, qa[t], s0);
            s1 = MFMA32(k1, qa[t], s1);
        }
        float ls0 = 0.f, ls1 = 0.f;
        u32 w[8];
        #pragma unroll
        for (int r = 0; r < 16; r += 2) {
            float pa = fexp2(s0[r]), pb = fexp2(s0[r + 1]);
            s0[r] = pa; s0[r + 1] = pb;
            ls0 += pa; ls1 += pb;
        }
        #pragma unroll
        for (int m = 0; m < 8; ++m) w[m] = cvtpk(s0[2*m], s0[2*m+1]);
        #pragma unroll
        for (int tl = 0; tl < 2; ++tl) {
            const int mb = 4 * tl, tk = tl;
            u32 send0 = hi ? w[mb]   : w[mb+2];
            u32 send1 = hi ? w[mb+1] : w[mb+3];
            u32 r0 = (u32)__shfl_xor((int)send0, 32, 64);
            u32 r1 = (u32)__shfl_xor((int)send1, 32, 64);
            union { u32 uw[4]; bf16x8 v; } pu;
            pu.uw[0] = hi ? r0 : w[mb];
            pu.uw[1] = hi ? r1 : w[mb+1];
            pu.uw[2] = hi ? w[mb+2] : r0;
            pu.uw[3] = hi ? w[mb+3] : r1;
            bf16x8 v0 = *(const bf16x8*)(Vt + ql * SPA + tk * 16 + hi * 8);
            bf16x8 v1 = *(const bf16x8*)(Vt + (32 + ql) * SPA + tk * 16 + hi * 8);
            o0 = MFMA32(pu.v, v0, o0);
            o1 = MFMA32(pu.v, v1, o1);
        }
        #pragma unroll
        for (int r = 0; r < 16; r += 2) {
            float pa = fexp2(s1[r]), pb = fexp2(s1[r + 1]);
            s1[r] = pa; s1[r + 1] = pb;
            ls0 += pa; ls1 += pb;
        }
        #pragma unroll
        for (int m = 0; m < 8; ++m) w[m] = cvtpk(s1[2*m], s1[2*m+1]);
        #pragma unroll
        for (int tl = 0; tl < 2; ++tl) {
            const int mb = 4 * tl, tk = 2 + tl;
            u32 send0 = hi ? w[mb]   : w[mb+2];
            u32 send1 = hi ? w[mb+1] : w[mb+3];
            u32 r0 = (u32)__shfl_xor((int)send0, 32, 64);
            u32 r1 = (u32)__shfl_xor((int)send1, 32, 64);
            union { u32 uw[4]; bf16x8 v; } pu;
            pu.uw[0] = hi ? r0 : w[mb];
            pu.uw[1] = hi ? r1 : w[mb+1];
            pu.uw[2] = hi ? w[mb+2] : r0;
            pu.uw[3] = hi ? w[mb+3] : r1;
            bf16x8 v0 = *(const bf16x8*)(Vt + ql * SPA + tk * 16 + hi * 8);
            bf16x8 v1 = *(const bf16x8*)(Vt + (32 + ql) * SPA + tk * 16 + hi * 8);
            o0 = MFMA32(pu.v, v0, o0);
            o1 = MFMA32(pu.v, v1, o1);
        }
        l_lane += ls0 + ls1;
    }
    float l_tot = l_lane + __shfl_xor(l_lane, 32, 64);
    float* Op = split ? Op1 : Op0;
    const size_t ob = ((size_t)b * TSEQ) * MDIM + h * DHD;
    #pragma unroll
    for (int r = 0; r < 16; ++r) {
        int qr = q0 + wq * 32 + (r & 3) + 8 * (r >> 2) + 4 * hi;
        Op[ob + (size_t)qr * MDIM + ql]      = o0[r];
        Op[ob + (size_t)qr * MDIM + 32 + ql] = o1[r];
    }
    if (hi == 0)
        lp[(((size_t)split * NB + b) * NH + h) * TSEQ + q0 + wq * 32 + ql] = l_tot;
}

// ---------------- U: per-(bt,d) — att[h] once, distribute to 8 experts, bf16 split -------------
__global__ __launch_bounds__(256)
void compute_U2(const float* __restrict__ Op0, const float* __restrict__ Op1,
                const float* __restrict__ lp, const u32* __restrict__ selo,
                unsigned short* __restrict__ Uh, unsigned short* __restrict__ Ul)
{
    int t = blockIdx.x * 256 + threadIdx.x;      // < MBT*64 = 262144
    int bt = t >> 6, d = t & 63;
    int b = bt >> 11, ts = bt & 2047;
    float att[16];
    #pragma unroll
    for (int h = 0; h < NH; ++h) {
        size_t li = ((size_t)b * NH + h) * TSEQ + ts;
        float l = lp[li] + lp[li + (size_t)NB * NH * TSEQ];
        size_t oi = (size_t)bt * MDIM + h * DHD + d;
        att[h] = (Op0[oi] + Op1[oi]) / l;
    }
    const u32* sp = selo + bt * 16;
    u32 m[16];
    #pragma unroll
    for (int h = 0; h < NH; ++h) m[h] = sp[h];
    #pragma unroll
    for (int e = 0; e < NE; ++e) {
        float sum = 0.f;
        #pragma unroll
        for (int h = 0; h < NH; ++h)
            if (m[h] & (1u << e)) sum += att[h];
        int idx = bt * 512 + e * 64 + d;
        unsigned short hi16 = f2bf(sum);
        Uh[idx] = hi16;
        Ul[idx] = f2bf(sum - bf2f(hi16));
    }
}

extern "C" void kernel_launch(void* const* d_in, const int* in_sizes, int n_in,
                              void* d_out, int out_size, void* d_ws, size_t ws_size,
                              hipStream_t stream)
{
    const float* x  = (const float*)d_in[0];
    const float* Wq = (const float*)d_in[1];
    const float* Wk = (const float*)d_in[2];
    const float* Wv = (const float*)d_in[3];
    const float* Ws = (const float*)d_in[4];
    const float* Wd = (const float*)d_in[5];
    const float* Wo = (const float*)d_in[6];
    float* out = (float*)d_out;
    char* ws = (char*)d_ws;

    // region 0 (16.78 MB): [xb|Wqkvb] -> Op0 ; region @46137344 (16.78 MB): xbl -> Op1
    unsigned short* xb    = (unsigned short*)(ws);
    unsigned short* Wqkvb = (unsigned short*)(ws + 8388608);
    float*          Op0   = (float*)(ws);
    unsigned short* QKVb  = (unsigned short*)(ws + 16777216);   // 20.97 MB
    unsigned short* Vtg   = (unsigned short*)(ws + 37748736);   // 8.39 MB
    unsigned short* xbl   = (unsigned short*)(ws + 46137344);   // 8.39 MB (dead before attn)
    float*          Op1   = (float*)(ws + 46137344);            // 16.78 MB
    float*          lp    = (float*)(ws + 62914560);            // 0.52 MB
    unsigned short* WoTh  = (unsigned short*)(ws + 63438848);   // 1.05 MB
    unsigned short* WoTl  = (unsigned short*)(ws + 64487424);   // 1.05 MB
    unsigned short* Uh    = (unsigned short*)(ws + 65536000);   // 4.19 MB
    u32*            flags = (u32*)(ws + 69730304);              // 64 KB (dead before Ul)
    unsigned short* Ul    = (unsigned short*)(ws + 69730304);   // 4.19 MB
    float2*         wvp   = (float2*)(ws + 73924608);           // 0.52 MB
    u32*            selv  = (u32*)(ws + 74448896);              // 0.26 MB
    u32*            selo  = (u32*)(ws + 74711040);              // 0.26 MB
    unsigned short* Wsdh  = (unsigned short*)(ws + 74973184);   // 0.52 MB
    unsigned short* Wsdl  = (unsigned short*)(ws + 75497472);   // 0.52 MB

    dim3 blk(256);
    prep<<<5504, blk, 0, stream>>>(x, Wq, Wk, Wv, Ws, Wd, Wo,
                                   xb, xbl, Wqkvb, Wsdh, Wsdl, WoTh, WoTl, flags);

    // merged QKV projection (640 blocks) + gate GEMM w/ fused top-k (256 blocks)
    qkvgate<<<896, blk, 0, stream>>>(xb, Wqkvb, QKVb, xbl, Wsdh, Wsdl,
                                     wvp, selv, selo, flags);

    gate_fix<<<128, blk, 0, stream>>>(x, Ws, Wd, flags, wvp, selv, selo);

    vtrans<<<256, blk, 0, stream>>>(QKVb, wvp, selv, Vtg);

    attn_mfma<<<1024, blk, 0, stream>>>(QKVb, Vtg, Op0, Op1, lp);

    compute_U2<<<1024, blk, 0, stream>>>(Op0, Op1, lp, selo, Uh, Ul);
    mfma_gemm3<<<512, blk, 0, stream>>>(Uh, Ul, WoTh, WoTl, out);
}

// Round 16
// 152.837 us; speedup vs baseline: 1.3180x; 1.0241x over previous
//
#include <hip/hip_runtime.h>
#include <math.h>

#define TSEQ 2048
#define NB   2
#define NH   16
#define NE   8
#define DHD  64
#define MDIM 1024
#define MBT  4096   // NB*TSEQ
#define LDQKV 2560  // Q(1024) | K(1024) | V-experts(512)
#define GTAU 1e-3f  // margin threshold for fp64 gate fix-up
#define MAXFLAG 16384

typedef __attribute__((ext_vector_type(8))) short bf16x8;
typedef __attribute__((ext_vector_type(4))) float f32x4;
typedef __attribute__((ext_vector_type(16))) float f32x16;
typedef unsigned int u32;

__device__ inline unsigned short f2bf(float f) {
    union { float f; unsigned u; } v; v.f = f;
    unsigned r = v.u + 0x7fff + ((v.u >> 16) & 1);
    return (unsigned short)(r >> 16);
}
__device__ inline float bf2f(unsigned short h) {
    union { unsigned u; float f; } v; v.u = ((unsigned)h) << 16;
    return v.f;
}
__device__ inline u32 cvtpk(float a, float b) {   // low16=bf16(a), high16=bf16(b)
    u32 r;
    asm("v_cvt_pk_bf16_f32 %0, %1, %2" : "=v"(r) : "v"(a), "v"(b));
    return r;
}
// single-instruction exp2 (inputs bounded |x|<~8 here; no denorm/range handling needed)
__device__ inline float fexp2(float x) {
#if __has_builtin(__builtin_amdgcn_exp2f)
    return __builtin_amdgcn_exp2f(x);
#else
    float r; asm("v_exp_f32 %0, %1" : "=v"(r) : "v"(x)); return r;
#endif
}

// async global->LDS, 16B per lane (dst wave-uniform base + lane*16)
__device__ inline void gload16(const void* g, void* l) {
    __builtin_amdgcn_global_load_lds((const __attribute__((address_space(1))) u32*)g,
                                     (__attribute__((address_space(3))) u32*)l, 16, 0, 0);
}

__device__ inline void cast8s(const float* __restrict__ in, unsigned short* __restrict__ out,
                              int i, float sc) {
    const float4* p = (const float4*)(in + (size_t)i * 8);
    float4 a = p[0], b = p[1];
    unsigned short o[8] = { f2bf(a.x*sc), f2bf(a.y*sc), f2bf(a.z*sc), f2bf(a.w*sc),
                            f2bf(b.x*sc), f2bf(b.y*sc), f2bf(b.z*sc), f2bf(b.w*sc) };
    *(uint4*)(out + (size_t)i * 8) = *(const uint4*)o;
}
__device__ inline void cast8hl(const float* __restrict__ in,
                               unsigned short* __restrict__ oh, unsigned short* __restrict__ ol,
                               int i) {
    const float4* p = (const float4*)(in + (size_t)i * 8);
    float4 a = p[0], b = p[1];
    float f[8] = { a.x, a.y, a.z, a.w, b.x, b.y, b.z, b.w };
    unsigned short h8[8], l8[8];
    #pragma unroll
    for (int j = 0; j < 8; ++j) {
        unsigned short hi = f2bf(f[j]);
        h8[j] = hi;
        l8[j] = f2bf(f[j] - bf2f(hi));
    }
    *(uint4*)(oh + (size_t)i * 8) = *(const uint4*)h8;
    *(uint4*)(ol + (size_t)i * 8) = *(const uint4*)l8;
}

// ---------------- fused prep (casts + Wsd split + Wo repack/split + flag reset) ----------------
__global__ __launch_bounds__(256)
void prep(const float* __restrict__ x,  const float* __restrict__ Wq,
          const float* __restrict__ Wk, const float* __restrict__ Wv,
          const float* __restrict__ Ws, const float* __restrict__ Wd,
          const float* __restrict__ Wo,
          unsigned short* __restrict__ xb, unsigned short* __restrict__ xbl,
          unsigned short* __restrict__ Wqkvb,
          unsigned short* __restrict__ Wsdh, unsigned short* __restrict__ Wsdl,
          unsigned short* __restrict__ WoTh, unsigned short* __restrict__ WoTl,
          u32* __restrict__ flags)
{
    const float qsc = 0.125f * 1.4426950408889634f;  // fold scale*log2(e) into Q
    int b = blockIdx.x, tid = threadIdx.x;
    if (b == 0 && tid == 0) flags[0] = 0;
    if (b < 2048)      cast8hl(x, xb, xbl,          (b        ) * 256 + tid);
    else if (b < 2560) cast8s(Wq, Wqkvb,            (b - 2048) * 256 + tid, qsc);
    else if (b < 3072) cast8s(Wk, Wqkvb + 1048576,  (b - 2560) * 256 + tid, 1.f);
    else if (b < 3328) cast8s(Wv, Wqkvb + 2097152,  (b - 3072) * 256 + tid, 1.f);
    else if (b < 3456) {
        int i = (b - 3328) * 256 + tid;   // 0..32767; 8 elems each of Ws|Wd
        const float* src = (i < 16384) ? Ws + (size_t)i * 8 : Wd + (size_t)(i - 16384) * 8;
        const float4* p = (const float4*)src;
        float4 a = p[0], bq = p[1];
        float f8[8] = { a.x, a.y, a.z, a.w, bq.x, bq.y, bq.z, bq.w };
        unsigned short h8[8], l8[8];
        #pragma unroll
        for (int j = 0; j < 8; ++j) {
            unsigned short hi = f2bf(f8[j]);
            h8[j] = hi;
            l8[j] = f2bf(f8[j] - bf2f(hi));
        }
        *(uint4*)(Wsdh + (size_t)i * 8) = *(const uint4*)h8;
        *(uint4*)(Wsdl + (size_t)i * 8) = *(const uint4*)l8;
    } else {
        int idx = (b - 3456) * 256 + tid;  // < 524288
        int f = idx >> 9, ed = idx & 511, e = ed >> 6, d = ed & 63;
        float v = Wo[(size_t)e * (MDIM * DHD) + (size_t)f * DHD + d];
        unsigned short hi = f2bf(v);
        WoTh[idx] = hi;
        WoTl[idx] = f2bf(v - bf2f(hi));
    }
}

// ---------------- merged QKV GEMM (640 blocks) + gate GEMM w/ fused top-k (256 blocks) --------
__global__ __launch_bounds__(256)
void qkvgate(const unsigned short* __restrict__ A,
             const unsigned short* __restrict__ B,
             unsigned short* __restrict__ C,
             const unsigned short* __restrict__ Al,
             const unsigned short* __restrict__ Bh2, const unsigned short* __restrict__ Bl2,
             float2* __restrict__ wv, u32* __restrict__ selv, u32* __restrict__ selo,
             u32* __restrict__ flags)
{
    __shared__ __align__(16) unsigned short S[8192];   // 16 KB, unioned between paths/phases
    const int tid = threadIdx.x;
    const int lane = tid & 63, wave = tid >> 6;
    const int fr = lane & 15, fg = lane >> 4;
    const int grow = lane >> 2, gcol = (lane & 3) * 8;

    if (blockIdx.x < 640) {
        // ---------------- QKV path ----------------
        const int K = 1024, N = LDQKV, nbx = 20;
        unsigned short* As = S;            // 128*32
        unsigned short* Bs = S + 4096;     // 128*32
        const int o = blockIdx.x;
        const int virt = (o & 7) * 80 + (o >> 3);      // bijective XCD-chunked remap (640/8=80)
        const int bx = virt % nbx, by = virt / nbx;
        const int m0 = by * 128, n0 = bx * 128;
        const int wm = (wave >> 1) * 64, wn = (wave & 1) * 64;

        f32x4 acc[4][4];
        #pragma unroll
        for (int i = 0; i < 4; ++i)
            #pragma unroll
            for (int j = 0; j < 4; ++j) acc[i][j] = (f32x4)0.f;

        for (int k0 = 0; k0 < K; k0 += 32) {
            __syncthreads();
            const unsigned short* gA = A + (size_t)(m0 + wave * 32 + grow) * K + k0 + gcol;
            gload16(gA,                  As + wave * 1024);
            gload16(gA + (size_t)16 * K, As + wave * 1024 + 512);
            const unsigned short* gB = B + (size_t)(n0 + wave * 32 + grow) * K + k0 + gcol;
            gload16(gB,                  Bs + wave * 1024);
            gload16(gB + (size_t)16 * K, Bs + wave * 1024 + 512);
            __syncthreads();
            bf16x8 af[4], bfr[4];
            #pragma unroll
            for (int t = 0; t < 4; ++t) {
                af[t]  = *(const bf16x8*)(As + (wm + t * 16 + fr) * 32 + fg * 8);
                bfr[t] = *(const bf16x8*)(Bs + (wn + t * 16 + fr) * 32 + fg * 8);
            }
            #pragma unroll
            for (int i = 0; i < 4; ++i)
                #pragma unroll
                for (int j = 0; j < 4; ++j)
                    acc[i][j] = __builtin_amdgcn_mfma_f32_16x16x32_bf16(af[i], bfr[j], acc[i][j], 0, 0, 0);
        }
        #pragma unroll
        for (int i = 0; i < 4; ++i)
            #pragma unroll
            for (int j = 0; j < 4; ++j)
                #pragma unroll
                for (int rr = 0; rr < 4; ++rr) {
                    int row = m0 + wm + i * 16 + fg * 4 + rr;
                    int col = n0 + wn + j * 16 + fr;
                    C[(size_t)row * N + col] = f2bf(acc[i][j][rr]);
                }
    } else {
        // ---------------- gate path (3-pass split-bf16, 64x64 tile, 4 waves of 32x32) ----------
        const int K = 1024;
        const int g = blockIdx.x - 640;                // 0..255
        const int m0 = (g >> 2) * 64, n0 = (g & 3) * 64;
        const int wm = (wave >> 1) * 32, wn = (wave & 1) * 32;
        const unsigned short* src = (wave == 0) ? A : (wave == 1) ? Al : (wave == 2) ? Bh2 : Bl2;
        const int brow = (wave >= 2) ? n0 : m0;

        f32x4 acc[2][2];
        #pragma unroll
        for (int i = 0; i < 2; ++i)
            #pragma unroll
            for (int j = 0; j < 2; ++j) acc[i][j] = (f32x4)0.f;

        for (int k0 = 0; k0 < K; k0 += 32) {
            __syncthreads();
            #pragma unroll
            for (int i = 0; i < 4; ++i)
                gload16(src + (size_t)(brow + i * 16 + grow) * K + k0 + gcol,
                        S + wave * 2048 + i * 512);
            __syncthreads();
            bf16x8 ah[2], al[2], bh[2], bl[2];
            #pragma unroll
            for (int t = 0; t < 2; ++t) {
                ah[t] = *(const bf16x8*)(S +        (wm + t * 16 + fr) * 32 + fg * 8);
                al[t] = *(const bf16x8*)(S + 2048 + (wm + t * 16 + fr) * 32 + fg * 8);
                bh[t] = *(const bf16x8*)(S + 4096 + (wn + t * 16 + fr) * 32 + fg * 8);
                bl[t] = *(const bf16x8*)(S + 6144 + (wn + t * 16 + fr) * 32 + fg * 8);
            }
            #pragma unroll
            for (int i = 0; i < 2; ++i)
                #pragma unroll
                for (int j = 0; j < 2; ++j) {
                    acc[i][j] = __builtin_amdgcn_mfma_f32_16x16x32_bf16(ah[i], bh[j], acc[i][j], 0, 0, 0);
                    acc[i][j] = __builtin_amdgcn_mfma_f32_16x16x32_bf16(ah[i], bl[j], acc[i][j], 0, 0, 0);
                    acc[i][j] = __builtin_amdgcn_mfma_f32_16x16x32_bf16(al[i], bh[j], acc[i][j], 0, 0, 0);
                }
        }
        // ---- fused top-k epilogue: spill 64x64 tile to LDS, then per-(bt,h) top-2/margin ----
        float* Tf = (float*)S;   // 64*64 f32 = 16 KB (exactly S)
        __syncthreads();         // all waves done reading staging from last k-step
        #pragma unroll
        for (int i = 0; i < 2; ++i)
            #pragma unroll
            for (int j = 0; j < 2; ++j)
                #pragma unroll
                for (int rr = 0; rr < 4; ++rr)
                    Tf[(wm + i * 16 + fg * 4 + rr) * 64 + wn + j * 16 + fr] = acc[i][j][rr];
        __syncthreads();
        const int type = (n0 >= 128);           // 0 = V gate, 1 = O gate
        const int hbase = (n0 & 127) >> 3;      // 0 or 8
        #pragma unroll
        for (int k = 0; k < 2; ++k) {
            int it = tid + k * 256;             // 512 items: 64 rows x 8 local-h
            int lr = it >> 3, lh = it & 7;
            int item = (m0 + lr) * 16 + hbase + lh;
            const float* gp = Tf + lr * 64 + lh * 8;
            float b1 = -1e30f, b2 = -1e30f, b3 = -1e30f; int e1 = 0, e2 = 0;
            #pragma unroll
            for (int e = 0; e < NE; ++e) {
                float v = gp[e];
                if (v > b1)      { b3 = b2; b2 = b1; e2 = e1; b1 = v; e1 = e; }
                else if (v > b2) { b3 = b2; b2 = v;  e2 = e; }
                else if (v > b3) { b3 = v; }
            }
            if (type == 0) {
                wv[item] = make_float2(1.f / (1.f + __expf(-b1)), 1.f / (1.f + __expf(-b2)));
                selv[item] = (u32)e1 | ((u32)e2 << 4);
                if (b2 - b3 < GTAU) {
                    u32 p = atomicAdd(flags, 1u);
                    if (p < MAXFLAG) flags[1 + p] = (u32)item;
                }
            } else {
                selo[item] = (1u << e1) | (1u << e2);
                if (b2 - b3 < GTAU) {
                    u32 p = atomicAdd(flags, 1u);
                    if (p < MAXFLAG) flags[1 + p] = (u32)item | 0x10000u;
                }
            }
        }
    }
}

// ---------------- split-bf16 3-pass MFMA GEMM, fp32 out (128x64 tiles, 512 blocks) ------------
__global__ __launch_bounds__(256)
void mfma_gemm3(const unsigned short* __restrict__ Ah, const unsigned short* __restrict__ Al,
                const unsigned short* __restrict__ Bh, const unsigned short* __restrict__ Bl,
                float* __restrict__ C)
{
    const int Kc = 512, N = 1024;
    __shared__ __align__(16) unsigned short Ash[128 * 32];
    __shared__ __align__(16) unsigned short Asl[128 * 32];
    __shared__ __align__(16) unsigned short Bsh[64 * 32];
    __shared__ __align__(16) unsigned short Bsl[64 * 32];
    const int o = blockIdx.x;                       // 512 blocks
    const int virt = (o & 7) * 64 + (o >> 3);       // bijective XCD-chunked remap
    const int bx = virt & 15, by = virt >> 4;
    const int tid = threadIdx.x;
    const int lane = tid & 63, wave = tid >> 6;
    const int m0 = by * 128, n0 = bx * 64;
    const int wm = (wave >> 1) * 64, wn = (wave & 1) * 32;
    const int fr = lane & 15, fg = lane >> 4;
    const int grow = lane >> 2, gcol = (lane & 3) * 8;

    f32x4 acc[4][2];
    #pragma unroll
    for (int i = 0; i < 4; ++i)
        #pragma unroll
        for (int j = 0; j < 2; ++j) acc[i][j] = (f32x4)0.f;

    for (int k0 = 0; k0 < Kc; k0 += 32) {
        __syncthreads();
        const size_t roff  = (size_t)(m0 + wave * 32 + grow) * Kc + k0 + gcol;
        const size_t roffB = (size_t)(n0 + wave * 16 + grow) * Kc + k0 + gcol;
        gload16(Ah + roff,             Ash + wave * 1024);
        gload16(Ah + roff + 16 * Kc,   Ash + wave * 1024 + 512);
        gload16(Al + roff,             Asl + wave * 1024);
        gload16(Al + roff + 16 * Kc,   Asl + wave * 1024 + 512);
        gload16(Bh + roffB,            Bsh + wave * 512);
        gload16(Bl + roffB,            Bsl + wave * 512);
        __syncthreads();
        bf16x8 ah[4], al[4], bh[2], bl[2];
        #pragma unroll
        for (int t = 0; t < 4; ++t) {
            ah[t] = *(const bf16x8*)(Ash + (wm + t * 16 + fr) * 32 + fg * 8);
            al[t] = *(const bf16x8*)(Asl + (wm + t * 16 + fr) * 32 + fg * 8);
        }
        #pragma unroll
        for (int t = 0; t < 2; ++t) {
            bh[t] = *(const bf16x8*)(Bsh + (wn + t * 16 + fr) * 32 + fg * 8);
            bl[t] = *(const bf16x8*)(Bsl + (wn + t * 16 + fr) * 32 + fg * 8);
        }
        #pragma unroll
        for (int i = 0; i < 4; ++i)
            #pragma unroll
            for (int j = 0; j < 2; ++j) {
                acc[i][j] = __builtin_amdgcn_mfma_f32_16x16x32_bf16(ah[i], bh[j], acc[i][j], 0, 0, 0);
                acc[i][j] = __builtin_amdgcn_mfma_f32_16x16x32_bf16(ah[i], bl[j], acc[i][j], 0, 0, 0);
                acc[i][j] = __builtin_amdgcn_mfma_f32_16x16x32_bf16(al[i], bh[j], acc[i][j], 0, 0, 0);
            }
    }
    #pragma unroll
    for (int i = 0; i < 4; ++i)
        #pragma unroll
        for (int j = 0; j < 2; ++j)
            #pragma unroll
            for (int rr = 0; rr < 4; ++rr) {
                int row = m0 + wm + i * 16 + fg * 4 + rr;
                int col = n0 + wn + j * 16 + fr;
                C[(size_t)row * N + col] = acc[i][j][rr];
            }
}

// ---------------- fp64 fix-up for flagged near-tie items (one wave per record) ----------------
__global__ __launch_bounds__(256)
void gate_fix(const float* __restrict__ x, const float* __restrict__ Ws,
              const float* __restrict__ Wd, const u32* __restrict__ flags,
              float2* __restrict__ wv, u32* __restrict__ selv, u32* __restrict__ selo)
{
    u32 nf = flags[0]; if (nf > MAXFLAG) nf = MAXFLAG;
    int gw = (blockIdx.x * 256 + threadIdx.x) >> 6;
    int lane = threadIdx.x & 63;
    int nwaves = gridDim.x * 4;
    for (u32 w = gw; w < nf; w += nwaves) {
        u32 rec = flags[1 + w];
        int item = rec & 0xffff, which = rec >> 16;
        int bt = item >> 4, h = item & 15;
        const float* W = (which ? Wd : Ws) + (size_t)h * NE * MDIM + lane * 16;
        const float* xr = x + (size_t)bt * MDIM + lane * 16;
        double g[8];
        #pragma unroll
        for (int e = 0; e < 8; ++e) {
            double s = 0.0;
            #pragma unroll
            for (int c = 0; c < 16; ++c)
                s += (double)xr[c] * (double)W[(size_t)e * MDIM + c];
            g[e] = s;
        }
        #pragma unroll
        for (int off = 32; off; off >>= 1)
            #pragma unroll
            for (int e = 0; e < 8; ++e)
                g[e] += __shfl_xor(g[e], off, 64);
        if (lane == 0) {
            double b1 = -1e300, b2 = -1e300; int i1 = 0, i2 = 0;
            #pragma unroll
            for (int e = 0; e < 8; ++e) {
                double v = g[e];
                if (v > b1)      { b2 = b1; i2 = i1; b1 = v; i1 = e; }
                else if (v > b2) { b2 = v;  i2 = e; }
            }
            if (which == 0) {
                wv[item] = make_float2(1.f / (1.f + __expf(-(float)b1)),
                                       1.f / (1.f + __expf(-(float)b2)));
                selv[item] = (u32)i1 | ((u32)i2 << 4);
            } else {
                selo[item] = (1u << i1) | (1u << i2);
            }
        }
    }
}

// ---------------- V mix + transpose, LDS-staged: Vtg[b][h][d][t] ----------------
#define VTP 72   // LDS row stride (bf16 elems), 144 B, 16B-aligned
__global__ __launch_bounds__(256)
void vtrans(const unsigned short* __restrict__ QKVb, const float2* __restrict__ wv,
            const u32* __restrict__ selv, unsigned short* __restrict__ Vtg)
{
    __shared__ __align__(16) unsigned short Ls[256 * VTP];
    const int vid = blockIdx.x;              // 0..255
    const int xcd = vid & 7, local = vid >> 3;
    const int virt = xcd * 32 + local;       // bijective XCD-chunked remap
    const int b = virt >> 7, rem = virt & 127;
    const int tblk = rem >> 4, h = rem & 15;
    const int tid = threadIdx.x;

    // phase 1: one thread per t — mix the 2 selected experts, vector loads
    {
        const int bt = b * TSEQ + tblk * 256 + tid;
        u32 s = selv[bt * 16 + h];
        float2 w = wv[bt * 16 + h];
        int e1 = s & 15, e2 = (s >> 4) & 15;
        const unsigned short* pv = QKVb + (size_t)bt * LDQKV + 2048;
        #pragma unroll
        for (int c = 0; c < 8; ++c) {
            uint4 a  = *(const uint4*)(pv + e1 * 64 + c * 8);
            uint4 bb = *(const uint4*)(pv + e2 * 64 + c * 8);
            unsigned short ea[8], eb[8], eo[8];
            *(uint4*)ea = a; *(uint4*)eb = bb;
            #pragma unroll
            for (int j = 0; j < 8; ++j)
                eo[j] = f2bf(w.x * bf2f(ea[j]) + w.y * bf2f(eb[j]));
            *(uint4*)(Ls + tid * VTP + c * 8) = *(const uint4*)eo;
        }
    }
    __syncthreads();
    // phase 2: transpose out of LDS — lane = d (conflict-free broadcast pairs)
    {
        const int d = tid & 63, outer = tid >> 6;
        const size_t vrow = ((size_t)((b * NH + h) * DHD + d)) * TSEQ + tblk * 256;
        #pragma unroll
        for (int c8 = 0; c8 < 8; ++c8) {
            int t0 = (outer * 8 + c8) * 8;
            unsigned short o[8];
            #pragma unroll
            for (int j = 0; j < 8; ++j)
                o[j] = Ls[(t0 + j) * VTP + d];
            *(uint4*)(Vtg + vrow + t0) = *(const uint4*)o;
        }
    }
}

// ---------------- attn: swapped-QK 32x32 MFMA, in-register P (permlane32_swap exchange) -------
// flat grid 1024, XCD-swizzled: each XCD owns 8 (b,h,split) groups x 16 q-blocks
#define SPA 72   // LDS row stride (bf16) = 144 B
#define MFMA32(A,B,C) __builtin_amdgcn_mfma_f32_32x32x16_bf16(A, B, C, 0, 0, 0)
__global__ __launch_bounds__(256)
void attn_mfma(const unsigned short* __restrict__ QKVb,
               const unsigned short* __restrict__ Vtg,
               float* __restrict__ Op0, float* __restrict__ Op1,
               float* __restrict__ lp)
{
    __shared__ __align__(16) unsigned short Ks[64 * SPA];
    __shared__ __align__(16) unsigned short Vt[64 * SPA];   // V^T: rows=d, cols=key
    const int vid = blockIdx.x;                  // 0..1023
    const int xcd = vid & 7, sl = vid >> 3;      // sl 0..127
    const int grp = xcd * 8 + (sl >> 4);         // 0..63 (b,h,split group)
    const int q0  = (sl & 15) * 128;
    const int h   = grp & 15;
    const int z   = grp >> 4;                    // 0..3
    const int b = z >> 1, split = z & 1;
    const int tid = threadIdx.x;
    const int lane = tid & 63, wq = tid >> 6;
    const int ql = lane & 31;
    const int hi = lane >> 5;
    const size_t base_q = ((size_t)b * TSEQ) * LDQKV + h * DHD;
    const size_t base_k = base_q + 1024;
    const size_t base_v = ((size_t)(b * NH + h) * DHD) * TSEQ;
    const int k00 = split * 1024;

    const int qrow = q0 + wq * 32 + ql;
    bf16x8 qa[4];
    #pragma unroll
    for (int t = 0; t < 4; ++t)
        qa[t] = *(const bf16x8*)(QKVb + base_q + (size_t)qrow * LDQKV + t * 16 + hi * 8);

    f32x16 o0 = (f32x16)0.f, o1 = (f32x16)0.f;
    float l_lane = 0.f;

    const int srow = tid >> 2, scol = (tid & 3) * 8;
    uint4 kr0 = *(const uint4*)(QKVb + base_k + (size_t)(k00 + srow) * LDQKV + scol);
    uint4 kr1 = *(const uint4*)(QKVb + base_k + (size_t)(k00 + srow) * LDQKV + scol + 32);
    uint4 vr0 = *(const uint4*)(Vtg + base_v + (size_t)srow * TSEQ + k00 + scol);
    uint4 vr1 = *(const uint4*)(Vtg + base_v + (size_t)srow * TSEQ + k00 + scol + 32);

    const int NT = 1024 / 64;
    for (int kb = 0; kb < NT; ++kb) {
        __syncthreads();
        *(uint4*)(Ks + srow * SPA + scol)      = kr0;
        *(uint4*)(Ks + srow * SPA + scol + 32) = kr1;
        *(uint4*)(Vt + srow * SPA + scol)      = vr0;
        *(uint4*)(Vt + srow * SPA + scol + 32) = vr1;
        __syncthreads();
        if (kb + 1 < NT) {
            const size_t gk = base_k + (size_t)(k00 + (kb + 1) * 64 + srow) * LDQKV + scol;
            const size_t gv = base_v + (size_t)srow * TSEQ + k00 + (kb + 1) * 64 + scol;
            kr0 = *(const uint4*)(QKVb + gk);
            kr1 = *(const uint4*)(QKVb + gk + 32);
            vr0 = *(const uint4*)(Vtg + gv);
            vr1 = *(const uint4*)(Vtg + gv + 32);
        }
        f32x16 s0 = (f32x16)0.f, s1 = (f32x16)0.f;
        #pragma unroll
        for (int t = 0; t < 4; ++t) {
            bf16x8 k0 = *(const bf16x8*)(Ks + ql * SPA + t * 16 + hi * 8);
            bf16x8 k1 = *(const bf16x8*)(Ks + (32 + ql) * SPA + t * 16 + hi * 8);
            s0 = MFMA32(k0, qa[t], s0);
            s1 = MFMA32(k1, qa[t], s1);
        }
        float ls0 = 0.f, ls1 = 0.f;
        u32 w[8];
        #pragma unroll
        for (int r = 0; r < 16; r += 2) {
            float pa = fexp2(s0[r]), pb = fexp2(s0[r + 1]);
            s0[r] = pa; s0[r + 1] = pb;
            ls0 += pa; ls1 += pb;
        }
        #pragma unroll
        for (int m = 0; m < 8; ++m) w[m] = cvtpk(s0[2*m], s0[2*m+1]);
        #pragma unroll
        for (int tl = 0; tl < 2; ++tl) {
            const int mb = 4 * tl, tk = tl;
            // v_permlane32_swap_b32 a,b: a.hi <- b.lo(old), b.lo <- a.hi(old)
            // with a=w[mb], b=w[mb+2]: new a == pu.uw[0], new b == pu.uw[2] (verified mapping)
            u32 a0 = w[mb],     b0 = w[mb + 2];
            u32 a1 = w[mb + 1], b1 = w[mb + 3];
            asm("v_permlane32_swap_b32 %0, %1" : "+v"(a0), "+v"(b0));
            asm("v_permlane32_swap_b32 %0, %1" : "+v"(a1), "+v"(b1));
            union { u32 uw[4]; bf16x8 v; } pu;
            pu.uw[0] = a0; pu.uw[1] = a1; pu.uw[2] = b0; pu.uw[3] = b1;
            bf16x8 v0 = *(const bf16x8*)(Vt + ql * SPA + tk * 16 + hi * 8);
            bf16x8 v1 = *(const bf16x8*)(Vt + (32 + ql) * SPA + tk * 16 + hi * 8);
            o0 = MFMA32(pu.v, v0, o0);
            o1 = MFMA32(pu.v, v1, o1);
        }
        #pragma unroll
        for (int r = 0; r < 16; r += 2) {
            float pa = fexp2(s1[r]), pb = fexp2(s1[r + 1]);
            s1[r] = pa; s1[r + 1] = pb;
            ls0 += pa; ls1 += pb;
        }
        #pragma unroll
        for (int m = 0; m < 8; ++m) w[m] = cvtpk(s1[2*m], s1[2*m+1]);
        #pragma unroll
        for (int tl = 0; tl < 2; ++tl) {
            const int mb = 4 * tl, tk = 2 + tl;
            u32 a0 = w[mb],     b0 = w[mb + 2];
            u32 a1 = w[mb + 1], b1 = w[mb + 3];
            asm("v_permlane32_swap_b32 %0, %1" : "+v"(a0), "+v"(b0));
            asm("v_permlane32_swap_b32 %0, %1" : "+v"(a1), "+v"(b1));
            union { u32 uw[4]; bf16x8 v; } pu;
            pu.uw[0] = a0; pu.uw[1] = a1; pu.uw[2] = b0; pu.uw[3] = b1;
            bf16x8 v0 = *(const bf16x8*)(Vt + ql * SPA + tk * 16 + hi * 8);
            bf16x8 v1 = *(const bf16x8*)(Vt + (32 + ql) * SPA + tk * 16 + hi * 8);
            o0 = MFMA32(pu.v, v0, o0);
            o1 = MFMA32(pu.v, v1, o1);
        }
        l_lane += ls0 + ls1;
    }
    float l_tot = l_lane + __shfl_xor(l_lane, 32, 64);
    float* Op = split ? Op1 : Op0;
    const size_t ob = ((size_t)b * TSEQ) * MDIM + h * DHD;
    #pragma unroll
    for (int r = 0; r < 16; ++r) {
        int qr = q0 + wq * 32 + (r & 3) + 8 * (r >> 2) + 4 * hi;
        Op[ob + (size_t)qr * MDIM + ql]      = o0[r];
        Op[ob + (size_t)qr * MDIM + 32 + ql] = o1[r];
    }
    if (hi == 0)
        lp[(((size_t)split * NB + b) * NH + h) * TSEQ + q0 + wq * 32 + ql] = l_tot;
}

// ---------------- U: per-(bt,d) — att[h] once, distribute to 8 experts, bf16 split -------------
__global__ __launch_bounds__(256)
void compute_U2(const float* __restrict__ Op0, const float* __restrict__ Op1,
                const float* __restrict__ lp, const u32* __restrict__ selo,
                unsigned short* __restrict__ Uh, unsigned short* __restrict__ Ul)
{
    int t = blockIdx.x * 256 + threadIdx.x;      // < MBT*64 = 262144
    int bt = t >> 6, d = t & 63;
    int b = bt >> 11, ts = bt & 2047;
    float att[16];
    #pragma unroll
    for (int h = 0; h < NH; ++h) {
        size_t li = ((size_t)b * NH + h) * TSEQ + ts;
        float l = lp[li] + lp[li + (size_t)NB * NH * TSEQ];
        size_t oi = (size_t)bt * MDIM + h * DHD + d;
        att[h] = (Op0[oi] + Op1[oi]) / l;
    }
    const u32* sp = selo + bt * 16;
    u32 m[16];
    #pragma unroll
    for (int h = 0; h < NH; ++h) m[h] = sp[h];
    #pragma unroll
    for (int e = 0; e < NE; ++e) {
        float sum = 0.f;
        #pragma unroll
        for (int h = 0; h < NH; ++h)
            if (m[h] & (1u << e)) sum += att[h];
        int idx = bt * 512 + e * 64 + d;
        unsigned short hi16 = f2bf(sum);
        Uh[idx] = hi16;
        Ul[idx] = f2bf(sum - bf2f(hi16));
    }
}

extern "C" void kernel_launch(void* const* d_in, const int* in_sizes, int n_in,
                              void* d_out, int out_size, void* d_ws, size_t ws_size,
                              hipStream_t stream)
{
    const float* x  = (const float*)d_in[0];
    const float* Wq = (const float*)d_in[1];
    const float* Wk = (const float*)d_in[2];
    const float* Wv = (const float*)d_in[3];
    const float* Ws = (const float*)d_in[4];
    const float* Wd = (const float*)d_in[5];
    const float* Wo = (const float*)d_in[6];
    float* out = (float*)d_out;
    char* ws = (char*)d_ws;

    // region 0 (16.78 MB): [xb|Wqkvb] -> Op0 ; region @46137344 (16.78 MB): xbl -> Op1
    unsigned short* xb    = (unsigned short*)(ws);
    unsigned short* Wqkvb = (unsigned short*)(ws + 8388608);
    float*          Op0   = (float*)(ws);
    unsigned short* QKVb  = (unsigned short*)(ws + 16777216);   // 20.97 MB
    unsigned short* Vtg   = (unsigned short*)(ws + 37748736);   // 8.39 MB
    unsigned short* xbl   = (unsigned short*)(ws + 46137344);   // 8.39 MB (dead before attn)
    float*          Op1   = (float*)(ws + 46137344);            // 16.78 MB
    float*          lp    = (float*)(ws + 62914560);            // 0.52 MB
    unsigned short* WoTh  = (unsigned short*)(ws + 63438848);   // 1.05 MB
    unsigned short* WoTl  = (unsigned short*)(ws + 64487424);   // 1.05 MB
    unsigned short* Uh    = (unsigned short*)(ws + 65536000);   // 4.19 MB
    u32*            flags = (u32*)(ws + 69730304);              // 64 KB (dead before Ul)
    unsigned short* Ul    = (unsigned short*)(ws + 69730304);   // 4.19 MB
    float2*         wvp   = (float2*)(ws + 73924608);           // 0.52 MB
    u32*            selv  = (u32*)(ws + 74448896);              // 0.26 MB
    u32*            selo  = (u32*)(ws + 74711040);              // 0.26 MB
    unsigned short* Wsdh  = (unsigned short*)(ws + 74973184);   // 0.52 MB
    unsigned short* Wsdl  = (unsigned short*)(ws + 75497472);   // 0.52 MB

    dim3 blk(256);
    prep<<<5504, blk, 0, stream>>>(x, Wq, Wk, Wv, Ws, Wd, Wo,
                                   xb, xbl, Wqkvb, Wsdh, Wsdl, WoTh, WoTl, flags);

    // merged QKV projection (640 blocks) + gate GEMM w/ fused top-k (256 blocks)
    qkvgate<<<896, blk, 0, stream>>>(xb, Wqkvb, QKVb, xbl, Wsdh, Wsdl,
                                     wvp, selv, selo, flags);

    gate_fix<<<128, blk, 0, stream>>>(x, Ws, Wd, flags, wvp, selv, selo);

    vtrans<<<256, blk, 0, stream>>>(QKVb, wvp, selv, Vtg);

    attn_mfma<<<1024, blk, 0, stream>>>(QKVb, Vtg, Op0, Op1, lp);

    compute_U2<<<1024, blk, 0, stream>>>(Op0, Op1, lp, selo, Uh, Ul);
    mfma_gemm3<<<512, blk, 0, stream>>>(Uh, Ul, WoTh, WoTl, out);
}

// Round 17
// 151.441 us; speedup vs baseline: 1.3301x; 1.0092x over previous
//
#include <hip/hip_runtime.h>
#include <math.h>

#define TSEQ 2048
#define NB   2
#define NH   16
#define NE   8
#define DHD  64
#define MDIM 1024
#define MBT  4096   // NB*TSEQ
#define LDQKV 2560  // Q(1024) | K(1024) | V-experts(512)
#define GTAU 1e-3f  // margin threshold for fp64 gate fix-up
#define MAXFLAG 16384

typedef __attribute__((ext_vector_type(8))) short bf16x8;
typedef __attribute__((ext_vector_type(4))) float f32x4;
typedef __attribute__((ext_vector_type(16))) float f32x16;
typedef unsigned int u32;

__device__ inline unsigned short f2bf(float f) {
    union { float f; unsigned u; } v; v.f = f;
    unsigned r = v.u + 0x7fff + ((v.u >> 16) & 1);
    return (unsigned short)(r >> 16);
}
__device__ inline float bf2f(unsigned short h) {
    union { unsigned u; float f; } v; v.u = ((unsigned)h) << 16;
    return v.f;
}
__device__ inline u32 cvtpk(float a, float b) {   // low16=bf16(a), high16=bf16(b)
    u32 r;
    asm("v_cvt_pk_bf16_f32 %0, %1, %2" : "=v"(r) : "v"(a), "v"(b));
    return r;
}
// single-instruction exp2 (inputs bounded |x|<~8 here; no denorm/range handling needed)
__device__ inline float fexp2(float x) {
#if __has_builtin(__builtin_amdgcn_exp2f)
    return __builtin_amdgcn_exp2f(x);
#else
    float r; asm("v_exp_f32 %0, %1" : "=v"(r) : "v"(x)); return r;
#endif
}

// async global->LDS, 16B per lane (dst wave-uniform base + lane*16)
__device__ inline void gload16(const void* g, void* l) {
    __builtin_amdgcn_global_load_lds((const __attribute__((address_space(1))) u32*)g,
                                     (__attribute__((address_space(3))) u32*)l, 16, 0, 0);
}

__device__ inline void cast8s(const float* __restrict__ in, unsigned short* __restrict__ out,
                              int i, float sc) {
    const float4* p = (const float4*)(in + (size_t)i * 8);
    float4 a = p[0], b = p[1];
    unsigned short o[8] = { f2bf(a.x*sc), f2bf(a.y*sc), f2bf(a.z*sc), f2bf(a.w*sc),
                            f2bf(b.x*sc), f2bf(b.y*sc), f2bf(b.z*sc), f2bf(b.w*sc) };
    *(uint4*)(out + (size_t)i * 8) = *(const uint4*)o;
}
__device__ inline void cast8hl(const float* __restrict__ in,
                               unsigned short* __restrict__ oh, unsigned short* __restrict__ ol,
                               int i) {
    const float4* p = (const float4*)(in + (size_t)i * 8);
    float4 a = p[0], b = p[1];
    float f[8] = { a.x, a.y, a.z, a.w, b.x, b.y, b.z, b.w };
    unsigned short h8[8], l8[8];
    #pragma unroll
    for (int j = 0; j < 8; ++j) {
        unsigned short hi = f2bf(f[j]);
        h8[j] = hi;
        l8[j] = f2bf(f[j] - bf2f(hi));
    }
    *(uint4*)(oh + (size_t)i * 8) = *(const uint4*)h8;
    *(uint4*)(ol + (size_t)i * 8) = *(const uint4*)l8;
}

// ---------------- fused prep (casts + Wsd split + Wo repack/split + flag reset) ----------------
__global__ __launch_bounds__(256)
void prep(const float* __restrict__ x,  const float* __restrict__ Wq,
          const float* __restrict__ Wk, const float* __restrict__ Wv,
          const float* __restrict__ Ws, const float* __restrict__ Wd,
          const float* __restrict__ Wo,
          unsigned short* __restrict__ xb, unsigned short* __restrict__ xbl,
          unsigned short* __restrict__ Wqkvb,
          unsigned short* __restrict__ Wsdh, unsigned short* __restrict__ Wsdl,
          unsigned short* __restrict__ WoTh, unsigned short* __restrict__ WoTl,
          u32* __restrict__ flags)
{
    const float qsc = 0.125f * 1.4426950408889634f;  // fold scale*log2(e) into Q
    int b = blockIdx.x, tid = threadIdx.x;
    if (b == 0 && tid == 0) flags[0] = 0;
    if (b < 2048)      cast8hl(x, xb, xbl,          (b        ) * 256 + tid);
    else if (b < 2560) cast8s(Wq, Wqkvb,            (b - 2048) * 256 + tid, qsc);
    else if (b < 3072) cast8s(Wk, Wqkvb + 1048576,  (b - 2560) * 256 + tid, 1.f);
    else if (b < 3328) cast8s(Wv, Wqkvb + 2097152,  (b - 3072) * 256 + tid, 1.f);
    else if (b < 3456) {
        int i = (b - 3328) * 256 + tid;   // 0..32767; 8 elems each of Ws|Wd
        const float* src = (i < 16384) ? Ws + (size_t)i * 8 : Wd + (size_t)(i - 16384) * 8;
        const float4* p = (const float4*)src;
        float4 a = p[0], bq = p[1];
        float f8[8] = { a.x, a.y, a.z, a.w, bq.x, bq.y, bq.z, bq.w };
        unsigned short h8[8], l8[8];
        #pragma unroll
        for (int j = 0; j < 8; ++j) {
            unsigned short hi = f2bf(f8[j]);
            h8[j] = hi;
            l8[j] = f2bf(f8[j] - bf2f(hi));
        }
        *(uint4*)(Wsdh + (size_t)i * 8) = *(const uint4*)h8;
        *(uint4*)(Wsdl + (size_t)i * 8) = *(const uint4*)l8;
    } else {
        int idx = (b - 3456) * 256 + tid;  // < 524288
        int f = idx >> 9, ed = idx & 511, e = ed >> 6, d = ed & 63;
        float v = Wo[(size_t)e * (MDIM * DHD) + (size_t)f * DHD + d];
        unsigned short hi = f2bf(v);
        WoTh[idx] = hi;
        WoTl[idx] = f2bf(v - bf2f(hi));
    }
}

// ---------------- merged QKV GEMM (640 blocks) + gate GEMM w/ fused top-k (256 blocks) --------
// QKV path: slot-XOR LDS swizzle (pre-swizzled global col, swizzled fragment read) + 2D XCD chunk
__global__ __launch_bounds__(256)
void qkvgate(const unsigned short* __restrict__ A,
             const unsigned short* __restrict__ B,
             unsigned short* __restrict__ C,
             const unsigned short* __restrict__ Al,
             const unsigned short* __restrict__ Bh2, const unsigned short* __restrict__ Bl2,
             float2* __restrict__ wv, u32* __restrict__ selv, u32* __restrict__ selo,
             u32* __restrict__ flags)
{
    __shared__ __align__(16) unsigned short S[8192];   // 16 KB, unioned between paths/phases
    const int tid = threadIdx.x;
    const int lane = tid & 63, wave = tid >> 6;
    const int fr = lane & 15, fg = lane >> 4;
    const int grow = lane >> 2, gcol = (lane & 3) * 8;

    if (blockIdx.x < 640) {
        // ---------------- QKV path ----------------
        const int K = 1024, N = LDQKV;
        unsigned short* As = S;            // 128*32
        unsigned short* Bs = S + 4096;     // 128*32
        const int o = blockIdx.x;
        // 2D XCD chunk: each XCD owns 8 by x 10 bx (A 2MB + B 2.6MB fits 4MB L2)
        const int xcd = o & 7, local = o >> 3;        // local 0..79
        const int lby = local / 10, lbx = local - lby * 10;
        const int by = (xcd >> 1) * 8 + lby;          // 0..31
        const int bx = (xcd & 1) * 10 + lbx;          // 0..19
        const int m0 = by * 128, n0 = bx * 128;
        const int wm = (wave >> 1) * 64, wn = (wave & 1) * 64;
        // slot-XOR swizzle: lane's global 16B-chunk index = (l&3) ^ ((l>>3)&3)
        const int swzcol = ((lane & 3) ^ ((lane >> 3) & 3)) * 8;
        const int rsw = ((fr >> 1) & 3);              // read-side slot XOR key

        f32x4 acc[4][4];
        #pragma unroll
        for (int i = 0; i < 4; ++i)
            #pragma unroll
            for (int j = 0; j < 4; ++j) acc[i][j] = (f32x4)0.f;

        for (int k0 = 0; k0 < K; k0 += 32) {
            __syncthreads();
            const unsigned short* gA = A + (size_t)(m0 + wave * 32 + grow) * K + k0 + swzcol;
            gload16(gA,                  As + wave * 1024);
            gload16(gA + (size_t)16 * K, As + wave * 1024 + 512);
            const unsigned short* gB = B + (size_t)(n0 + wave * 32 + grow) * K + k0 + swzcol;
            gload16(gB,                  Bs + wave * 1024);
            gload16(gB + (size_t)16 * K, Bs + wave * 1024 + 512);
            __syncthreads();
            bf16x8 af[4], bfr[4];
            #pragma unroll
            for (int t = 0; t < 4; ++t) {
                af[t]  = *(const bf16x8*)(As + (wm + t * 16 + fr) * 32 + (fg ^ rsw) * 8);
                bfr[t] = *(const bf16x8*)(Bs + (wn + t * 16 + fr) * 32 + (fg ^ rsw) * 8);
            }
            #pragma unroll
            for (int i = 0; i < 4; ++i)
                #pragma unroll
                for (int j = 0; j < 4; ++j)
                    acc[i][j] = __builtin_amdgcn_mfma_f32_16x16x32_bf16(af[i], bfr[j], acc[i][j], 0, 0, 0);
        }
        #pragma unroll
        for (int i = 0; i < 4; ++i)
            #pragma unroll
            for (int j = 0; j < 4; ++j)
                #pragma unroll
                for (int rr = 0; rr < 4; ++rr) {
                    int row = m0 + wm + i * 16 + fg * 4 + rr;
                    int col = n0 + wn + j * 16 + fr;
                    C[(size_t)row * N + col] = f2bf(acc[i][j][rr]);
                }
    } else {
        // ---------------- gate path (3-pass split-bf16, 64x64 tile, 4 waves of 32x32) ----------
        const int K = 1024;
        const int g = blockIdx.x - 640;                // 0..255
        const int m0 = (g >> 2) * 64, n0 = (g & 3) * 64;
        const int wm = (wave >> 1) * 32, wn = (wave & 1) * 32;
        const unsigned short* src = (wave == 0) ? A : (wave == 1) ? Al : (wave == 2) ? Bh2 : Bl2;
        const int brow = (wave >= 2) ? n0 : m0;

        f32x4 acc[2][2];
        #pragma unroll
        for (int i = 0; i < 2; ++i)
            #pragma unroll
            for (int j = 0; j < 2; ++j) acc[i][j] = (f32x4)0.f;

        for (int k0 = 0; k0 < K; k0 += 32) {
            __syncthreads();
            #pragma unroll
            for (int i = 0; i < 4; ++i)
                gload16(src + (size_t)(brow + i * 16 + grow) * K + k0 + gcol,
                        S + wave * 2048 + i * 512);
            __syncthreads();
            bf16x8 ah[2], al[2], bh[2], bl[2];
            #pragma unroll
            for (int t = 0; t < 2; ++t) {
                ah[t] = *(const bf16x8*)(S +        (wm + t * 16 + fr) * 32 + fg * 8);
                al[t] = *(const bf16x8*)(S + 2048 + (wm + t * 16 + fr) * 32 + fg * 8);
                bh[t] = *(const bf16x8*)(S + 4096 + (wn + t * 16 + fr) * 32 + fg * 8);
                bl[t] = *(const bf16x8*)(S + 6144 + (wn + t * 16 + fr) * 32 + fg * 8);
            }
            #pragma unroll
            for (int i = 0; i < 2; ++i)
                #pragma unroll
                for (int j = 0; j < 2; ++j) {
                    acc[i][j] = __builtin_amdgcn_mfma_f32_16x16x32_bf16(ah[i], bh[j], acc[i][j], 0, 0, 0);
                    acc[i][j] = __builtin_amdgcn_mfma_f32_16x16x32_bf16(ah[i], bl[j], acc[i][j], 0, 0, 0);
                    acc[i][j] = __builtin_amdgcn_mfma_f32_16x16x32_bf16(al[i], bh[j], acc[i][j], 0, 0, 0);
                }
        }
        // ---- fused top-k epilogue: spill 64x64 tile to LDS, then per-(bt,h) top-2/margin ----
        float* Tf = (float*)S;   // 64*64 f32 = 16 KB (exactly S)
        __syncthreads();         // all waves done reading staging from last k-step
        #pragma unroll
        for (int i = 0; i < 2; ++i)
            #pragma unroll
            for (int j = 0; j < 2; ++j)
                #pragma unroll
                for (int rr = 0; rr < 4; ++rr)
                    Tf[(wm + i * 16 + fg * 4 + rr) * 64 + wn + j * 16 + fr] = acc[i][j][rr];
        __syncthreads();
        const int type = (n0 >= 128);           // 0 = V gate, 1 = O gate
        const int hbase = (n0 & 127) >> 3;      // 0 or 8
        #pragma unroll
        for (int k = 0; k < 2; ++k) {
            int it = tid + k * 256;             // 512 items: 64 rows x 8 local-h
            int lr = it >> 3, lh = it & 7;
            int item = (m0 + lr) * 16 + hbase + lh;
            const float* gp = Tf + lr * 64 + lh * 8;
            float b1 = -1e30f, b2 = -1e30f, b3 = -1e30f; int e1 = 0, e2 = 0;
            #pragma unroll
            for (int e = 0; e < NE; ++e) {
                float v = gp[e];
                if (v > b1)      { b3 = b2; b2 = b1; e2 = e1; b1 = v; e1 = e; }
                else if (v > b2) { b3 = b2; b2 = v;  e2 = e; }
                else if (v > b3) { b3 = v; }
            }
            if (type == 0) {
                wv[item] = make_float2(1.f / (1.f + __expf(-b1)), 1.f / (1.f + __expf(-b2)));
                selv[item] = (u32)e1 | ((u32)e2 << 4);
                if (b2 - b3 < GTAU) {
                    u32 p = atomicAdd(flags, 1u);
                    if (p < MAXFLAG) flags[1 + p] = (u32)item;
                }
            } else {
                selo[item] = (1u << e1) | (1u << e2);
                if (b2 - b3 < GTAU) {
                    u32 p = atomicAdd(flags, 1u);
                    if (p < MAXFLAG) flags[1 + p] = (u32)item | 0x10000u;
                }
            }
        }
    }
}

// ---------------- split-bf16 3-pass MFMA GEMM, fp32 out (128x64 tiles, slot-swizzled) ----------
__global__ __launch_bounds__(256)
void mfma_gemm3(const unsigned short* __restrict__ Ah, const unsigned short* __restrict__ Al,
                const unsigned short* __restrict__ Bh, const unsigned short* __restrict__ Bl,
                float* __restrict__ C)
{
    const int Kc = 512, N = 1024;
    __shared__ __align__(16) unsigned short Ash[128 * 32];
    __shared__ __align__(16) unsigned short Asl[128 * 32];
    __shared__ __align__(16) unsigned short Bsh[64 * 32];
    __shared__ __align__(16) unsigned short Bsl[64 * 32];
    const int o = blockIdx.x;                       // 512 blocks
    const int virt = (o & 7) * 64 + (o >> 3);       // bijective XCD-chunked remap
    const int bx = virt & 15, by = virt >> 4;
    const int tid = threadIdx.x;
    const int lane = tid & 63, wave = tid >> 6;
    const int m0 = by * 128, n0 = bx * 64;
    const int wm = (wave >> 1) * 64, wn = (wave & 1) * 32;
    const int fr = lane & 15, fg = lane >> 4;
    const int grow = lane >> 2;
    const int swzcol = ((lane & 3) ^ ((lane >> 3) & 3)) * 8;
    const int rsw = ((fr >> 1) & 3);

    f32x4 acc[4][2];
    #pragma unroll
    for (int i = 0; i < 4; ++i)
        #pragma unroll
        for (int j = 0; j < 2; ++j) acc[i][j] = (f32x4)0.f;

    for (int k0 = 0; k0 < Kc; k0 += 32) {
        __syncthreads();
        const size_t roff  = (size_t)(m0 + wave * 32 + grow) * Kc + k0 + swzcol;
        const size_t roffB = (size_t)(n0 + wave * 16 + grow) * Kc + k0 + swzcol;
        gload16(Ah + roff,             Ash + wave * 1024);
        gload16(Ah + roff + 16 * Kc,   Ash + wave * 1024 + 512);
        gload16(Al + roff,             Asl + wave * 1024);
        gload16(Al + roff + 16 * Kc,   Asl + wave * 1024 + 512);
        gload16(Bh + roffB,            Bsh + wave * 512);
        gload16(Bl + roffB,            Bsl + wave * 512);
        __syncthreads();
        bf16x8 ah[4], al[4], bh[2], bl[2];
        #pragma unroll
        for (int t = 0; t < 4; ++t) {
            ah[t] = *(const bf16x8*)(Ash + (wm + t * 16 + fr) * 32 + (fg ^ rsw) * 8);
            al[t] = *(const bf16x8*)(Asl + (wm + t * 16 + fr) * 32 + (fg ^ rsw) * 8);
        }
        #pragma unroll
        for (int t = 0; t < 2; ++t) {
            bh[t] = *(const bf16x8*)(Bsh + (wn + t * 16 + fr) * 32 + (fg ^ rsw) * 8);
            bl[t] = *(const bf16x8*)(Bsl + (wn + t * 16 + fr) * 32 + (fg ^ rsw) * 8);
        }
        #pragma unroll
        for (int i = 0; i < 4; ++i)
            #pragma unroll
            for (int j = 0; j < 2; ++j) {
                acc[i][j] = __builtin_amdgcn_mfma_f32_16x16x32_bf16(ah[i], bh[j], acc[i][j], 0, 0, 0);
                acc[i][j] = __builtin_amdgcn_mfma_f32_16x16x32_bf16(ah[i], bl[j], acc[i][j], 0, 0, 0);
                acc[i][j] = __builtin_amdgcn_mfma_f32_16x16x32_bf16(al[i], bh[j], acc[i][j], 0, 0, 0);
            }
    }
    #pragma unroll
    for (int i = 0; i < 4; ++i)
        #pragma unroll
        for (int j = 0; j < 2; ++j)
            #pragma unroll
            for (int rr = 0; rr < 4; ++rr) {
                int row = m0 + wm + i * 16 + fg * 4 + rr;
                int col = n0 + wn + j * 16 + fr;
                C[(size_t)row * N + col] = acc[i][j][rr];
            }
}

// ---------------- fp64 fix-up for flagged near-tie items (one wave per record) ----------------
__global__ __launch_bounds__(256)
void gate_fix(const float* __restrict__ x, const float* __restrict__ Ws,
              const float* __restrict__ Wd, const u32* __restrict__ flags,
              float2* __restrict__ wv, u32* __restrict__ selv, u32* __restrict__ selo)
{
    u32 nf = flags[0]; if (nf > MAXFLAG) nf = MAXFLAG;
    int gw = (blockIdx.x * 256 + threadIdx.x) >> 6;
    int lane = threadIdx.x & 63;
    int nwaves = gridDim.x * 4;
    for (u32 w = gw; w < nf; w += nwaves) {
        u32 rec = flags[1 + w];
        int item = rec & 0xffff, which = rec >> 16;
        int bt = item >> 4, h = item & 15;
        const float* W = (which ? Wd : Ws) + (size_t)h * NE * MDIM + lane * 16;
        const float* xr = x + (size_t)bt * MDIM + lane * 16;
        double g[8];
        #pragma unroll
        for (int e = 0; e < 8; ++e) {
            double s = 0.0;
            #pragma unroll
            for (int c = 0; c < 16; ++c)
                s += (double)xr[c] * (double)W[(size_t)e * MDIM + c];
            g[e] = s;
        }
        #pragma unroll
        for (int off = 32; off; off >>= 1)
            #pragma unroll
            for (int e = 0; e < 8; ++e)
                g[e] += __shfl_xor(g[e], off, 64);
        if (lane == 0) {
            double b1 = -1e300, b2 = -1e300; int i1 = 0, i2 = 0;
            #pragma unroll
            for (int e = 0; e < 8; ++e) {
                double v = g[e];
                if (v > b1)      { b2 = b1; i2 = i1; b1 = v; i1 = e; }
                else if (v > b2) { b2 = v;  i2 = e; }
            }
            if (which == 0) {
                wv[item] = make_float2(1.f / (1.f + __expf(-(float)b1)),
                                       1.f / (1.f + __expf(-(float)b2)));
                selv[item] = (u32)i1 | ((u32)i2 << 4);
            } else {
                selo[item] = (1u << i1) | (1u << i2);
            }
        }
    }
}

// ---------------- V mix + transpose, LDS-staged: Vtg[b][h][d][t] ----------------
#define VTP 72   // LDS row stride (bf16 elems), 144 B, 16B-aligned
__global__ __launch_bounds__(256)
void vtrans(const unsigned short* __restrict__ QKVb, const float2* __restrict__ wv,
            const u32* __restrict__ selv, unsigned short* __restrict__ Vtg)
{
    __shared__ __align__(16) unsigned short Ls[256 * VTP];
    const int vid = blockIdx.x;              // 0..255
    const int xcd = vid & 7, local = vid >> 3;
    const int virt = xcd * 32 + local;       // bijective XCD-chunked remap
    const int b = virt >> 7, rem = virt & 127;
    const int tblk = rem >> 4, h = rem & 15;
    const int tid = threadIdx.x;

    // phase 1: one thread per t — mix the 2 selected experts, vector loads
    {
        const int bt = b * TSEQ + tblk * 256 + tid;
        u32 s = selv[bt * 16 + h];
        float2 w = wv[bt * 16 + h];
        int e1 = s & 15, e2 = (s >> 4) & 15;
        const unsigned short* pv = QKVb + (size_t)bt * LDQKV + 2048;
        #pragma unroll
        for (int c = 0; c < 8; ++c) {
            uint4 a  = *(const uint4*)(pv + e1 * 64 + c * 8);
            uint4 bb = *(const uint4*)(pv + e2 * 64 + c * 8);
            unsigned short ea[8], eb[8], eo[8];
            *(uint4*)ea = a; *(uint4*)eb = bb;
            #pragma unroll
            for (int j = 0; j < 8; ++j)
                eo[j] = f2bf(w.x * bf2f(ea[j]) + w.y * bf2f(eb[j]));
            *(uint4*)(Ls + tid * VTP + c * 8) = *(const uint4*)eo;
        }
    }
    __syncthreads();
    // phase 2: transpose out of LDS — lane = d (conflict-free broadcast pairs)
    {
        const int d = tid & 63, outer = tid >> 6;
        const size_t vrow = ((size_t)((b * NH + h) * DHD + d)) * TSEQ + tblk * 256;
        #pragma unroll
        for (int c8 = 0; c8 < 8; ++c8) {
            int t0 = (outer * 8 + c8) * 8;
            unsigned short o[8];
            #pragma unroll
            for (int j = 0; j < 8; ++j)
                o[j] = Ls[(t0 + j) * VTP + d];
            *(uint4*)(Vtg + vrow + t0) = *(const uint4*)o;
        }
    }
}

// ---------------- attn: swapped-QK 32x32 MFMA, in-register P (permlane32_swap exchange) -------
// flat grid 1024, XCD-swizzled: each XCD owns 8 (b,h,split) groups x 16 q-blocks
#define SPA 72   // LDS row stride (bf16) = 144 B
#define MFMA32(A,B,C) __builtin_amdgcn_mfma_f32_32x32x16_bf16(A, B, C, 0, 0, 0)
__global__ __launch_bounds__(256)
void attn_mfma(const unsigned short* __restrict__ QKVb,
               const unsigned short* __restrict__ Vtg,
               float* __restrict__ Op0, float* __restrict__ Op1,
               float* __restrict__ lp)
{
    __shared__ __align__(16) unsigned short Ks[64 * SPA];
    __shared__ __align__(16) unsigned short Vt[64 * SPA];   // V^T: rows=d, cols=key
    const int vid = blockIdx.x;                  // 0..1023
    const int xcd = vid & 7, sl = vid >> 3;      // sl 0..127
    const int grp = xcd * 8 + (sl >> 4);         // 0..63 (b,h,split group)
    const int q0  = (sl & 15) * 128;
    const int h   = grp & 15;
    const int z   = grp >> 4;                    // 0..3
    const int b = z >> 1, split = z & 1;
    const int tid = threadIdx.x;
    const int lane = tid & 63, wq = tid >> 6;
    const int ql = lane & 31;
    const int hi = lane >> 5;
    const size_t base_q = ((size_t)b * TSEQ) * LDQKV + h * DHD;
    const size_t base_k = base_q + 1024;
    const size_t base_v = ((size_t)(b * NH + h) * DHD) * TSEQ;
    const int k00 = split * 1024;

    const int qrow = q0 + wq * 32 + ql;
    bf16x8 qa[4];
    #pragma unroll
    for (int t = 0; t < 4; ++t)
        qa[t] = *(const bf16x8*)(QKVb + base_q + (size_t)qrow * LDQKV + t * 16 + hi * 8);

    f32x16 o0 = (f32x16)0.f, o1 = (f32x16)0.f;
    float l_lane = 0.f;

    const int srow = tid >> 2, scol = (tid & 3) * 8;
    uint4 kr0 = *(const uint4*)(QKVb + base_k + (size_t)(k00 + srow) * LDQKV + scol);
    uint4 kr1 = *(const uint4*)(QKVb + base_k + (size_t)(k00 + srow) * LDQKV + scol + 32);
    uint4 vr0 = *(const uint4*)(Vtg + base_v + (size_t)srow * TSEQ + k00 + scol);
    uint4 vr1 = *(const uint4*)(Vtg + base_v + (size_t)srow * TSEQ + k00 + scol + 32);

    const int NT = 1024 / 64;
    for (int kb = 0; kb < NT; ++kb) {
        __syncthreads();
        *(uint4*)(Ks + srow * SPA + scol)      = kr0;
        *(uint4*)(Ks + srow * SPA + scol + 32) = kr1;
        *(uint4*)(Vt + srow * SPA + scol)      = vr0;
        *(uint4*)(Vt + srow * SPA + scol + 32) = vr1;
        __syncthreads();
        if (kb + 1 < NT) {
            const size_t gk = base_k + (size_t)(k00 + (kb + 1) * 64 + srow) * LDQKV + scol;
            const size_t gv = base_v + (size_t)srow * TSEQ + k00 + (kb + 1) * 64 + scol;
            kr0 = *(const uint4*)(QKVb + gk);
            kr1 = *(const uint4*)(QKVb + gk + 32);
            vr0 = *(const uint4*)(Vtg + gv);
            vr1 = *(const uint4*)(Vtg + gv + 32);
        }
        f32x16 s0 = (f32x16)0.f, s1 = (f32x16)0.f;
        #pragma unroll
        for (int t = 0; t < 4; ++t) {
            bf16x8 k0 = *(const bf16x8*)(Ks + ql * SPA + t * 16 + hi * 8);
            bf16x8 k1 = *(const bf16x8*)(Ks + (32 + ql) * SPA + t * 16 + hi * 8);
            s0 = MFMA32(k0, qa[t], s0);
            s1 = MFMA32(k1, qa[t], s1);
        }
        float ls0 = 0.f, ls1 = 0.f;
        u32 w[8];
        #pragma unroll
        for (int r = 0; r < 16; r += 2) {
            float pa = fexp2(s0[r]), pb = fexp2(s0[r + 1]);
            s0[r] = pa; s0[r + 1] = pb;
            ls0 += pa; ls1 += pb;
        }
        #pragma unroll
        for (int m = 0; m < 8; ++m) w[m] = cvtpk(s0[2*m], s0[2*m+1]);
        #pragma unroll
        for (int tl = 0; tl < 2; ++tl) {
            const int mb = 4 * tl, tk = tl;
            u32 a0 = w[mb],     b0 = w[mb + 2];
            u32 a1 = w[mb + 1], b1 = w[mb + 3];
            asm("v_permlane32_swap_b32 %0, %1" : "+v"(a0), "+v"(b0));
            asm("v_permlane32_swap_b32 %0, %1" : "+v"(a1), "+v"(b1));
            union { u32 uw[4]; bf16x8 v; } pu;
            pu.uw[0] = a0; pu.uw[1] = a1; pu.uw[2] = b0; pu.uw[3] = b1;
            bf16x8 v0 = *(const bf16x8*)(Vt + ql * SPA + tk * 16 + hi * 8);
            bf16x8 v1 = *(const bf16x8*)(Vt + (32 + ql) * SPA + tk * 16 + hi * 8);
            o0 = MFMA32(pu.v, v0, o0);
            o1 = MFMA32(pu.v, v1, o1);
        }
        #pragma unroll
        for (int r = 0; r < 16; r += 2) {
            float pa = fexp2(s1[r]), pb = fexp2(s1[r + 1]);
            s1[r] = pa; s1[r + 1] = pb;
            ls0 += pa; ls1 += pb;
        }
        #pragma unroll
        for (int m = 0; m < 8; ++m) w[m] = cvtpk(s1[2*m], s1[2*m+1]);
        #pragma unroll
        for (int tl = 0; tl < 2; ++tl) {
            const int mb = 4 * tl, tk = 2 + tl;
            u32 a0 = w[mb],     b0 = w[mb + 2];
            u32 a1 = w[mb + 1], b1 = w[mb + 3];
            asm("v_permlane32_swap_b32 %0, %1" : "+v"(a0), "+v"(b0));
            asm("v_permlane32_swap_b32 %0, %1" : "+v"(a1), "+v"(b1));
            union { u32 uw[4]; bf16x8 v; } pu;
            pu.uw[0] = a0; pu.uw[1] = a1; pu.uw[2] = b0; pu.uw[3] = b1;
            bf16x8 v0 = *(const bf16x8*)(Vt + ql * SPA + tk * 16 + hi * 8);
            bf16x8 v1 = *(const bf16x8*)(Vt + (32 + ql) * SPA + tk * 16 + hi * 8);
            o0 = MFMA32(pu.v, v0, o0);
            o1 = MFMA32(pu.v, v1, o1);
        }
        l_lane += ls0 + ls1;
    }
    float l_tot = l_lane + __shfl_xor(l_lane, 32, 64);
    float* Op = split ? Op1 : Op0;
    const size_t ob = ((size_t)b * TSEQ) * MDIM + h * DHD;
    #pragma unroll
    for (int r = 0; r < 16; ++r) {
        int qr = q0 + wq * 32 + (r & 3) + 8 * (r >> 2) + 4 * hi;
        Op[ob + (size_t)qr * MDIM + ql]      = o0[r];
        Op[ob + (size_t)qr * MDIM + 32 + ql] = o1[r];
    }
    if (hi == 0)
        lp[(((size_t)split * NB + b) * NH + h) * TSEQ + q0 + wq * 32 + ql] = l_tot;
}

// ---------------- U: per-(bt,d) — att[h] once, distribute to 8 experts, bf16 split -------------
__global__ __launch_bounds__(256)
void compute_U2(const float* __restrict__ Op0, const float* __restrict__ Op1,
                const float* __restrict__ lp, const u32* __restrict__ selo,
                unsigned short* __restrict__ Uh, unsigned short* __restrict__ Ul)
{
    int t = blockIdx.x * 256 + threadIdx.x;      // < MBT*64 = 262144
    int bt = t >> 6, d = t & 63;
    int b = bt >> 11, ts = bt & 2047;
    float att[16];
    #pragma unroll
    for (int h = 0; h < NH; ++h) {
        size_t li = ((size_t)b * NH + h) * TSEQ + ts;
        float l = lp[li] + lp[li + (size_t)NB * NH * TSEQ];
        size_t oi = (size_t)bt * MDIM + h * DHD + d;
        att[h] = (Op0[oi] + Op1[oi]) / l;
    }
    const u32* sp = selo + bt * 16;
    u32 m[16];
    #pragma unroll
    for (int h = 0; h < NH; ++h) m[h] = sp[h];
    #pragma unroll
    for (int e = 0; e < NE; ++e) {
        float sum = 0.f;
        #pragma unroll
        for (int h = 0; h < NH; ++h)
            if (m[h] & (1u << e)) sum += att[h];
        int idx = bt * 512 + e * 64 + d;
        unsigned short hi16 = f2bf(sum);
        Uh[idx] = hi16;
        Ul[idx] = f2bf(sum - bf2f(hi16));
    }
}

extern "C" void kernel_launch(void* const* d_in, const int* in_sizes, int n_in,
                              void* d_out, int out_size, void* d_ws, size_t ws_size,
                              hipStream_t stream)
{
    const float* x  = (const float*)d_in[0];
    const float* Wq = (const float*)d_in[1];
    const float* Wk = (const float*)d_in[2];
    const float* Wv = (const float*)d_in[3];
    const float* Ws = (const float*)d_in[4];
    const float* Wd = (const float*)d_in[5];
    const float* Wo = (const float*)d_in[6];
    float* out = (float*)d_out;
    char* ws = (char*)d_ws;

    // region 0 (16.78 MB): [xb|Wqkvb] -> Op0 ; region @46137344 (16.78 MB): xbl -> Op1
    unsigned short* xb    = (unsigned short*)(ws);
    unsigned short* Wqkvb = (unsigned short*)(ws + 8388608);
    float*          Op0   = (float*)(ws);
    unsigned short* QKVb  = (unsigned short*)(ws + 16777216);   // 20.97 MB
    unsigned short* Vtg   = (unsigned short*)(ws + 37748736);   // 8.39 MB
    unsigned short* xbl   = (unsigned short*)(ws + 46137344);   // 8.39 MB (dead before attn)
    float*          Op1   = (float*)(ws + 46137344);            // 16.78 MB
    float*          lp    = (float*)(ws + 62914560);            // 0.52 MB
    unsigned short* WoTh  = (unsigned short*)(ws + 63438848);   // 1.05 MB
    unsigned short* WoTl  = (unsigned short*)(ws + 64487424);   // 1.05 MB
    unsigned short* Uh    = (unsigned short*)(ws + 65536000);   // 4.19 MB
    u32*            flags = (u32*)(ws + 69730304);              // 64 KB (dead before Ul)
    unsigned short* Ul    = (unsigned short*)(ws + 69730304);   // 4.19 MB
    float2*         wvp   = (float2*)(ws + 73924608);           // 0.52 MB
    u32*            selv  = (u32*)(ws + 74448896);              // 0.26 MB
    u32*            selo  = (u32*)(ws + 74711040);              // 0.26 MB
    unsigned short* Wsdh  = (unsigned short*)(ws + 74973184);   // 0.52 MB
    unsigned short* Wsdl  = (unsigned short*)(ws + 75497472);   // 0.52 MB

    dim3 blk(256);
    prep<<<5504, blk, 0, stream>>>(x, Wq, Wk, Wv, Ws, Wd, Wo,
                                   xb, xbl, Wqkvb, Wsdh, Wsdl, WoTh, WoTl, flags);

    // merged QKV projection (640 blocks) + gate GEMM w/ fused top-k (256 blocks)
    qkvgate<<<896, blk, 0, stream>>>(xb, Wqkvb, QKVb, xbl, Wsdh, Wsdl,
                                     wvp, selv, selo, flags);

    gate_fix<<<128, blk, 0, stream>>>(x, Ws, Wd, flags, wvp, selv, selo);

    vtrans<<<256, blk, 0, stream>>>(QKVb, wvp, selv, Vtg);

    attn_mfma<<<1024, blk, 0, stream>>>(QKVb, Vtg, Op0, Op1, lp);

    compute_U2<<<1024, blk, 0, stream>>>(Op0, Op1, lp, selo, Uh, Ul);
    mfma_gemm3<<<512, blk, 0, stream>>>(Uh, Ul, WoTh, WoTl, out);
}